// Round 3
// baseline (384.957 us; speedup 1.0000x reference)
//
#include <hip/hip_runtime.h>
#include <math.h>

// ---------------------------------------------------------------------------
// GAT_23613730193923 — round 3: k_mlp via split-bf16 MFMA (3-term Ootomo),
// rest unchanged. B=1024, N=80 (PAST=64, FUT=16), MLP 51->128->128->50.
// ---------------------------------------------------------------------------

#define NEGBIG (-1e30f)

// ---- workspace offsets (floats) ----
#define OFF_X     0          // B*80*51 = 4177920
#define OFF_X1    4177920    // B*64*50 = 3276800
#define OFF_YH    7454720    // B*16
#define OFF_A     7471104    // 80*80
#define OFF_AN11  7477504    // 64*64
#define OFF_AN22  7481600    // 16*16
#define OFF_TH    7481856    // 50*50
#define OFF_MK    7484356    // 16*64
#define OFF_G1AT  7514692    // 51*64
#define OFF_G1BT  7517956    // 64*50
#define OFF_G2AT  7521156    // 51*64
#define OFF_SC    7524420    // 1
// split-bf16 MLP weight fragments, [n][k] layout (k contiguous), ushort:
#define OFF_W1H   7524424    // 128*64 ushort = 4096 floats
#define OFF_W1L   7528520
#define OFF_W2H   7532616    // 128*128 ushort = 8192 floats
#define OFF_W2L   7540808
#define OFF_W3H   7549000    // 64*128 ushort = 4096 floats
#define OFF_W3L   7553096
// end = 7557192 floats ~= 30.2 MB

// ---- output offsets (floats): (out B*16, dist B*6400, A 6400) ----
#define OUT_OUT   0
#define OUT_DIST  16384
#define OUT_A     6569984

typedef __attribute__((ext_vector_type(8))) short bf16x8;
typedef __attribute__((ext_vector_type(4))) float f32x4;

__device__ __forceinline__ unsigned short f2bf(float x) {
  union { float f; unsigned u; } v; v.f = x;
  unsigned r = v.u + 0x7fffu + ((v.u >> 16) & 1u);
  return (unsigned short)(r >> 16);
}
__device__ __forceinline__ float bf2f(unsigned short h) {
  union { unsigned u; float f; } v; v.u = ((unsigned)h) << 16; return v.f;
}

// ===========================================================================
// k_prep: A/An/mask/theta + split-bf16 weight fragments + GCN weight copies.
// ===========================================================================
__global__ __launch_bounds__(256) void k_prep(
    const float* __restrict__ M, const float* __restrict__ Wk,
    const float* __restrict__ sm,
    const float* __restrict__ w1, const float* __restrict__ w2,
    const float* __restrict__ w3,
    const float* __restrict__ wg1a, const float* __restrict__ wg1b,
    const float* __restrict__ wg2a,
    float* __restrict__ ws, float* __restrict__ out)
{
  __shared__ float Msh[80 * 26];
  __shared__ float Ash[80 * 80];
  __shared__ float d1[64];
  __shared__ float d2s[16];
  const int t = threadIdx.x;

  if (blockIdx.x == 0) {
    for (int e = t; e < 80 * 26; e += 256) Msh[e] = M[e];
    __syncthreads();
    for (int e = t; e < 6400; e += 256) {
      int i = e / 80, j = e % 80;
      float v = 0.f;
      if (j < i) {
        float s = 0.f;
        for (int k = 0; k < 26; ++k) s += Msh[i * 26 + k] * Msh[j * 26 + k];
        v = s > 0.f ? s : 0.f;
      }
      Ash[e] = v;
    }
    __syncthreads();
    if (t > 0 && t < 80) {
      int i = t;
      float m = -3.4e38f;
      for (int j = 0; j < i; ++j) m = fmaxf(m, Ash[i * 80 + j]);
      float s = 0.f;
      for (int j = 0; j < i; ++j) {
        float e = expf(Ash[i * 80 + j] - m);
        Ash[i * 80 + j] = e;
        s += e;
      }
      float inv = 1.f / s;
      for (int j = 0; j < i; ++j) Ash[i * 80 + j] *= inv;
    }
    __syncthreads();
    {
      float* Aws = ws + OFF_A;
      float* Aout = out + OUT_A;
      for (int e = t; e < 6400; e += 256) { Aws[e] = Ash[e]; Aout[e] = Ash[e]; }
    }
    if (t < 64) {
      int c = 0;
      for (int j = 0; j < 64; ++j) if (Ash[t * 80 + j] > 1e-15f) ++c;
      d1[t] = 1.f / sqrtf(1.f + (float)c);
    } else if (t < 80) {
      int i = t - 64; int c = 0;
      for (int j = 0; j < 16; ++j) if (Ash[(64 + i) * 80 + 64 + j] > 1e-15f) ++c;
      d2s[i] = 1.f / sqrtf(1.f + (float)c);
    }
    __syncthreads();
    {
      float* an11 = ws + OFF_AN11;
      float* an22 = ws + OFF_AN22;
      for (int e = t; e < 4096; e += 256) {
        int i = e >> 6, j = e & 63;
        an11[e] = d1[i] * Ash[i * 80 + j] * d1[j];
      }
      for (int e = t; e < 256; e += 256) {
        int i = e >> 4, j = e & 15;
        an22[e] = d2s[i] * Ash[(64 + i) * 80 + 64 + j] * d2s[j];
      }
    }
    if (t < 16) {
      float* mk = ws + OFF_MK;
      int j = t;
      float m = -3.4e38f;
      for (int i = 0; i < 64; ++i) {
        float v = Ash[(64 + j) * 80 + i];
        v = (v != 0.f) ? v : NEGBIG;
        m = fmaxf(m, v);
      }
      float s = 0.f;
      for (int i = 0; i < 64; ++i) {
        float v = Ash[(64 + j) * 80 + i];
        v = (v != 0.f) ? v : NEGBIG;
        s += expf(v - m);
      }
      float inv = 1.f / s;
      for (int i = 0; i < 64; ++i) {
        float v = Ash[(64 + j) * 80 + i];
        v = (v != 0.f) ? v : NEGBIG;
        mk[j * 64 + i] = (expf(v - m) * inv >= 0.004f) ? 1.f : 0.f;
      }
    }
  } else if (blockIdx.x == 1) {
    float* th = ws + OFF_TH;
    for (int e = t; e < 2500; e += 256) {
      int i = e / 50, j = e % 50;
      float s = 0.f;
      for (int k = 0; k < 64; ++k) s += Wk[i * 64 + k] * Wk[j * 64 + k];
      th[e] = s;
    }
    if (t == 0) {
      float v = sm[0];
      float sig = 1.f / (1.f + expf(-v));
      (ws + OFF_SC)[0] = -0.5f / (sig * 0.01f);
    }
  } else if (blockIdx.x == 2) {
    // W1 frag [n=128][k=64] (k 51..63 zero) + W3 frag [n=64][k=128] (n>=50 zero)
    unsigned short* w1h = (unsigned short*)(ws + OFF_W1H);
    unsigned short* w1l = (unsigned short*)(ws + OFF_W1L);
    for (int e = t; e < 8192; e += 256) {
      int n = e >> 6, k = e & 63;
      float v = (k < 51) ? w1[n * 51 + k] : 0.f;
      unsigned short h = f2bf(v);
      w1h[e] = h; w1l[e] = f2bf(v - bf2f(h));
    }
    unsigned short* w3h = (unsigned short*)(ws + OFF_W3H);
    unsigned short* w3l = (unsigned short*)(ws + OFF_W3L);
    for (int e = t; e < 8192; e += 256) {
      int n = e >> 7, k = e & 127;
      float v = (n < 50) ? w3[n * 128 + k] : 0.f;
      unsigned short h = f2bf(v);
      w3h[e] = h; w3l[e] = f2bf(v - bf2f(h));
    }
    float* g1at = ws + OFF_G1AT;
    for (int e = t; e < 64 * 51; e += 256) { int o = e / 51, k = e % 51; g1at[k * 64 + o] = wg1a[e]; }
  } else {
    unsigned short* w2h = (unsigned short*)(ws + OFF_W2H);
    unsigned short* w2l = (unsigned short*)(ws + OFF_W2L);
    for (int e = t; e < 16384; e += 256) {
      int n = e >> 7, k = e & 127;
      float v = w2[n * 128 + k];
      unsigned short h = f2bf(v);
      w2h[e] = h; w2l[e] = f2bf(v - bf2f(h));
    }
    float* g1bt = ws + OFF_G1BT; float* g2at = ws + OFF_G2AT;
    for (int e = t; e < 50 * 64; e += 256) { int o = e / 64, k = e % 64; g1bt[k * 50 + o] = wg1b[e]; }
    for (int e = t; e < 64 * 51; e += 256) { int o = e / 51, k = e % 51; g2at[k * 64 + o] = wg2a[e]; }
  }
}

// ===========================================================================
// k_mlp v3: split-bf16 MFMA. 64 rows/block, 4 waves, each wave owns a
// private 16-row stripe (no inter-layer barriers). Activations hi/lo bf16 in
// LDS (stride 136, conflict-free ds_read_b128); weight B-frags direct from
// global (L2-hot, [n][k] fragment-linear layout).
// ===========================================================================
#define AST 136

__global__ __launch_bounds__(256) void k_mlp(
    const float* __restrict__ data,
    const float* __restrict__ emb0, const float* __restrict__ emb1,
    const float* __restrict__ emb2,
    const float* __restrict__ b1, const float* __restrict__ b2,
    const float* __restrict__ b3,
    float* __restrict__ ws)
{
  __shared__ unsigned short aHi[64 * AST];   // 17408 B
  __shared__ unsigned short aLo[64 * AST];   // 17408 B
  const int t = threadIdx.x;
  const int lane = t & 63, wave = t >> 6;
  const int m16 = lane & 15, quad = lane >> 4;
  const int base = blockIdx.x * 64;
  const unsigned short* w1h = (const unsigned short*)(ws + OFF_W1H);
  const unsigned short* w1l = (const unsigned short*)(ws + OFF_W1L);
  const unsigned short* w2h = (const unsigned short*)(ws + OFF_W2H);
  const unsigned short* w2l = (const unsigned short*)(ws + OFF_W2L);
  const unsigned short* w3h = (const unsigned short*)(ws + OFF_W3H);
  const unsigned short* w3l = (const unsigned short*)(ws + OFF_W3L);
  float* x = ws + OFF_X;

  // ---- gather 64 rows x 64 feats (51 real, 52..63 zero) as hi/lo bf16 ----
  for (int e = t; e < 64 * 64; e += 256) {
    int r = e >> 6, c = e & 63;
    int g = base + r;
    float v = 0.f;
    if (c < 32)      { int i0 = (int)data[g * 6 + 0]; v = emb0[i0 * 32 + c]; }
    else if (c < 40) { int i1 = (int)data[g * 6 + 1]; v = emb1[i1 * 8 + (c - 32)]; }
    else if (c < 48) { int i2 = (int)data[g * 6 + 2]; v = emb2[i2 * 8 + (c - 40)]; }
    else if (c < 51) { v = data[g * 6 + 3 + (c - 48)]; }
    unsigned short h = f2bf(v);
    aHi[r * AST + c] = h;
    aLo[r * AST + c] = f2bf(v - bf2f(h));
  }
  __syncthreads();

  const int row0 = wave * 16;                       // wave-private stripe
  const int aoff = (row0 + m16) * AST + quad * 8;   // + kb

  // ---- layer 1: K=64, N=128 ----
  {
    f32x4 acc[8];
#pragma unroll
    for (int n = 0; n < 8; ++n) acc[n] = (f32x4){0.f, 0.f, 0.f, 0.f};
#pragma unroll
    for (int kb = 0; kb < 64; kb += 32) {
      bf16x8 aH = *(const bf16x8*)(aHi + aoff + kb);
      bf16x8 aL = *(const bf16x8*)(aLo + aoff + kb);
#pragma unroll
      for (int n = 0; n < 8; ++n) {
        const int col = n * 16 + m16;
        bf16x8 bH = *(const bf16x8*)(w1h + col * 64 + quad * 8 + kb);
        bf16x8 bL = *(const bf16x8*)(w1l + col * 64 + quad * 8 + kb);
        acc[n] = __builtin_amdgcn_mfma_f32_16x16x32_bf16(aH, bH, acc[n], 0, 0, 0);
        acc[n] = __builtin_amdgcn_mfma_f32_16x16x32_bf16(aH, bL, acc[n], 0, 0, 0);
        acc[n] = __builtin_amdgcn_mfma_f32_16x16x32_bf16(aL, bH, acc[n], 0, 0, 0);
      }
    }
#pragma unroll
    for (int n = 0; n < 8; ++n) {
      const int col = n * 16 + m16;
      const float bias = b1[col];
#pragma unroll
      for (int r = 0; r < 4; ++r) {
        float v = acc[n][r] + bias; v = v > 0.f ? v : 0.f;
        int row = row0 + quad * 4 + r;
        unsigned short h = f2bf(v);
        aHi[row * AST + col] = h;
        aLo[row * AST + col] = f2bf(v - bf2f(h));
      }
    }
  }

  // ---- layer 2: K=128, N=128 ----
  {
    f32x4 acc[8];
#pragma unroll
    for (int n = 0; n < 8; ++n) acc[n] = (f32x4){0.f, 0.f, 0.f, 0.f};
#pragma unroll
    for (int kb = 0; kb < 128; kb += 32) {
      bf16x8 aH = *(const bf16x8*)(aHi + aoff + kb);
      bf16x8 aL = *(const bf16x8*)(aLo + aoff + kb);
#pragma unroll
      for (int n = 0; n < 8; ++n) {
        const int col = n * 16 + m16;
        bf16x8 bH = *(const bf16x8*)(w2h + col * 128 + quad * 8 + kb);
        bf16x8 bL = *(const bf16x8*)(w2l + col * 128 + quad * 8 + kb);
        acc[n] = __builtin_amdgcn_mfma_f32_16x16x32_bf16(aH, bH, acc[n], 0, 0, 0);
        acc[n] = __builtin_amdgcn_mfma_f32_16x16x32_bf16(aH, bL, acc[n], 0, 0, 0);
        acc[n] = __builtin_amdgcn_mfma_f32_16x16x32_bf16(aL, bH, acc[n], 0, 0, 0);
      }
    }
#pragma unroll
    for (int n = 0; n < 8; ++n) {
      const int col = n * 16 + m16;
      const float bias = b2[col];
#pragma unroll
      for (int r = 0; r < 4; ++r) {
        float v = acc[n][r] + bias; v = v > 0.f ? v : 0.f;
        int row = row0 + quad * 4 + r;
        unsigned short h = f2bf(v);
        aHi[row * AST + col] = h;
        aLo[row * AST + col] = f2bf(v - bf2f(h));
      }
    }
  }

  // ---- layer 3: K=128, N=64 (50 real) -> x ----
  {
    f32x4 acc[4];
#pragma unroll
    for (int n = 0; n < 4; ++n) acc[n] = (f32x4){0.f, 0.f, 0.f, 0.f};
#pragma unroll
    for (int kb = 0; kb < 128; kb += 32) {
      bf16x8 aH = *(const bf16x8*)(aHi + aoff + kb);
      bf16x8 aL = *(const bf16x8*)(aLo + aoff + kb);
#pragma unroll
      for (int n = 0; n < 4; ++n) {
        const int col = n * 16 + m16;
        bf16x8 bH = *(const bf16x8*)(w3h + col * 128 + quad * 8 + kb);
        bf16x8 bL = *(const bf16x8*)(w3l + col * 128 + quad * 8 + kb);
        acc[n] = __builtin_amdgcn_mfma_f32_16x16x32_bf16(aH, bH, acc[n], 0, 0, 0);
        acc[n] = __builtin_amdgcn_mfma_f32_16x16x32_bf16(aH, bL, acc[n], 0, 0, 0);
        acc[n] = __builtin_amdgcn_mfma_f32_16x16x32_bf16(aL, bH, acc[n], 0, 0, 0);
      }
    }
#pragma unroll
    for (int n = 0; n < 4; ++n) {
      const int col = n * 16 + m16;
      if (col < 50) {
        const float bias = b3[col];
#pragma unroll
        for (int r = 0; r < 4; ++r) {
          int row = row0 + quad * 4 + r;
          x[(base + row) * 51 + col] = acc[n][r] + bias;
        }
      }
    }
  }
  if (t < 64) x[(base + t) * 51 + 50] = data[(base + t) * 6 + 5];
}

// ===========================================================================
// k_g1: per-batch GCN stack on past nodes, float4 k-loops (stride 68).
// ===========================================================================
template <int K, bool RELU>
__device__ __forceinline__ void gemm_tile68(const float* __restrict__ Am,
                                            const float* __restrict__ Bm,
                                            float* __restrict__ Cm, int t)
{
  const int r0 = (t >> 4) * 4, o0 = (t & 15) * 4;
  float acc[4][4] = {{0.f}};
  for (int kk = 0; kk < K; kk += 4) {
    float4 a[4], w[4];
#pragma unroll
    for (int i = 0; i < 4; ++i) a[i] = *(const float4*)(Am + (r0 + i) * 68 + kk);
#pragma unroll
    for (int q = 0; q < 4; ++q) w[q] = *(const float4*)(Bm + (kk + q) * 68 + o0);
#pragma unroll
    for (int i = 0; i < 4; ++i) {
      const float ak[4] = {a[i].x, a[i].y, a[i].z, a[i].w};
#pragma unroll
      for (int q = 0; q < 4; ++q) {
        acc[i][0] += ak[q] * w[q].x; acc[i][1] += ak[q] * w[q].y;
        acc[i][2] += ak[q] * w[q].z; acc[i][3] += ak[q] * w[q].w;
      }
    }
  }
#pragma unroll
  for (int i = 0; i < 4; ++i) {
#pragma unroll
    for (int j = 0; j < 4; ++j) {
      float v = acc[i][j];
      if (RELU) v = v > 0.f ? v : 0.f;
      Cm[(r0 + i) * 68 + o0 + j] = v;
    }
  }
}

__global__ __launch_bounds__(256) void k_g1(float* __restrict__ ws)
{
  __shared__ __align__(16) float B0[64 * 68];
  __shared__ __align__(16) float B1[64 * 68];
  __shared__ __align__(16) float B2[64 * 68];
  const int t = threadIdx.x, b = blockIdx.x;
  const float* x = ws + OFF_X;
  const float* an11 = ws + OFF_AN11;
  const float* g1at = ws + OFF_G1AT;
  const float* g1bt = ws + OFF_G1BT;
  float* x1 = ws + OFF_X1;

  for (int e = t; e < 64 * 51; e += 256) {
    int r = e / 51, c = e % 51;
    B0[r * 68 + c] = x[(b * 80 + r) * 51 + c];
  }
  for (int r = t; r < 64; r += 256) B0[r * 68 + 51] = 0.f;
  for (int e = t; e < 51 * 64; e += 256) B1[(e / 64) * 68 + (e & 63)] = g1at[e];
  for (int c = t; c < 64; c += 256) B1[51 * 68 + c] = 0.f;
  __syncthreads();
  gemm_tile68<52, false>(B0, B1, B2, t);        // t1 = sg1 @ W1aT   (64x64)
  __syncthreads();
  for (int e = t; e < 4096; e += 256) B1[(e >> 6) * 68 + (e & 63)] = an11[e];
  __syncthreads();
  gemm_tile68<64, true>(B1, B2, B0, t);         // P = relu(An @ t1)
  __syncthreads();
  gemm_tile68<64, false>(B1, B0, B2, t);        // Q = An @ P
  __syncthreads();
  for (int e = t; e < 64 * 50; e += 256) {
    int k = e / 50, o = e % 50;
    B0[k * 68 + o] = g1bt[e];
  }
  for (int k = t; k < 64; k += 256) { B0[k * 68 + 50] = 0.f; B0[k * 68 + 51] = 0.f; }
  __syncthreads();
  {
    const int r0 = (t >> 4) * 4, o0 = (t & 15) * 4;
    float acc[4][4] = {{0.f}};
    for (int kk = 0; kk < 64; kk += 4) {
      float4 a[4], w[4];
#pragma unroll
      for (int i = 0; i < 4; ++i) a[i] = *(const float4*)(B2 + (r0 + i) * 68 + kk);
#pragma unroll
      for (int q = 0; q < 4; ++q) w[q] = *(const float4*)(B0 + (kk + q) * 68 + o0);
#pragma unroll
      for (int i = 0; i < 4; ++i) {
        const float ak[4] = {a[i].x, a[i].y, a[i].z, a[i].w};
#pragma unroll
        for (int q = 0; q < 4; ++q) {
          acc[i][0] += ak[q] * w[q].x; acc[i][1] += ak[q] * w[q].y;
          acc[i][2] += ak[q] * w[q].z; acc[i][3] += ak[q] * w[q].w;
        }
      }
    }
#pragma unroll
    for (int i = 0; i < 4; ++i) {
#pragma unroll
      for (int j = 0; j < 4; ++j) {
        int o = o0 + j;
        if (o < 50) x1[(b * 64 + r0 + i) * 50 + o] = acc[i][j];
      }
    }
  }
}

// ===========================================================================
// k_q: q decomposition + masked softmax over FUT axis + yh. stride 60.
// ===========================================================================
__global__ __launch_bounds__(256) void k_q(float* __restrict__ ws)
{
  __shared__ __align__(16) float Xp[64 * 60];
  __shared__ __align__(16) float Xf[16 * 60];
  __shared__ __align__(16) float Th[52 * 60];
  __shared__ __align__(16) float U[64 * 60];
  __shared__ float V[16 * 60];
  __shared__ float yv[64];
  __shared__ float sv[64];
  __shared__ float rv[16];
  __shared__ float al[16 * 64];
  __shared__ float mks[16 * 64];
  const int t = threadIdx.x, b = blockIdx.x;
  const float* x = ws + OFF_X;
  const float* x1 = ws + OFF_X1;
  const float* th = ws + OFF_TH;
  const float* mk = ws + OFF_MK;
  const float sc = (ws + OFF_SC)[0];
  float* yh = ws + OFF_YH;

  for (int e = t; e < 64 * 60; e += 256) {
    int r = e / 60, c = e - r * 60;
    Xp[e] = (c < 50) ? x1[(b * 64 + r) * 50 + c] : 0.f;
  }
  for (int e = t; e < 16 * 60; e += 256) {
    int r = e / 60, c = e - r * 60;
    Xf[e] = (c < 50) ? x[(b * 80 + 64 + r) * 51 + c] : 0.f;
  }
  for (int e = t; e < 52 * 60; e += 256) {
    int r = e / 60, c = e - r * 60;
    Th[e] = (r < 50 && c < 50) ? th[r * 50 + c] : 0.f;
  }
  for (int e = t; e < 1024; e += 256) mks[e] = mk[e];
  if (t < 64) yv[t] = x[(b * 80 + t) * 51 + 50];
  __syncthreads();

  {
    const int r0 = (t >> 4) * 4;
    int o0 = (t & 15) * 4; if (o0 > 56) o0 = 56;
    float acc[4][4] = {{0.f}};
    for (int kk = 0; kk < 52; kk += 4) {
      float4 a[4], w[4];
#pragma unroll
      for (int i = 0; i < 4; ++i) a[i] = *(const float4*)(Xp + (r0 + i) * 60 + kk);
#pragma unroll
      for (int q = 0; q < 4; ++q) w[q] = *(const float4*)(Th + (kk + q) * 60 + o0);
#pragma unroll
      for (int i = 0; i < 4; ++i) {
        const float ak[4] = {a[i].x, a[i].y, a[i].z, a[i].w};
#pragma unroll
        for (int q = 0; q < 4; ++q) {
          acc[i][0] += ak[q] * w[q].x; acc[i][1] += ak[q] * w[q].y;
          acc[i][2] += ak[q] * w[q].z; acc[i][3] += ak[q] * w[q].w;
        }
      }
    }
#pragma unroll
    for (int i = 0; i < 4; ++i)
      *(float4*)(U + (r0 + i) * 60 + o0) = make_float4(acc[i][0], acc[i][1], acc[i][2], acc[i][3]);
    const int jr = t >> 4;
    float accv[4] = {0.f, 0.f, 0.f, 0.f};
    for (int k = 0; k < 50; ++k) {
      float a = Xf[jr * 60 + k];
#pragma unroll
      for (int j = 0; j < 4; ++j) accv[j] += a * Th[k * 60 + o0 + j];
    }
#pragma unroll
    for (int j = 0; j < 4; ++j) V[jr * 60 + o0 + j] = accv[j];
  }
  __syncthreads();
  if (t < 64) {
    float s = 0.f;
    for (int k = 0; k < 50; ++k) s += U[t * 60 + k] * Xp[t * 60 + k];
    sv[t] = s;
  } else if (t < 80) {
    int j = t - 64; float s = 0.f;
    for (int k = 0; k < 50; ++k) s += V[j * 60 + k] * Xf[j * 60 + k];
    rv[j] = s;
  }
  __syncthreads();
  {
    const int i = t & 63;
    const int j0 = (t >> 6) * 4;
#pragma unroll
    for (int jj = 0; jj < 4; ++jj) {
      int j = j0 + jj;
      float d = 0.f;
      for (int kk = 0; kk < 52; kk += 4) {
        float4 u = *(const float4*)(U + i * 60 + kk);
        float4 f = *(const float4*)(Xf + j * 60 + kk);
        d += u.x * f.x + u.y * f.y + u.z * f.z + u.w * f.w;
      }
      al[j * 64 + i] = sc * (sv[i] + rv[j] - 2.f * d);
    }
  }
  __syncthreads();
  if (t < 64) {
    const int i = t;
    float m = -3.4e38f;
#pragma unroll
    for (int j = 0; j < 16; ++j) {
      float v = (mks[j * 64 + i] != 0.f) ? al[j * 64 + i] : NEGBIG;
      m = fmaxf(m, v);
    }
    float s = 0.f; float ex[16];
#pragma unroll
    for (int j = 0; j < 16; ++j) {
      float v = (mks[j * 64 + i] != 0.f) ? al[j * 64 + i] : NEGBIG;
      ex[j] = expf(v - m); s += ex[j];
    }
    float inv = 1.f / s;
#pragma unroll
    for (int j = 0; j < 16; ++j) al[j * 64 + i] = ex[j] * inv;
  }
  __syncthreads();
  if (t < 16) {
    float s = 0.f;
    for (int i = 0; i < 64; ++i) s += al[t * 64 + i] * yv[i];
    yh[b * 16 + t] = s;
  }
}

// ===========================================================================
// k_g2 (unchanged — tiny)
// ===========================================================================
__global__ __launch_bounds__(256) void k_g2(const float* __restrict__ wg2b,
                                            float* __restrict__ ws,
                                            float* __restrict__ out)
{
  __shared__ float X2[16 * 53];
  __shared__ __align__(16) float G[16 * 68];
  __shared__ float P[16 * 68];
  __shared__ float A22[256];
  __shared__ float wb[64];
  __shared__ float z[16];
  const int t = threadIdx.x, b = blockIdx.x;
  const float* x = ws + OFF_X;
  const float* yh = ws + OFF_YH;
  const float* an22 = ws + OFF_AN22;
  const float* g2at = ws + OFF_G2AT;

  for (int e = t; e < 16 * 51; e += 256) {
    int r = e / 51, c = e % 51;
    X2[r * 53 + c] = (c < 50) ? x[(b * 80 + 64 + r) * 51 + c] : yh[b * 16 + r];
  }
  for (int e = t; e < 256; e += 256) A22[e] = an22[e];
  if (t < 64) wb[t] = wg2b[t];
  __syncthreads();
  {
    const int j = t >> 4, o0 = (t & 15) * 4;
    float acc[4] = {0.f, 0.f, 0.f, 0.f};
    for (int k = 0; k < 51; ++k) {
      float a = X2[j * 53 + k];
      const float4 w = *(const float4*)(g2at + k * 64 + o0);
      acc[0] += a * w.x; acc[1] += a * w.y; acc[2] += a * w.z; acc[3] += a * w.w;
    }
#pragma unroll
    for (int q2 = 0; q2 < 4; ++q2) G[j * 68 + o0 + q2] = acc[q2];
  }
  __syncthreads();
  {
    const int j = t >> 4, o0 = (t & 15) * 4;
    float acc[4] = {0.f, 0.f, 0.f, 0.f};
    for (int k = 0; k < 16; ++k) {
      float a = A22[j * 16 + k];
      const float4 g4 = *(const float4*)(G + k * 68 + o0);
      acc[0] += a * g4.x; acc[1] += a * g4.y; acc[2] += a * g4.z; acc[3] += a * g4.w;
    }
#pragma unroll
    for (int q2 = 0; q2 < 4; ++q2) {
      float v = acc[q2];
      P[j * 68 + o0 + q2] = v > 0.f ? v : 0.f;
    }
  }
  __syncthreads();
  if (t < 16) {
    float s = 0.f;
    for (int o = 0; o < 64; ++o) s += P[t * 68 + o] * wb[o];
    z[t] = s;
  }
  __syncthreads();
  if (t < 16) {
    float s = 0.f;
#pragma unroll
    for (int k = 0; k < 16; ++k) s += A22[t * 16 + k] * z[k];
    out[OUT_OUT + b * 16 + t] = s;
  }
}

// ===========================================================================
// k_dist: pairwise distances; stride 60, float4 k-loop, coalesced stores.
// ===========================================================================
__global__ __launch_bounds__(256) void k_dist(float* __restrict__ ws,
                                              float* __restrict__ out)
{
  __shared__ __align__(16) float Xc[80 * 60];
  __shared__ float sq[80];
  const int t = threadIdx.x, b = blockIdx.x;
  const float* x = ws + OFF_X;
  const float* yh = ws + OFF_YH;
  float* dist = out + OUT_DIST + b * 6400;

  for (int e = t; e < 80 * 60; e += 256) {
    int n = e / 60, c = e - n * 60;
    float v = 0.f;
    if (c < 50)       v = x[(b * 80 + n) * 51 + c];
    else if (c == 50) v = (n < 64) ? x[(b * 80 + n) * 51 + 50] : yh[b * 16 + (n - 64)];
    Xc[e] = v;
  }
  __syncthreads();
  if (t < 80) {
    float s = 0.f;
    for (int c = 0; c < 51; ++c) { float v = Xc[t * 60 + c]; s += v * v; }
    sq[t] = s;
  }
  __syncthreads();
  const int n0 = (t >> 4) * 5;
  const int mc = t & 15;
  float acc[5][5] = {{0.f}};
  for (int kk = 0; kk < 52; kk += 4) {
    float4 a[5], bv[5];
#pragma unroll
    for (int i = 0; i < 5; ++i) a[i] = *(const float4*)(Xc + (n0 + i) * 60 + kk);
#pragma unroll
    for (int j = 0; j < 5; ++j) bv[j] = *(const float4*)(Xc + (mc + 16 * j) * 60 + kk);
#pragma unroll
    for (int i = 0; i < 5; ++i) {
#pragma unroll
      for (int j = 0; j < 5; ++j) {
        acc[i][j] += a[i].x * bv[j].x + a[i].y * bv[j].y +
                     a[i].z * bv[j].z + a[i].w * bv[j].w;
      }
    }
  }
#pragma unroll
  for (int i = 0; i < 5; ++i) {
#pragma unroll
    for (int j = 0; j < 5; ++j) {
      int m = mc + 16 * j;
      float d2 = sq[n0 + i] + sq[m] - 2.f * acc[i][j];
      d2 = d2 > 0.f ? d2 : 0.f;
      dist[(n0 + i) * 80 + m] = d2 > 0.f ? sqrtf(d2) : 0.f;
    }
  }
}

// ===========================================================================
extern "C" void kernel_launch(void* const* d_in, const int* in_sizes, int n_in,
                              void* d_out, int out_size, void* d_ws, size_t ws_size,
                              hipStream_t stream)
{
  const float* data = (const float*)d_in[0];
  const float* emb0 = (const float*)d_in[1];
  const float* emb1 = (const float*)d_in[2];
  const float* emb2 = (const float*)d_in[3];
  const float* w1   = (const float*)d_in[4];
  const float* b1   = (const float*)d_in[5];
  const float* w2   = (const float*)d_in[6];
  const float* b2   = (const float*)d_in[7];
  const float* w3   = (const float*)d_in[8];
  const float* b3   = (const float*)d_in[9];
  const float* M    = (const float*)d_in[10];
  const float* wg1a = (const float*)d_in[11];
  const float* wg1b = (const float*)d_in[12];
  const float* Wk   = (const float*)d_in[13];
  const float* smo  = (const float*)d_in[14];
  const float* wg2a = (const float*)d_in[15];
  const float* wg2b = (const float*)d_in[16];
  float* ws  = (float*)d_ws;
  float* out = (float*)d_out;

  k_prep<<<dim3(4),    dim3(256), 0, stream>>>(M, Wk, smo, w1, w2, w3, wg1a, wg1b, wg2a, ws, out);
  k_mlp <<<dim3(1280), dim3(256), 0, stream>>>(data, emb0, emb1, emb2, b1, b2, b3, ws);
  k_g1  <<<dim3(1024), dim3(256), 0, stream>>>(ws);
  k_q   <<<dim3(1024), dim3(256), 0, stream>>>(ws);
  k_g2  <<<dim3(1024), dim3(256), 0, stream>>>(wg2b, ws, out);
  k_dist<<<dim3(1024), dim3(256), 0, stream>>>(ws, out);
}

// Round 4
// 317.131 us; speedup vs baseline: 1.2139x; 1.2139x over previous
//
#include <hip/hip_runtime.h>
#include <math.h>

// ---------------------------------------------------------------------------
// GAT_23613730193923 — round 4: k_mlp v4 (LDS-staged split-bf16 weights,
// XOR-swizzled LDS) + k_g1 converted to split-bf16 MFMA.
// B=1024, N=80 (PAST=64, FUT=16), MLP 51->128->128->50.
// ---------------------------------------------------------------------------

#define NEGBIG (-1e30f)

// ---- workspace offsets (floats) ----
#define OFF_X     0          // B*80*51 = 4177920
#define OFF_X1    4177920    // B*64*50 = 3276800
#define OFF_YH    7454720    // B*16
#define OFF_A     7471104    // 80*80
#define OFF_AN11  7477504    // 64*64 (fp32, unused by compute now)
#define OFF_AN22  7481600    // 16*16
#define OFF_TH    7481856    // 50*50
#define OFF_MK    7484356    // 16*64
#define OFF_GAH   7514692    // W1a hi: 64*64 ushort = 2048 fl
#define OFF_GAL   7516740    // W1a lo
#define OFF_G2AT  7521156    // 51*64 fp32 (k_g2)
#define OFF_SC    7524420    // 1
#define OFF_W1H   7524424    // 128*64 ushort
#define OFF_W1L   7528520
#define OFF_W2H   7532616    // 128*128 ushort
#define OFF_W2L   7540808
#define OFF_W3H   7549000    // 64*128 ushort
#define OFF_W3L   7553096
#define OFF_ANH   7557192    // An11 hi: 64*64 ushort
#define OFF_ANL   7559240
#define OFF_GBH   7561288    // W1b hi: 64*64 ushort
#define OFF_GBL   7563336
// end = 7565384 floats ~= 30.26 MB

// ---- output offsets (floats): (out B*16, dist B*6400, A 6400) ----
#define OUT_OUT   0
#define OUT_DIST  16384
#define OUT_A     6569984

typedef __attribute__((ext_vector_type(8))) short bf16x8;
typedef __attribute__((ext_vector_type(4))) short s16x4;
typedef __attribute__((ext_vector_type(4))) float f32x4;

__device__ __forceinline__ unsigned short f2bf(float x) {
  union { float f; unsigned u; } v; v.f = x;
  unsigned r = v.u + 0x7fffu + ((v.u >> 16) & 1u);
  return (unsigned short)(r >> 16);
}
__device__ __forceinline__ float bf2f(unsigned short h) {
  union { unsigned u; float f; } v; v.u = ((unsigned)h) << 16; return v.f;
}
// swizzled ushort index for [r][k] array, row stride (1<<SB) ushorts
// phys chunk = (k>>3) ^ (r&7); keeps 16B chunks, spreads banks.
#define SWZ6(r, k) (((r) << 6) + (((((k) >> 3) ^ ((r) & 7)) << 3) | ((k) & 7)))
#define SWZ7(r, k) (((r) << 7) + (((((k) >> 3) ^ ((r) & 7)) << 3) | ((k) & 7)))

// ===========================================================================
// k_prep: A/An/mask/theta + split-bf16 weights (MLP + GCN1 + An11)
// ===========================================================================
__global__ __launch_bounds__(256) void k_prep(
    const float* __restrict__ M, const float* __restrict__ Wk,
    const float* __restrict__ sm,
    const float* __restrict__ w1, const float* __restrict__ w2,
    const float* __restrict__ w3,
    const float* __restrict__ wg1a, const float* __restrict__ wg1b,
    const float* __restrict__ wg2a,
    float* __restrict__ ws, float* __restrict__ out)
{
  __shared__ float Msh[80 * 26];
  __shared__ float Ash[80 * 80];
  __shared__ float d1[64];
  __shared__ float d2s[16];
  const int t = threadIdx.x;

  if (blockIdx.x == 0) {
    for (int e = t; e < 80 * 26; e += 256) Msh[e] = M[e];
    __syncthreads();
    for (int e = t; e < 6400; e += 256) {
      int i = e / 80, j = e % 80;
      float v = 0.f;
      if (j < i) {
        float s = 0.f;
        for (int k = 0; k < 26; ++k) s += Msh[i * 26 + k] * Msh[j * 26 + k];
        v = s > 0.f ? s : 0.f;
      }
      Ash[e] = v;
    }
    __syncthreads();
    if (t > 0 && t < 80) {
      int i = t;
      float m = -3.4e38f;
      for (int j = 0; j < i; ++j) m = fmaxf(m, Ash[i * 80 + j]);
      float s = 0.f;
      for (int j = 0; j < i; ++j) {
        float e = expf(Ash[i * 80 + j] - m);
        Ash[i * 80 + j] = e;
        s += e;
      }
      float inv = 1.f / s;
      for (int j = 0; j < i; ++j) Ash[i * 80 + j] *= inv;
    }
    __syncthreads();
    {
      float* Aws = ws + OFF_A;
      float* Aout = out + OUT_A;
      for (int e = t; e < 6400; e += 256) { Aws[e] = Ash[e]; Aout[e] = Ash[e]; }
    }
    if (t < 64) {
      int c = 0;
      for (int j = 0; j < 64; ++j) if (Ash[t * 80 + j] > 1e-15f) ++c;
      d1[t] = 1.f / sqrtf(1.f + (float)c);
    } else if (t < 80) {
      int i = t - 64; int c = 0;
      for (int j = 0; j < 16; ++j) if (Ash[(64 + i) * 80 + 64 + j] > 1e-15f) ++c;
      d2s[i] = 1.f / sqrtf(1.f + (float)c);
    }
    __syncthreads();
    {
      float* an22 = ws + OFF_AN22;
      unsigned short* anH = (unsigned short*)(ws + OFF_ANH);
      unsigned short* anL = (unsigned short*)(ws + OFF_ANL);
      for (int e = t; e < 4096; e += 256) {
        int i = e >> 6, j = e & 63;
        float v = d1[i] * Ash[i * 80 + j] * d1[j];
        unsigned short h = f2bf(v);
        anH[e] = h; anL[e] = f2bf(v - bf2f(h));
      }
      for (int e = t; e < 256; e += 256) {
        int i = e >> 4, j = e & 15;
        an22[e] = d2s[i] * Ash[(64 + i) * 80 + 64 + j] * d2s[j];
      }
    }
    if (t < 16) {
      float* mk = ws + OFF_MK;
      int j = t;
      float m = -3.4e38f;
      for (int i = 0; i < 64; ++i) {
        float v = Ash[(64 + j) * 80 + i];
        v = (v != 0.f) ? v : NEGBIG;
        m = fmaxf(m, v);
      }
      float s = 0.f;
      for (int i = 0; i < 64; ++i) {
        float v = Ash[(64 + j) * 80 + i];
        v = (v != 0.f) ? v : NEGBIG;
        s += expf(v - m);
      }
      float inv = 1.f / s;
      for (int i = 0; i < 64; ++i) {
        float v = Ash[(64 + j) * 80 + i];
        v = (v != 0.f) ? v : NEGBIG;
        mk[j * 64 + i] = (expf(v - m) * inv >= 0.004f) ? 1.f : 0.f;
      }
    }
  } else if (blockIdx.x == 1) {
    float* th = ws + OFF_TH;
    for (int e = t; e < 2500; e += 256) {
      int i = e / 50, j = e % 50;
      float s = 0.f;
      for (int k = 0; k < 64; ++k) s += Wk[i * 64 + k] * Wk[j * 64 + k];
      th[e] = s;
    }
    if (t == 0) {
      float v = sm[0];
      float sig = 1.f / (1.f + expf(-v));
      (ws + OFF_SC)[0] = -0.5f / (sig * 0.01f);
    }
  } else if (blockIdx.x == 2) {
    // W1 frag [n=128][k=64], W3 frag [n=64][k=128], W1a frag [n=64][k=64]
    unsigned short* w1h = (unsigned short*)(ws + OFF_W1H);
    unsigned short* w1l = (unsigned short*)(ws + OFF_W1L);
    for (int e = t; e < 8192; e += 256) {
      int n = e >> 6, k = e & 63;
      float v = (k < 51) ? w1[n * 51 + k] : 0.f;
      unsigned short h = f2bf(v);
      w1h[e] = h; w1l[e] = f2bf(v - bf2f(h));
    }
    unsigned short* w3h = (unsigned short*)(ws + OFF_W3H);
    unsigned short* w3l = (unsigned short*)(ws + OFF_W3L);
    for (int e = t; e < 8192; e += 256) {
      int n = e >> 7, k = e & 127;
      float v = (n < 50) ? w3[n * 128 + k] : 0.f;
      unsigned short h = f2bf(v);
      w3h[e] = h; w3l[e] = f2bf(v - bf2f(h));
    }
    unsigned short* gah = (unsigned short*)(ws + OFF_GAH);
    unsigned short* gal = (unsigned short*)(ws + OFF_GAL);
    for (int e = t; e < 4096; e += 256) {
      int n = e >> 6, k = e & 63;
      float v = (k < 51) ? wg1a[n * 51 + k] : 0.f;
      unsigned short h = f2bf(v);
      gah[e] = h; gal[e] = f2bf(v - bf2f(h));
    }
  } else {
    unsigned short* w2h = (unsigned short*)(ws + OFF_W2H);
    unsigned short* w2l = (unsigned short*)(ws + OFF_W2L);
    for (int e = t; e < 16384; e += 256) {
      int n = e >> 7, k = e & 127;
      float v = w2[n * 128 + k];
      unsigned short h = f2bf(v);
      w2h[e] = h; w2l[e] = f2bf(v - bf2f(h));
    }
    unsigned short* gbh = (unsigned short*)(ws + OFF_GBH);
    unsigned short* gbl = (unsigned short*)(ws + OFF_GBL);
    for (int e = t; e < 4096; e += 256) {
      int n = e >> 6, k = e & 63;
      float v = (n < 50) ? wg1b[n * 64 + k] : 0.f;
      unsigned short h = f2bf(v);
      gbh[e] = h; gbl[e] = f2bf(v - bf2f(h));
    }
    float* g2at = ws + OFF_G2AT;
    for (int e = t; e < 64 * 51; e += 256) { int o = e / 51, k = e % 51; g2at[k * 64 + o] = wg2a[e]; }
  }
}

// ===========================================================================
// k_mlp v4: split-bf16 MFMA, weights staged in LDS per layer, XOR swizzle.
// 64 rows/block, 4 waves x 16-row private stripes. LDS = 64 KB exactly.
// ===========================================================================
__global__ __launch_bounds__(256) void k_mlp(
    const float* __restrict__ data,
    const float* __restrict__ emb0, const float* __restrict__ emb1,
    const float* __restrict__ emb2,
    const float* __restrict__ b1, const float* __restrict__ b2,
    const float* __restrict__ b3,
    float* __restrict__ ws)
{
  __shared__ __align__(16) unsigned short actH[64 * 128];  // 16 KB
  __shared__ __align__(16) unsigned short actL[64 * 128];  // 16 KB
  __shared__ __align__(16) unsigned short wbH[8192];       // 16 KB
  __shared__ __align__(16) unsigned short wbL[8192];       // 16 KB
  const int t = threadIdx.x;
  const int lane = t & 63, wave = t >> 6;
  const int m16 = lane & 15, quad = lane >> 4;
  const int base = blockIdx.x * 64;
  const int row0 = wave * 16;
  const int arow = row0 + m16;           // A-frag row for this lane
  const unsigned short* w1h = (const unsigned short*)(ws + OFF_W1H);
  const unsigned short* w1l = (const unsigned short*)(ws + OFF_W1L);
  const unsigned short* w2h = (const unsigned short*)(ws + OFF_W2H);
  const unsigned short* w2l = (const unsigned short*)(ws + OFF_W2L);
  const unsigned short* w3h = (const unsigned short*)(ws + OFF_W3H);
  const unsigned short* w3l = (const unsigned short*)(ws + OFF_W3L);
  float* x = ws + OFF_X;

  // ---- gather 64 rows x 64 feats (51 real) into act chunks 0..7 ----
  for (int e = t; e < 4096; e += 256) {
    int r = e >> 6, c = e & 63;
    int g = base + r;
    float v = 0.f;
    if (c < 32)      { int i0 = (int)data[g * 6 + 0]; v = emb0[i0 * 32 + c]; }
    else if (c < 40) { int i1 = (int)data[g * 6 + 1]; v = emb1[i1 * 8 + (c - 32)]; }
    else if (c < 48) { int i2 = (int)data[g * 6 + 2]; v = emb2[i2 * 8 + (c - 40)]; }
    else if (c < 51) { v = data[g * 6 + 3 + (c - 48)]; }
    int idx = SWZ7(r, c);
    unsigned short h = f2bf(v);
    actH[idx] = h; actL[idx] = f2bf(v - bf2f(h));
  }
  // ---- stage W1 (128 cols x 8 chunks) ----
  for (int q = t; q < 1024; q += 256) {
    int col = q >> 3, c = q & 7;
    int dst = (col << 6) + ((c ^ (col & 7)) << 3);
    *(bf16x8*)(wbH + dst) = *(const bf16x8*)(w1h + (col << 6) + (c << 3));
    *(bf16x8*)(wbL + dst) = *(const bf16x8*)(w1l + (col << 6) + (c << 3));
  }
  __syncthreads();

  // ---- layer 1: K=64, N=128 ----
  f32x4 acc2[8];   // reused for layer2 accumulation later
  {
    f32x4 acc[8];
#pragma unroll
    for (int n = 0; n < 8; ++n) acc[n] = (f32x4){0.f, 0.f, 0.f, 0.f};
#pragma unroll
    for (int kb8 = 0; kb8 < 8; kb8 += 4) {
      int ach = ((quad + kb8) ^ (m16 & 7)) << 3;
      bf16x8 aH = *(const bf16x8*)(actH + (arow << 7) + ach);
      bf16x8 aL = *(const bf16x8*)(actL + (arow << 7) + ach);
#pragma unroll
      for (int n = 0; n < 8; ++n) {
        const int col = n * 16 + m16;
        int boff = (col << 6) + ach;
        bf16x8 bH = *(const bf16x8*)(wbH + boff);
        bf16x8 bL = *(const bf16x8*)(wbL + boff);
        acc[n] = __builtin_amdgcn_mfma_f32_16x16x32_bf16(aH, bH, acc[n], 0, 0, 0);
        acc[n] = __builtin_amdgcn_mfma_f32_16x16x32_bf16(aH, bL, acc[n], 0, 0, 0);
        acc[n] = __builtin_amdgcn_mfma_f32_16x16x32_bf16(aL, bH, acc[n], 0, 0, 0);
      }
    }
#pragma unroll
    for (int n = 0; n < 8; ++n) {
      const int col = n * 16 + m16;
      const float bias = b1[col];
#pragma unroll
      for (int r = 0; r < 4; ++r) {
        float v = acc[n][r] + bias; v = v > 0.f ? v : 0.f;
        int row = row0 + quad * 4 + r;
        int idx = SWZ7(row, col);
        unsigned short h = f2bf(v);
        actH[idx] = h; actL[idx] = f2bf(v - bf2f(h));
      }
    }
  }

  // ---- layer 2: K=128, N=128 in two 64-col halves ----
#pragma unroll
  for (int n = 0; n < 8; ++n) acc2[n] = (f32x4){0.f, 0.f, 0.f, 0.f};
  for (int h2 = 0; h2 < 2; ++h2) {
    __syncthreads();   // previous wbuf reads done (L1 / half-0 compute)
    for (int q = t; q < 1024; q += 256) {
      int coll = q >> 4, c = q & 15;
      int srcc = (((h2 << 6) + coll) << 7) + (c << 3);
      int dst = (coll << 7) + ((c ^ (coll & 7)) << 3);
      *(bf16x8*)(wbH + dst) = *(const bf16x8*)(w2h + srcc);
      *(bf16x8*)(wbL + dst) = *(const bf16x8*)(w2l + srcc);
    }
    __syncthreads();
#pragma unroll
    for (int kb8 = 0; kb8 < 16; kb8 += 4) {
      int ach = ((quad + kb8) ^ (m16 & 7)) << 3;
      bf16x8 aH = *(const bf16x8*)(actH + (arow << 7) + ach);
      bf16x8 aL = *(const bf16x8*)(actL + (arow << 7) + ach);
#pragma unroll
      for (int n = 0; n < 4; ++n) {
        const int col = n * 16 + m16;
        int boff = (col << 7) + ach;
        bf16x8 bH = *(const bf16x8*)(wbH + boff);
        bf16x8 bL = *(const bf16x8*)(wbL + boff);
        f32x4 a = acc2[h2 * 4 + n];
        a = __builtin_amdgcn_mfma_f32_16x16x32_bf16(aH, bH, a, 0, 0, 0);
        a = __builtin_amdgcn_mfma_f32_16x16x32_bf16(aH, bL, a, 0, 0, 0);
        a = __builtin_amdgcn_mfma_f32_16x16x32_bf16(aL, bH, a, 0, 0, 0);
        acc2[h2 * 4 + n] = a;
      }
    }
  }
  // write h2 (own rows — wave-private, no barrier needed before writes)
#pragma unroll
  for (int hh = 0; hh < 2; ++hh) {
#pragma unroll
    for (int n = 0; n < 4; ++n) {
      const int col = hh * 64 + n * 16 + m16;
      const float bias = b2[col];
#pragma unroll
      for (int r = 0; r < 4; ++r) {
        float v = acc2[hh * 4 + n][r] + bias; v = v > 0.f ? v : 0.f;
        int row = row0 + quad * 4 + r;
        int idx = SWZ7(row, col);
        unsigned short h = f2bf(v);
        actH[idx] = h; actL[idx] = f2bf(v - bf2f(h));
      }
    }
  }

  // ---- layer 3: K=128, N=64 (50 real) ----
  __syncthreads();   // all W2 reads + h2 writes done
  for (int q = t; q < 1024; q += 256) {
    int coll = q >> 4, c = q & 15;
    int dst = (coll << 7) + ((c ^ (coll & 7)) << 3);
    *(bf16x8*)(wbH + dst) = *(const bf16x8*)(w3h + (coll << 7) + (c << 3));
    *(bf16x8*)(wbL + dst) = *(const bf16x8*)(w3l + (coll << 7) + (c << 3));
  }
  __syncthreads();
  {
    f32x4 acc[4];
#pragma unroll
    for (int n = 0; n < 4; ++n) acc[n] = (f32x4){0.f, 0.f, 0.f, 0.f};
#pragma unroll
    for (int kb8 = 0; kb8 < 16; kb8 += 4) {
      int ach = ((quad + kb8) ^ (m16 & 7)) << 3;
      bf16x8 aH = *(const bf16x8*)(actH + (arow << 7) + ach);
      bf16x8 aL = *(const bf16x8*)(actL + (arow << 7) + ach);
#pragma unroll
      for (int n = 0; n < 4; ++n) {
        const int col = n * 16 + m16;
        int boff = (col << 7) + ach;
        bf16x8 bH = *(const bf16x8*)(wbH + boff);
        bf16x8 bL = *(const bf16x8*)(wbL + boff);
        acc[n] = __builtin_amdgcn_mfma_f32_16x16x32_bf16(aH, bH, acc[n], 0, 0, 0);
        acc[n] = __builtin_amdgcn_mfma_f32_16x16x32_bf16(aH, bL, acc[n], 0, 0, 0);
        acc[n] = __builtin_amdgcn_mfma_f32_16x16x32_bf16(aL, bH, acc[n], 0, 0, 0);
      }
    }
#pragma unroll
    for (int n = 0; n < 4; ++n) {
      const int col = n * 16 + m16;
      if (col < 50) {
        const float bias = b3[col];
#pragma unroll
        for (int r = 0; r < 4; ++r) {
          int row = row0 + quad * 4 + r;
          x[(base + row) * 51 + col] = acc[n][r] + bias;
        }
      }
    }
  }
  if (t < 64) x[(base + t) * 51 + 50] = data[(base + t) * 6 + 5];
}

// ===========================================================================
// k_g1 v2: split-bf16 MFMA GCN stack. 1 batch/block, 4 waves x 16-row tiles.
// T1 = sg1@W1a^T ; P = relu(An@T1) ; Q = An@P ; x1 = Q@W1b^T. LDS = 64 KB.
// ===========================================================================
__global__ __launch_bounds__(256) void k_g1(float* __restrict__ ws)
{
  __shared__ __align__(16) unsigned short b1H[4096], b1L[4096];   // sg1 -> Q  [r][k]
  __shared__ __align__(16) unsigned short b2H[4096], b2L[4096];   // T1 -> P   [col][k]
  __shared__ __align__(16) unsigned short anH[4096], anL[4096];   // An        [r][k]
  __shared__ __align__(16) unsigned short wH[4096],  wL[4096];    // W1a -> W1b [n][k]
  const int t = threadIdx.x, b = blockIdx.x;
  const int lane = t & 63, wave = t >> 6;
  const int m16 = lane & 15, quad = lane >> 4;
  const int row0 = wave * 16;
  const int arow = row0 + m16;
  const float* x = ws + OFF_X;
  const unsigned short* gAnH = (const unsigned short*)(ws + OFF_ANH);
  const unsigned short* gAnL = (const unsigned short*)(ws + OFF_ANL);
  const unsigned short* gaH = (const unsigned short*)(ws + OFF_GAH);
  const unsigned short* gaL = (const unsigned short*)(ws + OFF_GAL);
  const unsigned short* gbH = (const unsigned short*)(ws + OFF_GBH);
  const unsigned short* gbL = (const unsigned short*)(ws + OFF_GBL);
  float* x1 = ws + OFF_X1;

  // ---- gather sg1 (64x51 -> K=64) into b1 ----
  for (int e = t; e < 4096; e += 256) {
    int r = e >> 6, k = e & 63;
    float v = (k < 51) ? x[(b * 80 + r) * 51 + k] : 0.f;
    int idx = SWZ6(r, k);
    unsigned short h = f2bf(v);
    b1H[idx] = h; b1L[idx] = f2bf(v - bf2f(h));
  }
  // ---- stage An + W1a ----
  for (int q = t; q < 512; q += 256) {
    int r = q >> 3, c = q & 7;
    int dst = (r << 6) + ((c ^ (r & 7)) << 3);
    int src = (r << 6) + (c << 3);
    *(bf16x8*)(anH + dst) = *(const bf16x8*)(gAnH + src);
    *(bf16x8*)(anL + dst) = *(const bf16x8*)(gAnL + src);
    *(bf16x8*)(wH + dst)  = *(const bf16x8*)(gaH + src);
    *(bf16x8*)(wL + dst)  = *(const bf16x8*)(gaL + src);
  }
  __syncthreads();

  // ---- GEMM1: T1 = sg1 @ W1a^T -> b2 [col][k] ----
  {
    f32x4 acc[4];
#pragma unroll
    for (int n = 0; n < 4; ++n) acc[n] = (f32x4){0.f, 0.f, 0.f, 0.f};
#pragma unroll
    for (int kb8 = 0; kb8 < 8; kb8 += 4) {
      int ach = ((quad + kb8) ^ (m16 & 7)) << 3;
      bf16x8 aH = *(const bf16x8*)(b1H + (arow << 6) + ach);
      bf16x8 aL = *(const bf16x8*)(b1L + (arow << 6) + ach);
#pragma unroll
      for (int n = 0; n < 4; ++n) {
        const int col = n * 16 + m16;
        int boff = (col << 6) + ach;
        bf16x8 bH = *(const bf16x8*)(wH + boff);
        bf16x8 bL = *(const bf16x8*)(wL + boff);
        acc[n] = __builtin_amdgcn_mfma_f32_16x16x32_bf16(aH, bH, acc[n], 0, 0, 0);
        acc[n] = __builtin_amdgcn_mfma_f32_16x16x32_bf16(aH, bL, acc[n], 0, 0, 0);
        acc[n] = __builtin_amdgcn_mfma_f32_16x16x32_bf16(aL, bH, acc[n], 0, 0, 0);
      }
    }
    // T1[k=row][n=col] -> store [col][k], packed 4-k (8B) per store
    const int kb = row0 + quad * 4;
#pragma unroll
    for (int n = 0; n < 4; ++n) {
      const int col = n * 16 + m16;
      int idx = (col << 6) + (((((kb >> 3) ^ (col & 7)) << 3)) | (kb & 7));
      s16x4 hv, lv;
#pragma unroll
      for (int r = 0; r < 4; ++r) {
        float v = acc[n][r];
        unsigned short h = f2bf(v);
        hv[r] = (short)h; lv[r] = (short)f2bf(v - bf2f(h));
      }
      *(s16x4*)(b2H + idx) = hv; *(s16x4*)(b2L + idx) = lv;
    }
  }
  __syncthreads();   // T1 visible; W1a reads done

  // ---- stage W1b (overwrite wbuf) + GEMM2: P = relu(An @ T1) ----
  for (int q = t; q < 512; q += 256) {
    int r = q >> 3, c = q & 7;
    int dst = (r << 6) + ((c ^ (r & 7)) << 3);
    int src = (r << 6) + (c << 3);
    *(bf16x8*)(wH + dst) = *(const bf16x8*)(gbH + src);
    *(bf16x8*)(wL + dst) = *(const bf16x8*)(gbL + src);
  }
  f32x4 accP[4];
  {
#pragma unroll
    for (int n = 0; n < 4; ++n) accP[n] = (f32x4){0.f, 0.f, 0.f, 0.f};
#pragma unroll
    for (int kb8 = 0; kb8 < 8; kb8 += 4) {
      int ach = ((quad + kb8) ^ (m16 & 7)) << 3;
      bf16x8 aH = *(const bf16x8*)(anH + (arow << 6) + ach);
      bf16x8 aL = *(const bf16x8*)(anL + (arow << 6) + ach);
#pragma unroll
      for (int n = 0; n < 4; ++n) {
        const int col = n * 16 + m16;
        int boff = (col << 6) + ach;
        bf16x8 bH = *(const bf16x8*)(b2H + boff);
        bf16x8 bL = *(const bf16x8*)(b2L + boff);
        accP[n] = __builtin_amdgcn_mfma_f32_16x16x32_bf16(aH, bH, accP[n], 0, 0, 0);
        accP[n] = __builtin_amdgcn_mfma_f32_16x16x32_bf16(aH, bL, accP[n], 0, 0, 0);
        accP[n] = __builtin_amdgcn_mfma_f32_16x16x32_bf16(aL, bH, accP[n], 0, 0, 0);
      }
    }
  }
  __syncthreads();   // all T1 reads done before overwriting b2 with P
  {
    const int kb = row0 + quad * 4;
#pragma unroll
    for (int n = 0; n < 4; ++n) {
      const int col = n * 16 + m16;
      int idx = (col << 6) + (((((kb >> 3) ^ (col & 7)) << 3)) | (kb & 7));
      s16x4 hv, lv;
#pragma unroll
      for (int r = 0; r < 4; ++r) {
        float v = accP[n][r]; v = v > 0.f ? v : 0.f;   // relu
        unsigned short h = f2bf(v);
        hv[r] = (short)h; lv[r] = (short)f2bf(v - bf2f(h));
      }
      *(s16x4*)(b2H + idx) = hv; *(s16x4*)(b2L + idx) = lv;
    }
  }
  __syncthreads();   // P visible

  // ---- GEMM3: Q = An @ P -> b1 [row][k] (own rows) ----
  {
    f32x4 acc[4];
#pragma unroll
    for (int n = 0; n < 4; ++n) acc[n] = (f32x4){0.f, 0.f, 0.f, 0.f};
#pragma unroll
    for (int kb8 = 0; kb8 < 8; kb8 += 4) {
      int ach = ((quad + kb8) ^ (m16 & 7)) << 3;
      bf16x8 aH = *(const bf16x8*)(anH + (arow << 6) + ach);
      bf16x8 aL = *(const bf16x8*)(anL + (arow << 6) + ach);
#pragma unroll
      for (int n = 0; n < 4; ++n) {
        const int col = n * 16 + m16;
        int boff = (col << 6) + ach;
        bf16x8 bH = *(const bf16x8*)(b2H + boff);
        bf16x8 bL = *(const bf16x8*)(b2L + boff);
        acc[n] = __builtin_amdgcn_mfma_f32_16x16x32_bf16(aH, bH, acc[n], 0, 0, 0);
        acc[n] = __builtin_amdgcn_mfma_f32_16x16x32_bf16(aH, bL, acc[n], 0, 0, 0);
        acc[n] = __builtin_amdgcn_mfma_f32_16x16x32_bf16(aL, bH, acc[n], 0, 0, 0);
      }
    }
    // Q[row][col] row-major into b1 (rows are wave-private)
#pragma unroll
    for (int n = 0; n < 4; ++n) {
      const int col = n * 16 + m16;
#pragma unroll
      for (int r = 0; r < 4; ++r) {
        int row = row0 + quad * 4 + r;
        int idx = SWZ6(row, col);
        float v = acc[n][r];
        unsigned short h = f2bf(v);
        b1H[idx] = h; b1L[idx] = f2bf(v - bf2f(h));
      }
    }
  }
  // no barrier: GEMM4 A-reads are this wave's own rows, in-order LDS per wave

  // ---- GEMM4: x1 = Q @ W1b^T -> global ----
  {
    f32x4 acc[4];
#pragma unroll
    for (int n = 0; n < 4; ++n) acc[n] = (f32x4){0.f, 0.f, 0.f, 0.f};
#pragma unroll
    for (int kb8 = 0; kb8 < 8; kb8 += 4) {
      int ach = ((quad + kb8) ^ (m16 & 7)) << 3;
      bf16x8 aH = *(const bf16x8*)(b1H + (arow << 6) + ach);
      bf16x8 aL = *(const bf16x8*)(b1L + (arow << 6) + ach);
#pragma unroll
      for (int n = 0; n < 4; ++n) {
        const int col = n * 16 + m16;
        int boff = (col << 6) + ach;
        bf16x8 bH = *(const bf16x8*)(wH + boff);
        bf16x8 bL = *(const bf16x8*)(wL + boff);
        acc[n] = __builtin_amdgcn_mfma_f32_16x16x32_bf16(aH, bH, acc[n], 0, 0, 0);
        acc[n] = __builtin_amdgcn_mfma_f32_16x16x32_bf16(aH, bL, acc[n], 0, 0, 0);
        acc[n] = __builtin_amdgcn_mfma_f32_16x16x32_bf16(aL, bH, acc[n], 0, 0, 0);
      }
    }
#pragma unroll
    for (int n = 0; n < 4; ++n) {
      const int col = n * 16 + m16;
      if (col < 50) {
#pragma unroll
        for (int r = 0; r < 4; ++r) {
          int row = row0 + quad * 4 + r;
          x1[(b * 64 + row) * 50 + col] = acc[n][r];
        }
      }
    }
  }
}

// ===========================================================================
// k_q: q decomposition + masked softmax over FUT axis + yh. (unchanged)
// ===========================================================================
__global__ __launch_bounds__(256) void k_q(float* __restrict__ ws)
{
  __shared__ __align__(16) float Xp[64 * 60];
  __shared__ __align__(16) float Xf[16 * 60];
  __shared__ __align__(16) float Th[52 * 60];
  __shared__ __align__(16) float U[64 * 60];
  __shared__ float V[16 * 60];
  __shared__ float yv[64];
  __shared__ float sv[64];
  __shared__ float rv[16];
  __shared__ float al[16 * 64];
  __shared__ float mks[16 * 64];
  const int t = threadIdx.x, b = blockIdx.x;
  const float* x = ws + OFF_X;
  const float* x1 = ws + OFF_X1;
  const float* th = ws + OFF_TH;
  const float* mk = ws + OFF_MK;
  const float sc = (ws + OFF_SC)[0];
  float* yh = ws + OFF_YH;

  for (int e = t; e < 64 * 60; e += 256) {
    int r = e / 60, c = e - r * 60;
    Xp[e] = (c < 50) ? x1[(b * 64 + r) * 50 + c] : 0.f;
  }
  for (int e = t; e < 16 * 60; e += 256) {
    int r = e / 60, c = e - r * 60;
    Xf[e] = (c < 50) ? x[(b * 80 + 64 + r) * 51 + c] : 0.f;
  }
  for (int e = t; e < 52 * 60; e += 256) {
    int r = e / 60, c = e - r * 60;
    Th[e] = (r < 50 && c < 50) ? th[r * 50 + c] : 0.f;
  }
  for (int e = t; e < 1024; e += 256) mks[e] = mk[e];
  if (t < 64) yv[t] = x[(b * 80 + t) * 51 + 50];
  __syncthreads();

  {
    const int r0 = (t >> 4) * 4;
    int o0 = (t & 15) * 4; if (o0 > 56) o0 = 56;
    float acc[4][4] = {{0.f}};
    for (int kk = 0; kk < 52; kk += 4) {
      float4 a[4], w[4];
#pragma unroll
      for (int i = 0; i < 4; ++i) a[i] = *(const float4*)(Xp + (r0 + i) * 60 + kk);
#pragma unroll
      for (int q = 0; q < 4; ++q) w[q] = *(const float4*)(Th + (kk + q) * 60 + o0);
#pragma unroll
      for (int i = 0; i < 4; ++i) {
        const float ak[4] = {a[i].x, a[i].y, a[i].z, a[i].w};
#pragma unroll
        for (int q = 0; q < 4; ++q) {
          acc[i][0] += ak[q] * w[q].x; acc[i][1] += ak[q] * w[q].y;
          acc[i][2] += ak[q] * w[q].z; acc[i][3] += ak[q] * w[q].w;
        }
      }
    }
#pragma unroll
    for (int i = 0; i < 4; ++i)
      *(float4*)(U + (r0 + i) * 60 + o0) = make_float4(acc[i][0], acc[i][1], acc[i][2], acc[i][3]);
    const int jr = t >> 4;
    float accv[4] = {0.f, 0.f, 0.f, 0.f};
    for (int k = 0; k < 50; ++k) {
      float a = Xf[jr * 60 + k];
#pragma unroll
      for (int j = 0; j < 4; ++j) accv[j] += a * Th[k * 60 + o0 + j];
    }
#pragma unroll
    for (int j = 0; j < 4; ++j) V[jr * 60 + o0 + j] = accv[j];
  }
  __syncthreads();
  if (t < 64) {
    float s = 0.f;
    for (int k = 0; k < 50; ++k) s += U[t * 60 + k] * Xp[t * 60 + k];
    sv[t] = s;
  } else if (t < 80) {
    int j = t - 64; float s = 0.f;
    for (int k = 0; k < 50; ++k) s += V[j * 60 + k] * Xf[j * 60 + k];
    rv[j] = s;
  }
  __syncthreads();
  {
    const int i = t & 63;
    const int j0 = (t >> 6) * 4;
#pragma unroll
    for (int jj = 0; jj < 4; ++jj) {
      int j = j0 + jj;
      float d = 0.f;
      for (int kk = 0; kk < 52; kk += 4) {
        float4 u = *(const float4*)(U + i * 60 + kk);
        float4 f = *(const float4*)(Xf + j * 60 + kk);
        d += u.x * f.x + u.y * f.y + u.z * f.z + u.w * f.w;
      }
      al[j * 64 + i] = sc * (sv[i] + rv[j] - 2.f * d);
    }
  }
  __syncthreads();
  if (t < 64) {
    const int i = t;
    float m = -3.4e38f;
#pragma unroll
    for (int j = 0; j < 16; ++j) {
      float v = (mks[j * 64 + i] != 0.f) ? al[j * 64 + i] : NEGBIG;
      m = fmaxf(m, v);
    }
    float s = 0.f; float ex[16];
#pragma unroll
    for (int j = 0; j < 16; ++j) {
      float v = (mks[j * 64 + i] != 0.f) ? al[j * 64 + i] : NEGBIG;
      ex[j] = expf(v - m); s += ex[j];
    }
    float inv = 1.f / s;
#pragma unroll
    for (int j = 0; j < 16; ++j) al[j * 64 + i] = ex[j] * inv;
  }
  __syncthreads();
  if (t < 16) {
    float s = 0.f;
    for (int i = 0; i < 64; ++i) s += al[t * 64 + i] * yv[i];
    yh[b * 16 + t] = s;
  }
}

// ===========================================================================
// k_g2 (unchanged — tiny)
// ===========================================================================
__global__ __launch_bounds__(256) void k_g2(const float* __restrict__ wg2b,
                                            float* __restrict__ ws,
                                            float* __restrict__ out)
{
  __shared__ float X2[16 * 53];
  __shared__ __align__(16) float G[16 * 68];
  __shared__ float P[16 * 68];
  __shared__ float A22[256];
  __shared__ float wb[64];
  __shared__ float z[16];
  const int t = threadIdx.x, b = blockIdx.x;
  const float* x = ws + OFF_X;
  const float* yh = ws + OFF_YH;
  const float* an22 = ws + OFF_AN22;
  const float* g2at = ws + OFF_G2AT;

  for (int e = t; e < 16 * 51; e += 256) {
    int r = e / 51, c = e % 51;
    X2[r * 53 + c] = (c < 50) ? x[(b * 80 + 64 + r) * 51 + c] : yh[b * 16 + r];
  }
  for (int e = t; e < 256; e += 256) A22[e] = an22[e];
  if (t < 64) wb[t] = wg2b[t];
  __syncthreads();
  {
    const int j = t >> 4, o0 = (t & 15) * 4;
    float acc[4] = {0.f, 0.f, 0.f, 0.f};
    for (int k = 0; k < 51; ++k) {
      float a = X2[j * 53 + k];
      const float4 w = *(const float4*)(g2at + k * 64 + o0);
      acc[0] += a * w.x; acc[1] += a * w.y; acc[2] += a * w.z; acc[3] += a * w.w;
    }
#pragma unroll
    for (int q2 = 0; q2 < 4; ++q2) G[j * 68 + o0 + q2] = acc[q2];
  }
  __syncthreads();
  {
    const int j = t >> 4, o0 = (t & 15) * 4;
    float acc[4] = {0.f, 0.f, 0.f, 0.f};
    for (int k = 0; k < 16; ++k) {
      float a = A22[j * 16 + k];
      const float4 g4 = *(const float4*)(G + k * 68 + o0);
      acc[0] += a * g4.x; acc[1] += a * g4.y; acc[2] += a * g4.z; acc[3] += a * g4.w;
    }
#pragma unroll
    for (int q2 = 0; q2 < 4; ++q2) {
      float v = acc[q2];
      P[j * 68 + o0 + q2] = v > 0.f ? v : 0.f;
    }
  }
  __syncthreads();
  if (t < 16) {
    float s = 0.f;
    for (int o = 0; o < 64; ++o) s += P[t * 68 + o] * wb[o];
    z[t] = s;
  }
  __syncthreads();
  if (t < 16) {
    float s = 0.f;
#pragma unroll
    for (int k = 0; k < 16; ++k) s += A22[t * 16 + k] * z[k];
    out[OUT_OUT + b * 16 + t] = s;
  }
}

// ===========================================================================
// k_dist: pairwise distances; stride 60, float4 k-loop, coalesced stores.
// ===========================================================================
__global__ __launch_bounds__(256) void k_dist(float* __restrict__ ws,
                                              float* __restrict__ out)
{
  __shared__ __align__(16) float Xc[80 * 60];
  __shared__ float sq[80];
  const int t = threadIdx.x, b = blockIdx.x;
  const float* x = ws + OFF_X;
  const float* yh = ws + OFF_YH;
  float* dist = out + OUT_DIST + b * 6400;

  for (int e = t; e < 80 * 60; e += 256) {
    int n = e / 60, c = e - n * 60;
    float v = 0.f;
    if (c < 50)       v = x[(b * 80 + n) * 51 + c];
    else if (c == 50) v = (n < 64) ? x[(b * 80 + n) * 51 + 50] : yh[b * 16 + (n - 64)];
    Xc[e] = v;
  }
  __syncthreads();
  if (t < 80) {
    float s = 0.f;
    for (int c = 0; c < 51; ++c) { float v = Xc[t * 60 + c]; s += v * v; }
    sq[t] = s;
  }
  __syncthreads();
  const int n0 = (t >> 4) * 5;
  const int mc = t & 15;
  float acc[5][5] = {{0.f}};
  for (int kk = 0; kk < 52; kk += 4) {
    float4 a[5], bv[5];
#pragma unroll
    for (int i = 0; i < 5; ++i) a[i] = *(const float4*)(Xc + (n0 + i) * 60 + kk);
#pragma unroll
    for (int j = 0; j < 5; ++j) bv[j] = *(const float4*)(Xc + (mc + 16 * j) * 60 + kk);
#pragma unroll
    for (int i = 0; i < 5; ++i) {
#pragma unroll
      for (int j = 0; j < 5; ++j) {
        acc[i][j] += a[i].x * bv[j].x + a[i].y * bv[j].y +
                     a[i].z * bv[j].z + a[i].w * bv[j].w;
      }
    }
  }
#pragma unroll
  for (int i = 0; i < 5; ++i) {
#pragma unroll
    for (int j = 0; j < 5; ++j) {
      int m = mc + 16 * j;
      float d2 = sq[n0 + i] + sq[m] - 2.f * acc[i][j];
      d2 = d2 > 0.f ? d2 : 0.f;
      dist[(n0 + i) * 80 + m] = d2 > 0.f ? sqrtf(d2) : 0.f;
    }
  }
}

// ===========================================================================
extern "C" void kernel_launch(void* const* d_in, const int* in_sizes, int n_in,
                              void* d_out, int out_size, void* d_ws, size_t ws_size,
                              hipStream_t stream)
{
  const float* data = (const float*)d_in[0];
  const float* emb0 = (const float*)d_in[1];
  const float* emb1 = (const float*)d_in[2];
  const float* emb2 = (const float*)d_in[3];
  const float* w1   = (const float*)d_in[4];
  const float* b1   = (const float*)d_in[5];
  const float* w2   = (const float*)d_in[6];
  const float* b2   = (const float*)d_in[7];
  const float* w3   = (const float*)d_in[8];
  const float* b3   = (const float*)d_in[9];
  const float* M    = (const float*)d_in[10];
  const float* wg1a = (const float*)d_in[11];
  const float* wg1b = (const float*)d_in[12];
  const float* Wk   = (const float*)d_in[13];
  const float* smo  = (const float*)d_in[14];
  const float* wg2a = (const float*)d_in[15];
  const float* wg2b = (const float*)d_in[16];
  float* ws  = (float*)d_ws;
  float* out = (float*)d_out;

  k_prep<<<dim3(4),    dim3(256), 0, stream>>>(M, Wk, smo, w1, w2, w3, wg1a, wg1b, wg2a, ws, out);
  k_mlp <<<dim3(1280), dim3(256), 0, stream>>>(data, emb0, emb1, emb2, b1, b2, b3, ws);
  k_g1  <<<dim3(1024), dim3(256), 0, stream>>>(ws);
  k_q   <<<dim3(1024), dim3(256), 0, stream>>>(ws);
  k_g2  <<<dim3(1024), dim3(256), 0, stream>>>(wg2b, ws, out);
  k_dist<<<dim3(1024), dim3(256), 0, stream>>>(ws, out);
}

// Round 5
// 261.638 us; speedup vs baseline: 1.4713x; 1.2121x over previous
//
#include <hip/hip_runtime.h>
#include <math.h>

// ---------------------------------------------------------------------------
// GAT_23613730193923 — round 5: k_q via theta=Wk*Wk^T factorization (MFMA),
// k_g2 merged into k_q, k_dist via MFMA Gram with diagonal-exact sq.
// ---------------------------------------------------------------------------

#define NEGBIG (-1e30f)

// ---- workspace offsets (floats) ----
#define OFF_X     0          // B*80*51 = 4177920
#define OFF_X1    4177920    // B*64*50 = 3276800
#define OFF_YH    7454720    // B*16
#define OFF_A     7471104    // 80*80
#define OFF_AN22  7481600    // 16*16
#define OFF_MK    7484356    // 16*64
#define OFF_GAH   7514692    // W1a hi: 64*64 ushort
#define OFF_GAL   7516740
#define OFF_G2AT  7521156    // 51*64 fp32
#define OFF_SC    7524420    // 1
#define OFF_W1H   7524424    // 128*64 ushort
#define OFF_W1L   7528520
#define OFF_W2H   7532616    // 128*128 ushort
#define OFF_W2L   7540808
#define OFF_W3H   7549000    // 64*128 ushort
#define OFF_W3L   7553096
#define OFF_ANH   7557192    // An11 hi: 64*64 ushort
#define OFF_ANL   7559240
#define OFF_GBH   7561288    // W1b hi: 64*64 ushort
#define OFF_GBL   7563336
#define OFF_WKH   7565384    // Wk^T hi: [h=64][o=64] ushort
#define OFF_WKL   7567432
// end = 7569480 floats ~= 30.3 MB

// ---- output offsets (floats): (out B*16, dist B*6400, A 6400) ----
#define OUT_OUT   0
#define OUT_DIST  16384
#define OUT_A     6569984

typedef __attribute__((ext_vector_type(8))) short bf16x8;
typedef __attribute__((ext_vector_type(4))) short s16x4;
typedef __attribute__((ext_vector_type(4))) float f32x4;

__device__ __forceinline__ unsigned short f2bf(float x) {
  union { float f; unsigned u; } v; v.f = x;
  unsigned r = v.u + 0x7fffu + ((v.u >> 16) & 1u);
  return (unsigned short)(r >> 16);
}
__device__ __forceinline__ float bf2f(unsigned short h) {
  union { unsigned u; float f; } v; v.u = ((unsigned)h) << 16; return v.f;
}
#define SWZ6(r, k) (((r) << 6) + (((((k) >> 3) ^ ((r) & 7)) << 3) | ((k) & 7)))
#define SWZ7(r, k) (((r) << 7) + (((((k) >> 3) ^ ((r) & 7)) << 3) | ((k) & 7)))

// ===========================================================================
// k_prep
// ===========================================================================
__global__ __launch_bounds__(256) void k_prep(
    const float* __restrict__ M, const float* __restrict__ Wk,
    const float* __restrict__ sm,
    const float* __restrict__ w1, const float* __restrict__ w2,
    const float* __restrict__ w3,
    const float* __restrict__ wg1a, const float* __restrict__ wg1b,
    const float* __restrict__ wg2a,
    float* __restrict__ ws, float* __restrict__ out)
{
  __shared__ float Msh[80 * 26];
  __shared__ float Ash[80 * 80];
  __shared__ float d1[64];
  __shared__ float d2s[16];
  const int t = threadIdx.x;

  if (blockIdx.x == 0) {
    for (int e = t; e < 80 * 26; e += 256) Msh[e] = M[e];
    __syncthreads();
    for (int e = t; e < 6400; e += 256) {
      int i = e / 80, j = e % 80;
      float v = 0.f;
      if (j < i) {
        float s = 0.f;
        for (int k = 0; k < 26; ++k) s += Msh[i * 26 + k] * Msh[j * 26 + k];
        v = s > 0.f ? s : 0.f;
      }
      Ash[e] = v;
    }
    __syncthreads();
    if (t > 0 && t < 80) {
      int i = t;
      float m = -3.4e38f;
      for (int j = 0; j < i; ++j) m = fmaxf(m, Ash[i * 80 + j]);
      float s = 0.f;
      for (int j = 0; j < i; ++j) {
        float e = expf(Ash[i * 80 + j] - m);
        Ash[i * 80 + j] = e;
        s += e;
      }
      float inv = 1.f / s;
      for (int j = 0; j < i; ++j) Ash[i * 80 + j] *= inv;
    }
    __syncthreads();
    {
      float* Aws = ws + OFF_A;
      float* Aout = out + OUT_A;
      for (int e = t; e < 6400; e += 256) { Aws[e] = Ash[e]; Aout[e] = Ash[e]; }
    }
    if (t < 64) {
      int c = 0;
      for (int j = 0; j < 64; ++j) if (Ash[t * 80 + j] > 1e-15f) ++c;
      d1[t] = 1.f / sqrtf(1.f + (float)c);
    } else if (t < 80) {
      int i = t - 64; int c = 0;
      for (int j = 0; j < 16; ++j) if (Ash[(64 + i) * 80 + 64 + j] > 1e-15f) ++c;
      d2s[i] = 1.f / sqrtf(1.f + (float)c);
    }
    __syncthreads();
    {
      float* an22 = ws + OFF_AN22;
      unsigned short* anH = (unsigned short*)(ws + OFF_ANH);
      unsigned short* anL = (unsigned short*)(ws + OFF_ANL);
      for (int e = t; e < 4096; e += 256) {
        int i = e >> 6, j = e & 63;
        float v = d1[i] * Ash[i * 80 + j] * d1[j];
        unsigned short h = f2bf(v);
        anH[e] = h; anL[e] = f2bf(v - bf2f(h));
      }
      for (int e = t; e < 256; e += 256) {
        int i = e >> 4, j = e & 15;
        an22[e] = d2s[i] * Ash[(64 + i) * 80 + 64 + j] * d2s[j];
      }
    }
    if (t < 16) {
      float* mk = ws + OFF_MK;
      int j = t;
      float m = -3.4e38f;
      for (int i = 0; i < 64; ++i) {
        float v = Ash[(64 + j) * 80 + i];
        v = (v != 0.f) ? v : NEGBIG;
        m = fmaxf(m, v);
      }
      float s = 0.f;
      for (int i = 0; i < 64; ++i) {
        float v = Ash[(64 + j) * 80 + i];
        v = (v != 0.f) ? v : NEGBIG;
        s += expf(v - m);
      }
      float inv = 1.f / s;
      for (int i = 0; i < 64; ++i) {
        float v = Ash[(64 + j) * 80 + i];
        v = (v != 0.f) ? v : NEGBIG;
        mk[j * 64 + i] = (expf(v - m) * inv >= 0.004f) ? 1.f : 0.f;
      }
    }
  } else if (blockIdx.x == 1) {
    // Wk^T split frag [h=64][o=64] (o>=50 zero)
    unsigned short* wkh = (unsigned short*)(ws + OFF_WKH);
    unsigned short* wkl = (unsigned short*)(ws + OFF_WKL);
    for (int e = t; e < 4096; e += 256) {
      int h = e >> 6, o = e & 63;
      float v = (o < 50) ? Wk[o * 64 + h] : 0.f;
      unsigned short hh = f2bf(v);
      wkh[e] = hh; wkl[e] = f2bf(v - bf2f(hh));
    }
    if (t == 0) {
      float v = sm[0];
      float sig = 1.f / (1.f + expf(-v));
      (ws + OFF_SC)[0] = -0.5f / (sig * 0.01f);
    }
  } else if (blockIdx.x == 2) {
    unsigned short* w1h = (unsigned short*)(ws + OFF_W1H);
    unsigned short* w1l = (unsigned short*)(ws + OFF_W1L);
    for (int e = t; e < 8192; e += 256) {
      int n = e >> 6, k = e & 63;
      float v = (k < 51) ? w1[n * 51 + k] : 0.f;
      unsigned short h = f2bf(v);
      w1h[e] = h; w1l[e] = f2bf(v - bf2f(h));
    }
    unsigned short* w3h = (unsigned short*)(ws + OFF_W3H);
    unsigned short* w3l = (unsigned short*)(ws + OFF_W3L);
    for (int e = t; e < 8192; e += 256) {
      int n = e >> 7, k = e & 127;
      float v = (n < 50) ? w3[n * 128 + k] : 0.f;
      unsigned short h = f2bf(v);
      w3h[e] = h; w3l[e] = f2bf(v - bf2f(h));
    }
    unsigned short* gah = (unsigned short*)(ws + OFF_GAH);
    unsigned short* gal = (unsigned short*)(ws + OFF_GAL);
    for (int e = t; e < 4096; e += 256) {
      int n = e >> 6, k = e & 63;
      float v = (k < 51) ? wg1a[n * 51 + k] : 0.f;
      unsigned short h = f2bf(v);
      gah[e] = h; gal[e] = f2bf(v - bf2f(h));
    }
  } else {
    unsigned short* w2h = (unsigned short*)(ws + OFF_W2H);
    unsigned short* w2l = (unsigned short*)(ws + OFF_W2L);
    for (int e = t; e < 16384; e += 256) {
      int n = e >> 7, k = e & 127;
      float v = w2[n * 128 + k];
      unsigned short h = f2bf(v);
      w2h[e] = h; w2l[e] = f2bf(v - bf2f(h));
    }
    unsigned short* gbh = (unsigned short*)(ws + OFF_GBH);
    unsigned short* gbl = (unsigned short*)(ws + OFF_GBL);
    for (int e = t; e < 4096; e += 256) {
      int n = e >> 6, k = e & 63;
      float v = (n < 50) ? wg1b[n * 64 + k] : 0.f;
      unsigned short h = f2bf(v);
      gbh[e] = h; gbl[e] = f2bf(v - bf2f(h));
    }
    float* g2at = ws + OFF_G2AT;
    for (int e = t; e < 64 * 51; e += 256) { int o = e / 51, k = e % 51; g2at[k * 64 + o] = wg2a[e]; }
  }
}

// ===========================================================================
// k_mlp (unchanged from round 4)
// ===========================================================================
__global__ __launch_bounds__(256) void k_mlp(
    const float* __restrict__ data,
    const float* __restrict__ emb0, const float* __restrict__ emb1,
    const float* __restrict__ emb2,
    const float* __restrict__ b1, const float* __restrict__ b2,
    const float* __restrict__ b3,
    float* __restrict__ ws)
{
  __shared__ __align__(16) unsigned short actH[64 * 128];
  __shared__ __align__(16) unsigned short actL[64 * 128];
  __shared__ __align__(16) unsigned short wbH[8192];
  __shared__ __align__(16) unsigned short wbL[8192];
  const int t = threadIdx.x;
  const int lane = t & 63, wave = t >> 6;
  const int m16 = lane & 15, quad = lane >> 4;
  const int base = blockIdx.x * 64;
  const int row0 = wave * 16;
  const int arow = row0 + m16;
  const unsigned short* w1h = (const unsigned short*)(ws + OFF_W1H);
  const unsigned short* w1l = (const unsigned short*)(ws + OFF_W1L);
  const unsigned short* w2h = (const unsigned short*)(ws + OFF_W2H);
  const unsigned short* w2l = (const unsigned short*)(ws + OFF_W2L);
  const unsigned short* w3h = (const unsigned short*)(ws + OFF_W3H);
  const unsigned short* w3l = (const unsigned short*)(ws + OFF_W3L);
  float* x = ws + OFF_X;

  for (int e = t; e < 4096; e += 256) {
    int r = e >> 6, c = e & 63;
    int g = base + r;
    float v = 0.f;
    if (c < 32)      { int i0 = (int)data[g * 6 + 0]; v = emb0[i0 * 32 + c]; }
    else if (c < 40) { int i1 = (int)data[g * 6 + 1]; v = emb1[i1 * 8 + (c - 32)]; }
    else if (c < 48) { int i2 = (int)data[g * 6 + 2]; v = emb2[i2 * 8 + (c - 40)]; }
    else if (c < 51) { v = data[g * 6 + 3 + (c - 48)]; }
    int idx = SWZ7(r, c);
    unsigned short h = f2bf(v);
    actH[idx] = h; actL[idx] = f2bf(v - bf2f(h));
  }
  for (int q = t; q < 1024; q += 256) {
    int col = q >> 3, c = q & 7;
    int dst = (col << 6) + ((c ^ (col & 7)) << 3);
    *(bf16x8*)(wbH + dst) = *(const bf16x8*)(w1h + (col << 6) + (c << 3));
    *(bf16x8*)(wbL + dst) = *(const bf16x8*)(w1l + (col << 6) + (c << 3));
  }
  __syncthreads();

  f32x4 acc2[8];
  {
    f32x4 acc[8];
#pragma unroll
    for (int n = 0; n < 8; ++n) acc[n] = (f32x4){0.f, 0.f, 0.f, 0.f};
#pragma unroll
    for (int kb8 = 0; kb8 < 8; kb8 += 4) {
      int ach = ((quad + kb8) ^ (m16 & 7)) << 3;
      bf16x8 aH = *(const bf16x8*)(actH + (arow << 7) + ach);
      bf16x8 aL = *(const bf16x8*)(actL + (arow << 7) + ach);
#pragma unroll
      for (int n = 0; n < 8; ++n) {
        const int col = n * 16 + m16;
        int boff = (col << 6) + ach;
        bf16x8 bH = *(const bf16x8*)(wbH + boff);
        bf16x8 bL = *(const bf16x8*)(wbL + boff);
        acc[n] = __builtin_amdgcn_mfma_f32_16x16x32_bf16(aH, bH, acc[n], 0, 0, 0);
        acc[n] = __builtin_amdgcn_mfma_f32_16x16x32_bf16(aH, bL, acc[n], 0, 0, 0);
        acc[n] = __builtin_amdgcn_mfma_f32_16x16x32_bf16(aL, bH, acc[n], 0, 0, 0);
      }
    }
#pragma unroll
    for (int n = 0; n < 8; ++n) {
      const int col = n * 16 + m16;
      const float bias = b1[col];
#pragma unroll
      for (int r = 0; r < 4; ++r) {
        float v = acc[n][r] + bias; v = v > 0.f ? v : 0.f;
        int row = row0 + quad * 4 + r;
        int idx = SWZ7(row, col);
        unsigned short h = f2bf(v);
        actH[idx] = h; actL[idx] = f2bf(v - bf2f(h));
      }
    }
  }

#pragma unroll
  for (int n = 0; n < 8; ++n) acc2[n] = (f32x4){0.f, 0.f, 0.f, 0.f};
  for (int h2 = 0; h2 < 2; ++h2) {
    __syncthreads();
    for (int q = t; q < 1024; q += 256) {
      int coll = q >> 4, c = q & 15;
      int srcc = (((h2 << 6) + coll) << 7) + (c << 3);
      int dst = (coll << 7) + ((c ^ (coll & 7)) << 3);
      *(bf16x8*)(wbH + dst) = *(const bf16x8*)(w2h + srcc);
      *(bf16x8*)(wbL + dst) = *(const bf16x8*)(w2l + srcc);
    }
    __syncthreads();
#pragma unroll
    for (int kb8 = 0; kb8 < 16; kb8 += 4) {
      int ach = ((quad + kb8) ^ (m16 & 7)) << 3;
      bf16x8 aH = *(const bf16x8*)(actH + (arow << 7) + ach);
      bf16x8 aL = *(const bf16x8*)(actL + (arow << 7) + ach);
#pragma unroll
      for (int n = 0; n < 4; ++n) {
        const int col = n * 16 + m16;
        int boff = (col << 7) + ach;
        bf16x8 bH = *(const bf16x8*)(wbH + boff);
        bf16x8 bL = *(const bf16x8*)(wbL + boff);
        f32x4 a = acc2[h2 * 4 + n];
        a = __builtin_amdgcn_mfma_f32_16x16x32_bf16(aH, bH, a, 0, 0, 0);
        a = __builtin_amdgcn_mfma_f32_16x16x32_bf16(aH, bL, a, 0, 0, 0);
        a = __builtin_amdgcn_mfma_f32_16x16x32_bf16(aL, bH, a, 0, 0, 0);
        acc2[h2 * 4 + n] = a;
      }
    }
  }
#pragma unroll
  for (int hh = 0; hh < 2; ++hh) {
#pragma unroll
    for (int n = 0; n < 4; ++n) {
      const int col = hh * 64 + n * 16 + m16;
      const float bias = b2[col];
#pragma unroll
      for (int r = 0; r < 4; ++r) {
        float v = acc2[hh * 4 + n][r] + bias; v = v > 0.f ? v : 0.f;
        int row = row0 + quad * 4 + r;
        int idx = SWZ7(row, col);
        unsigned short h = f2bf(v);
        actH[idx] = h; actL[idx] = f2bf(v - bf2f(h));
      }
    }
  }

  __syncthreads();
  for (int q = t; q < 1024; q += 256) {
    int coll = q >> 4, c = q & 15;
    int dst = (coll << 7) + ((c ^ (coll & 7)) << 3);
    *(bf16x8*)(wbH + dst) = *(const bf16x8*)(w3h + (coll << 7) + (c << 3));
    *(bf16x8*)(wbL + dst) = *(const bf16x8*)(w3l + (coll << 7) + (c << 3));
  }
  __syncthreads();
  {
    f32x4 acc[4];
#pragma unroll
    for (int n = 0; n < 4; ++n) acc[n] = (f32x4){0.f, 0.f, 0.f, 0.f};
#pragma unroll
    for (int kb8 = 0; kb8 < 16; kb8 += 4) {
      int ach = ((quad + kb8) ^ (m16 & 7)) << 3;
      bf16x8 aH = *(const bf16x8*)(actH + (arow << 7) + ach);
      bf16x8 aL = *(const bf16x8*)(actL + (arow << 7) + ach);
#pragma unroll
      for (int n = 0; n < 4; ++n) {
        const int col = n * 16 + m16;
        int boff = (col << 7) + ach;
        bf16x8 bH = *(const bf16x8*)(wbH + boff);
        bf16x8 bL = *(const bf16x8*)(wbL + boff);
        acc[n] = __builtin_amdgcn_mfma_f32_16x16x32_bf16(aH, bH, acc[n], 0, 0, 0);
        acc[n] = __builtin_amdgcn_mfma_f32_16x16x32_bf16(aH, bL, acc[n], 0, 0, 0);
        acc[n] = __builtin_amdgcn_mfma_f32_16x16x32_bf16(aL, bH, acc[n], 0, 0, 0);
      }
    }
#pragma unroll
    for (int n = 0; n < 4; ++n) {
      const int col = n * 16 + m16;
      if (col < 50) {
        const float bias = b3[col];
#pragma unroll
        for (int r = 0; r < 4; ++r) {
          int row = row0 + quad * 4 + r;
          x[(base + row) * 51 + col] = acc[n][r] + bias;
        }
      }
    }
  }
  if (t < 64) x[(base + t) * 51 + 50] = data[(base + t) * 6 + 5];
}

// ===========================================================================
// k_g1 (unchanged from round 4)
// ===========================================================================
__global__ __launch_bounds__(256) void k_g1(float* __restrict__ ws)
{
  __shared__ __align__(16) unsigned short b1H[4096], b1L[4096];
  __shared__ __align__(16) unsigned short b2H[4096], b2L[4096];
  __shared__ __align__(16) unsigned short anH[4096], anL[4096];
  __shared__ __align__(16) unsigned short wH[4096],  wL[4096];
  const int t = threadIdx.x, b = blockIdx.x;
  const int lane = t & 63, wave = t >> 6;
  const int m16 = lane & 15, quad = lane >> 4;
  const int row0 = wave * 16;
  const int arow = row0 + m16;
  const float* x = ws + OFF_X;
  const unsigned short* gAnH = (const unsigned short*)(ws + OFF_ANH);
  const unsigned short* gAnL = (const unsigned short*)(ws + OFF_ANL);
  const unsigned short* gaH = (const unsigned short*)(ws + OFF_GAH);
  const unsigned short* gaL = (const unsigned short*)(ws + OFF_GAL);
  const unsigned short* gbH = (const unsigned short*)(ws + OFF_GBH);
  const unsigned short* gbL = (const unsigned short*)(ws + OFF_GBL);
  float* x1 = ws + OFF_X1;

  for (int e = t; e < 4096; e += 256) {
    int r = e >> 6, k = e & 63;
    float v = (k < 51) ? x[(b * 80 + r) * 51 + k] : 0.f;
    int idx = SWZ6(r, k);
    unsigned short h = f2bf(v);
    b1H[idx] = h; b1L[idx] = f2bf(v - bf2f(h));
  }
  for (int q = t; q < 512; q += 256) {
    int r = q >> 3, c = q & 7;
    int dst = (r << 6) + ((c ^ (r & 7)) << 3);
    int src = (r << 6) + (c << 3);
    *(bf16x8*)(anH + dst) = *(const bf16x8*)(gAnH + src);
    *(bf16x8*)(anL + dst) = *(const bf16x8*)(gAnL + src);
    *(bf16x8*)(wH + dst)  = *(const bf16x8*)(gaH + src);
    *(bf16x8*)(wL + dst)  = *(const bf16x8*)(gaL + src);
  }
  __syncthreads();

  {
    f32x4 acc[4];
#pragma unroll
    for (int n = 0; n < 4; ++n) acc[n] = (f32x4){0.f, 0.f, 0.f, 0.f};
#pragma unroll
    for (int kb8 = 0; kb8 < 8; kb8 += 4) {
      int ach = ((quad + kb8) ^ (m16 & 7)) << 3;
      bf16x8 aH = *(const bf16x8*)(b1H + (arow << 6) + ach);
      bf16x8 aL = *(const bf16x8*)(b1L + (arow << 6) + ach);
#pragma unroll
      for (int n = 0; n < 4; ++n) {
        const int col = n * 16 + m16;
        int boff = (col << 6) + ach;
        bf16x8 bH = *(const bf16x8*)(wH + boff);
        bf16x8 bL = *(const bf16x8*)(wL + boff);
        acc[n] = __builtin_amdgcn_mfma_f32_16x16x32_bf16(aH, bH, acc[n], 0, 0, 0);
        acc[n] = __builtin_amdgcn_mfma_f32_16x16x32_bf16(aH, bL, acc[n], 0, 0, 0);
        acc[n] = __builtin_amdgcn_mfma_f32_16x16x32_bf16(aL, bH, acc[n], 0, 0, 0);
      }
    }
    const int kb = row0 + quad * 4;
#pragma unroll
    for (int n = 0; n < 4; ++n) {
      const int col = n * 16 + m16;
      int idx = (col << 6) + (((((kb >> 3) ^ (col & 7)) << 3)) | (kb & 7));
      s16x4 hv, lv;
#pragma unroll
      for (int r = 0; r < 4; ++r) {
        float v = acc[n][r];
        unsigned short h = f2bf(v);
        hv[r] = (short)h; lv[r] = (short)f2bf(v - bf2f(h));
      }
      *(s16x4*)(b2H + idx) = hv; *(s16x4*)(b2L + idx) = lv;
    }
  }
  __syncthreads();

  for (int q = t; q < 512; q += 256) {
    int r = q >> 3, c = q & 7;
    int dst = (r << 6) + ((c ^ (r & 7)) << 3);
    int src = (r << 6) + (c << 3);
    *(bf16x8*)(wH + dst) = *(const bf16x8*)(gbH + src);
    *(bf16x8*)(wL + dst) = *(const bf16x8*)(gbL + src);
  }
  f32x4 accP[4];
  {
#pragma unroll
    for (int n = 0; n < 4; ++n) accP[n] = (f32x4){0.f, 0.f, 0.f, 0.f};
#pragma unroll
    for (int kb8 = 0; kb8 < 8; kb8 += 4) {
      int ach = ((quad + kb8) ^ (m16 & 7)) << 3;
      bf16x8 aH = *(const bf16x8*)(anH + (arow << 6) + ach);
      bf16x8 aL = *(const bf16x8*)(anL + (arow << 6) + ach);
#pragma unroll
      for (int n = 0; n < 4; ++n) {
        const int col = n * 16 + m16;
        int boff = (col << 6) + ach;
        bf16x8 bH = *(const bf16x8*)(b2H + boff);
        bf16x8 bL = *(const bf16x8*)(b2L + boff);
        accP[n] = __builtin_amdgcn_mfma_f32_16x16x32_bf16(aH, bH, accP[n], 0, 0, 0);
        accP[n] = __builtin_amdgcn_mfma_f32_16x16x32_bf16(aH, bL, accP[n], 0, 0, 0);
        accP[n] = __builtin_amdgcn_mfma_f32_16x16x32_bf16(aL, bH, accP[n], 0, 0, 0);
      }
    }
  }
  __syncthreads();
  {
    const int kb = row0 + quad * 4;
#pragma unroll
    for (int n = 0; n < 4; ++n) {
      const int col = n * 16 + m16;
      int idx = (col << 6) + (((((kb >> 3) ^ (col & 7)) << 3)) | (kb & 7));
      s16x4 hv, lv;
#pragma unroll
      for (int r = 0; r < 4; ++r) {
        float v = accP[n][r]; v = v > 0.f ? v : 0.f;
        unsigned short h = f2bf(v);
        hv[r] = (short)h; lv[r] = (short)f2bf(v - bf2f(h));
      }
      *(s16x4*)(b2H + idx) = hv; *(s16x4*)(b2L + idx) = lv;
    }
  }
  __syncthreads();

  {
    f32x4 acc[4];
#pragma unroll
    for (int n = 0; n < 4; ++n) acc[n] = (f32x4){0.f, 0.f, 0.f, 0.f};
#pragma unroll
    for (int kb8 = 0; kb8 < 8; kb8 += 4) {
      int ach = ((quad + kb8) ^ (m16 & 7)) << 3;
      bf16x8 aH = *(const bf16x8*)(anH + (arow << 6) + ach);
      bf16x8 aL = *(const bf16x8*)(anL + (arow << 6) + ach);
#pragma unroll
      for (int n = 0; n < 4; ++n) {
        const int col = n * 16 + m16;
        int boff = (col << 6) + ach;
        bf16x8 bH = *(const bf16x8*)(b2H + boff);
        bf16x8 bL = *(const bf16x8*)(b2L + boff);
        acc[n] = __builtin_amdgcn_mfma_f32_16x16x32_bf16(aH, bH, acc[n], 0, 0, 0);
        acc[n] = __builtin_amdgcn_mfma_f32_16x16x32_bf16(aH, bL, acc[n], 0, 0, 0);
        acc[n] = __builtin_amdgcn_mfma_f32_16x16x32_bf16(aL, bH, acc[n], 0, 0, 0);
      }
    }
#pragma unroll
    for (int n = 0; n < 4; ++n) {
      const int col = n * 16 + m16;
#pragma unroll
      for (int r = 0; r < 4; ++r) {
        int row = row0 + quad * 4 + r;
        int idx = SWZ6(row, col);
        float v = acc[n][r];
        unsigned short h = f2bf(v);
        b1H[idx] = h; b1L[idx] = f2bf(v - bf2f(h));
      }
    }
  }

  {
    f32x4 acc[4];
#pragma unroll
    for (int n = 0; n < 4; ++n) acc[n] = (f32x4){0.f, 0.f, 0.f, 0.f};
#pragma unroll
    for (int kb8 = 0; kb8 < 8; kb8 += 4) {
      int ach = ((quad + kb8) ^ (m16 & 7)) << 3;
      bf16x8 aH = *(const bf16x8*)(b1H + (arow << 6) + ach);
      bf16x8 aL = *(const bf16x8*)(b1L + (arow << 6) + ach);
#pragma unroll
      for (int n = 0; n < 4; ++n) {
        const int col = n * 16 + m16;
        int boff = (col << 6) + ach;
        bf16x8 bH = *(const bf16x8*)(wH + boff);
        bf16x8 bL = *(const bf16x8*)(wL + boff);
        acc[n] = __builtin_amdgcn_mfma_f32_16x16x32_bf16(aH, bH, acc[n], 0, 0, 0);
        acc[n] = __builtin_amdgcn_mfma_f32_16x16x32_bf16(aH, bL, acc[n], 0, 0, 0);
        acc[n] = __builtin_amdgcn_mfma_f32_16x16x32_bf16(aL, bH, acc[n], 0, 0, 0);
      }
    }
#pragma unroll
    for (int n = 0; n < 4; ++n) {
      const int col = n * 16 + m16;
      if (col < 50) {
#pragma unroll
        for (int r = 0; r < 4; ++r) {
          int row = row0 + quad * 4 + r;
          x1[(b * 64 + row) * 50 + col] = acc[n][r];
        }
      }
    }
  }
}

// ===========================================================================
// k_q v2: q via Zp=Xp@Wk, Zf=Xf@Wk, cross=Zp@Zf^T (split-bf16 MFMA),
// masked softmax over FUT, yh, then fused g2 -> out. 1 batch/block.
// ===========================================================================
__global__ __launch_bounds__(256) void k_q(const float* __restrict__ wg2b,
                                           float* __restrict__ ws,
                                           float* __restrict__ out)
{
  __shared__ __align__(16) unsigned short zH[4096], zL[4096];   // Xp -> Zp
  __shared__ __align__(16) unsigned char bufB[16384];           // WkT | g2 scratch
  __shared__ __align__(16) unsigned short xfH[1024], xfL[1024]; // Xf split
  __shared__ __align__(16) unsigned short zfH[1024], zfL[1024]; // Zf split
  __shared__ float al[64 * 17];
  __shared__ float spP[64 * 17];
  __shared__ float sp[64], sf[16], yv[64], yhs[16];
  const int t = threadIdx.x, b = blockIdx.x;
  const int lane = t & 63, wave = t >> 6;
  const int m16 = lane & 15, quad = lane >> 4;
  const int row0 = wave * 16;
  const int arow = row0 + m16;
  const float* x = ws + OFF_X;
  const float* x1 = ws + OFF_X1;
  const float* mk = ws + OFF_MK;
  const float* an22 = ws + OFF_AN22;
  const float* g2at = ws + OFF_G2AT;
  const float sc = (ws + OFF_SC)[0];
  float* yh = ws + OFF_YH;

  unsigned short* wkH = (unsigned short*)bufB;
  unsigned short* wkL = wkH + 4096;

  // ---- stage Xp, Xf, WkT, y ----
  for (int e = t; e < 4096; e += 256) {
    int r = e >> 6, c = e & 63;
    float v = (c < 50) ? x1[(b * 64 + r) * 50 + c] : 0.f;
    int idx = SWZ6(r, c);
    unsigned short h = f2bf(v);
    zH[idx] = h; zL[idx] = f2bf(v - bf2f(h));
  }
  for (int e = t; e < 1024; e += 256) {
    int r = e >> 6, c = e & 63;
    float v = (c < 50) ? x[(b * 80 + 64 + r) * 51 + c] : 0.f;
    int idx = SWZ6(r, c);
    unsigned short h = f2bf(v);
    xfH[idx] = h; xfL[idx] = f2bf(v - bf2f(h));
  }
  {
    const unsigned short* gwkH = (const unsigned short*)(ws + OFF_WKH);
    const unsigned short* gwkL = (const unsigned short*)(ws + OFF_WKL);
    for (int q = t; q < 512; q += 256) {
      int r = q >> 3, c = q & 7;
      int dst = (r << 6) + ((c ^ (r & 7)) << 3);
      int src = (r << 6) + (c << 3);
      *(bf16x8*)(wkH + dst) = *(const bf16x8*)(gwkH + src);
      *(bf16x8*)(wkL + dst) = *(const bf16x8*)(gwkL + src);
    }
  }
  if (t < 64) yv[t] = x[(b * 80 + t) * 51 + 50];
  __syncthreads();

  // ---- GEMM1: Zp = Xp @ Wk  (64x64, K=64) + sp partials; in-place store ----
  {
    f32x4 acc[4];
#pragma unroll
    for (int n = 0; n < 4; ++n) acc[n] = (f32x4){0.f, 0.f, 0.f, 0.f};
#pragma unroll
    for (int kb8 = 0; kb8 < 8; kb8 += 4) {
      int ach = ((quad + kb8) ^ (m16 & 7)) << 3;
      bf16x8 aH = *(const bf16x8*)(zH + (arow << 6) + ach);
      bf16x8 aL = *(const bf16x8*)(zL + (arow << 6) + ach);
#pragma unroll
      for (int n = 0; n < 4; ++n) {
        const int col = n * 16 + m16;
        int boff = (col << 6) + ach;
        bf16x8 bH = *(const bf16x8*)(wkH + boff);
        bf16x8 bL = *(const bf16x8*)(wkL + boff);
        acc[n] = __builtin_amdgcn_mfma_f32_16x16x32_bf16(aH, bH, acc[n], 0, 0, 0);
        acc[n] = __builtin_amdgcn_mfma_f32_16x16x32_bf16(aH, bL, acc[n], 0, 0, 0);
        acc[n] = __builtin_amdgcn_mfma_f32_16x16x32_bf16(aL, bH, acc[n], 0, 0, 0);
      }
    }
    float s2[4] = {0.f, 0.f, 0.f, 0.f};
#pragma unroll
    for (int n = 0; n < 4; ++n) {
      const int h = n * 16 + m16;
#pragma unroll
      for (int r = 0; r < 4; ++r) {
        float v = acc[n][r];
        s2[r] += v * v;
        int i = row0 + quad * 4 + r;
        int idx = SWZ6(i, h);
        unsigned short hh = f2bf(v);
        zH[idx] = hh; zL[idx] = f2bf(v - bf2f(hh));
      }
    }
#pragma unroll
    for (int r = 0; r < 4; ++r) spP[(row0 + quad * 4 + r) * 17 + m16] = s2[r];
  }
  // ---- Zf = Xf @ Wk (16x64): wave w computes h-frag w ----
  {
    f32x4 af = (f32x4){0.f, 0.f, 0.f, 0.f};
#pragma unroll
    for (int kb8 = 0; kb8 < 8; kb8 += 4) {
      int ach = ((quad + kb8) ^ (m16 & 7)) << 3;
      bf16x8 aH = *(const bf16x8*)(xfH + (m16 << 6) + ach);
      bf16x8 aL = *(const bf16x8*)(xfL + (m16 << 6) + ach);
      const int col = wave * 16 + m16;
      int boff = (col << 6) + ach;
      bf16x8 bH = *(const bf16x8*)(wkH + boff);
      bf16x8 bL = *(const bf16x8*)(wkL + boff);
      af = __builtin_amdgcn_mfma_f32_16x16x32_bf16(aH, bH, af, 0, 0, 0);
      af = __builtin_amdgcn_mfma_f32_16x16x32_bf16(aH, bL, af, 0, 0, 0);
      af = __builtin_amdgcn_mfma_f32_16x16x32_bf16(aL, bH, af, 0, 0, 0);
    }
    const int h = wave * 16 + m16;
#pragma unroll
    for (int r = 0; r < 4; ++r) {
      int j = quad * 4 + r;
      int idx = SWZ6(j, h);
      float v = af[r];
      unsigned short hh = f2bf(v);
      zfH[idx] = hh; zfL[idx] = f2bf(v - bf2f(hh));
    }
  }
  __syncthreads();

  // ---- GEMM2: cross = Zp @ Zf^T (64x16, K=64); sp/sf reductions ----
  f32x4 ac2 = (f32x4){0.f, 0.f, 0.f, 0.f};
#pragma unroll
  for (int kb8 = 0; kb8 < 8; kb8 += 4) {
    int ach = ((quad + kb8) ^ (m16 & 7)) << 3;
    bf16x8 aH = *(const bf16x8*)(zH + (arow << 6) + ach);
    bf16x8 aL = *(const bf16x8*)(zL + (arow << 6) + ach);
    bf16x8 bH = *(const bf16x8*)(zfH + (m16 << 6) + ach);
    bf16x8 bL = *(const bf16x8*)(zfL + (m16 << 6) + ach);
    ac2 = __builtin_amdgcn_mfma_f32_16x16x32_bf16(aH, bH, ac2, 0, 0, 0);
    ac2 = __builtin_amdgcn_mfma_f32_16x16x32_bf16(aH, bL, ac2, 0, 0, 0);
    ac2 = __builtin_amdgcn_mfma_f32_16x16x32_bf16(aL, bH, ac2, 0, 0, 0);
  }
  if (t < 64) {
    float s = 0.f;
#pragma unroll
    for (int m = 0; m < 16; ++m) s += spP[t * 17 + m];
    sp[t] = s;
  } else if (t < 80) {
    int j = t - 64;
    float s = 0.f;
    for (int h = 0; h < 64; ++h) {
      int idx = SWZ6(j, h);
      float v = bf2f(zfH[idx]) + bf2f(zfL[idx]);
      s += v * v;
    }
    sf[j] = s;
  }
  __syncthreads();

  // ---- logits ----
#pragma unroll
  for (int r = 0; r < 4; ++r) {
    int i = row0 + quad * 4 + r;
    al[i * 17 + m16] = sc * (sp[i] + sf[m16] - 2.f * ac2[r]);
  }
  __syncthreads();
  // ---- masked softmax over j per i ----
  if (t < 64) {
    const int i = t;
    float lv[16];
    float m = -3.4e38f;
#pragma unroll
    for (int j = 0; j < 16; ++j) {
      float v = (mk[j * 64 + i] != 0.f) ? al[i * 17 + j] : NEGBIG;
      lv[j] = v;
      m = fmaxf(m, v);
    }
    float s = 0.f;
#pragma unroll
    for (int j = 0; j < 16; ++j) { lv[j] = expf(lv[j] - m); s += lv[j]; }
    float inv = 1.f / s;
#pragma unroll
    for (int j = 0; j < 16; ++j) al[i * 17 + j] = lv[j] * inv;
  }
  __syncthreads();
  if (t < 16) {
    float s = 0.f;
    for (int i = 0; i < 64; ++i) s += al[i * 17 + t] * yv[i];
    yh[b * 16 + t] = s;
    yhs[t] = s;
  }
  __syncthreads();

  // ================= fused g2 (reuses bufB as fp32 scratch) =================
  float* X2  = (float*)bufB;    // 16*52
  float* A22 = X2 + 832;        // 256
  float* G   = A22 + 256;       // 16*64
  float* Pm  = G + 1024;        // 16*64
  float* wb  = Pm + 1024;       // 64
  float* zz  = wb + 64;         // 16

  for (int e = t; e < 832; e += 256) {
    int r = e / 52, c = e - r * 52;
    float v = 0.f;
    if (c < 50)       v = x[(b * 80 + 64 + r) * 51 + c];
    else if (c == 50) v = yhs[r];
    X2[e] = v;
  }
  for (int e = t; e < 256; e += 256) A22[e] = an22[e];
  if (t < 64) wb[t] = wg2b[t];
  __syncthreads();
  for (int e = t; e < 1024; e += 256) {
    int j = e >> 6, h = e & 63;
    float s = 0.f;
    for (int k = 0; k < 51; ++k) s += X2[j * 52 + k] * g2at[k * 64 + h];
    G[e] = s;
  }
  __syncthreads();
  for (int e = t; e < 1024; e += 256) {
    int j = e >> 6, h = e & 63;
    float s = 0.f;
#pragma unroll
    for (int k = 0; k < 16; ++k) s += A22[j * 16 + k] * G[k * 64 + h];
    Pm[e] = s > 0.f ? s : 0.f;
  }
  __syncthreads();
  if (t < 16) {
    float s = 0.f;
    for (int h = 0; h < 64; ++h) s += Pm[t * 64 + h] * wb[h];
    zz[t] = s;
  }
  __syncthreads();
  if (t < 16) {
    float s = 0.f;
#pragma unroll
    for (int k = 0; k < 16; ++k) s += A22[t * 16 + k] * zz[k];
    out[OUT_OUT + b * 16 + t] = s;
  }
}

// ===========================================================================
// k_dist v2: Gram = Xc@Xc^T via split-bf16 MFMA; sq from Gram diagonal.
// 320 threads (5 waves x 16-row stripes), 1 batch/block.
// ===========================================================================
__global__ __launch_bounds__(320) void k_dist(float* __restrict__ ws,
                                              float* __restrict__ out)
{
  __shared__ __align__(16) unsigned short xcH[5120], xcL[5120];  // 80 x 64
  __shared__ float sq[80];
  const int t = threadIdx.x, b = blockIdx.x;
  const int lane = t & 63, wave = t >> 6;      // wave 0..4
  const int m16 = lane & 15, quad = lane >> 4;
  const int row0 = wave * 16;
  const int arow = row0 + m16;
  const float* x = ws + OFF_X;
  const float* yhg = ws + OFF_YH;
  float* dist = out + OUT_DIST + b * 6400;

  for (int e = t; e < 5120; e += 320) {
    int n = e >> 6, c = e & 63;
    float v = 0.f;
    if (c < 50)       v = x[(b * 80 + n) * 51 + c];
    else if (c == 50) v = (n < 64) ? x[(b * 80 + n) * 51 + 50] : yhg[b * 16 + (n - 64)];
    int idx = SWZ6(n, c);
    unsigned short h = f2bf(v);
    xcH[idx] = h; xcL[idx] = f2bf(v - bf2f(h));
  }
  __syncthreads();

  f32x4 acc[5];
#pragma unroll
  for (int n = 0; n < 5; ++n) acc[n] = (f32x4){0.f, 0.f, 0.f, 0.f};
#pragma unroll
  for (int kb8 = 0; kb8 < 8; kb8 += 4) {
    int ach = ((quad + kb8) ^ (m16 & 7)) << 3;
    bf16x8 aH = *(const bf16x8*)(xcH + (arow << 6) + ach);
    bf16x8 aL = *(const bf16x8*)(xcL + (arow << 6) + ach);
#pragma unroll
    for (int nf = 0; nf < 5; ++nf) {
      const int col = nf * 16 + m16;
      int boff = (col << 6) + ach;
      bf16x8 bH = *(const bf16x8*)(xcH + boff);
      bf16x8 bL = *(const bf16x8*)(xcL + boff);
      acc[nf] = __builtin_amdgcn_mfma_f32_16x16x32_bf16(aH, bH, acc[nf], 0, 0, 0);
      acc[nf] = __builtin_amdgcn_mfma_f32_16x16x32_bf16(aH, bL, acc[nf], 0, 0, 0);
      acc[nf] = __builtin_amdgcn_mfma_f32_16x16x32_bf16(aL, bH, acc[nf], 0, 0, 0);
    }
  }
  // diagonal -> sq (exact zero on the diagonal of d2)
  if ((m16 >> 2) == quad) sq[row0 + m16] = acc[wave][m16 & 3];
  __syncthreads();

#pragma unroll
  for (int nf = 0; nf < 5; ++nf) {
    const int m = nf * 16 + m16;
#pragma unroll
    for (int r = 0; r < 4; ++r) {
      int i = row0 + quad * 4 + r;
      float d2 = sq[i] + sq[m] - 2.f * acc[nf][r];
      d2 = d2 > 0.f ? d2 : 0.f;
      dist[i * 80 + m] = d2 > 0.f ? sqrtf(d2) : 0.f;
    }
  }
}

// ===========================================================================
extern "C" void kernel_launch(void* const* d_in, const int* in_sizes, int n_in,
                              void* d_out, int out_size, void* d_ws, size_t ws_size,
                              hipStream_t stream)
{
  const float* data = (const float*)d_in[0];
  const float* emb0 = (const float*)d_in[1];
  const float* emb1 = (const float*)d_in[2];
  const float* emb2 = (const float*)d_in[3];
  const float* w1   = (const float*)d_in[4];
  const float* b1   = (const float*)d_in[5];
  const float* w2   = (const float*)d_in[6];
  const float* b2   = (const float*)d_in[7];
  const float* w3   = (const float*)d_in[8];
  const float* b3   = (const float*)d_in[9];
  const float* M    = (const float*)d_in[10];
  const float* wg1a = (const float*)d_in[11];
  const float* wg1b = (const float*)d_in[12];
  const float* Wk   = (const float*)d_in[13];
  const float* smo  = (const float*)d_in[14];
  const float* wg2a = (const float*)d_in[15];
  const float* wg2b = (const float*)d_in[16];
  float* ws  = (float*)d_ws;
  float* out = (float*)d_out;

  k_prep<<<dim3(4),    dim3(256), 0, stream>>>(M, Wk, smo, w1, w2, w3, wg1a, wg1b, wg2a, ws, out);
  k_mlp <<<dim3(1280), dim3(256), 0, stream>>>(data, emb0, emb1, emb2, b1, b2, b3, ws);
  k_g1  <<<dim3(1024), dim3(256), 0, stream>>>(ws);
  k_q   <<<dim3(1024), dim3(256), 0, stream>>>(wg2b, ws, out);
  k_dist<<<dim3(1024), dim3(320), 0, stream>>>(ws, out);
}

// Round 7
// 228.560 us; speedup vs baseline: 1.6843x; 1.1447x over previous
//
#include <hip/hip_runtime.h>
#include <math.h>

// ---------------------------------------------------------------------------
// GAT_23613730193923 — round 7: round-6 8-wave structure + RTN split restored
// (round-6 trunc split caused softmax flips in the sc~-100 logit path) and
// 4-term MFMA (adds aL*bL) in k_q's Zp/Zf/cross GEMMs for accuracy margin.
// ---------------------------------------------------------------------------

#define NEGBIG (-1e30f)

// ---- workspace offsets (floats) ----
#define OFF_X     0          // B*80*51 = 4177920
#define OFF_X1    4177920    // B*64*50 = 3276800
#define OFF_YH    7454720    // B*16
#define OFF_A     7471104    // 80*80
#define OFF_AN22  7481600    // 16*16
#define OFF_MK    7484356    // 16*64
#define OFF_GAH   7514692    // W1a hi: 64*64 ushort
#define OFF_GAL   7516740
#define OFF_G2AT  7521156    // 51*64 fp32
#define OFF_SC    7524420    // 1
#define OFF_W1H   7524424    // 128*64 ushort
#define OFF_W1L   7528520
#define OFF_W2H   7532616    // 128*128 ushort
#define OFF_W2L   7540808
#define OFF_W3H   7549000    // 64*128 ushort
#define OFF_W3L   7553096
#define OFF_ANH   7557192    // An11 hi: 64*64 ushort
#define OFF_ANL   7559240
#define OFF_GBH   7561288    // W1b hi: 64*64 ushort
#define OFF_GBL   7563336
#define OFF_WKH   7565384    // Wk^T hi: [h=64][o=64] ushort
#define OFF_WKL   7567432

// ---- output offsets (floats): (out B*16, dist B*6400, A 6400) ----
#define OUT_OUT   0
#define OUT_DIST  16384
#define OUT_A     6569984

typedef __attribute__((ext_vector_type(8))) short bf16x8;
typedef __attribute__((ext_vector_type(4))) short s16x4;
typedef __attribute__((ext_vector_type(4))) float f32x4;

__device__ __forceinline__ unsigned short f2bf(float x) {  // RTN
  union { float f; unsigned u; } v; v.f = x;
  unsigned r = v.u + 0x7fffu + ((v.u >> 16) & 1u);
  return (unsigned short)(r >> 16);
}
__device__ __forceinline__ float bf2f(unsigned short h) {
  union { unsigned u; float f; } v; v.u = ((unsigned)h) << 16; return v.f;
}
// RTN-based hi/lo split (round-5 numerics; trunc split regressed — r6 post-mortem)
__device__ __forceinline__ void split2(float v, unsigned short& h, unsigned short& l) {
  unsigned short hh = f2bf(v);
  h = hh;
  l = f2bf(v - bf2f(hh));
}
#define SWZ6(r, k) (((r) << 6) + (((((k) >> 3) ^ ((r) & 7)) << 3) | ((k) & 7)))
#define SWZ7(r, k) (((r) << 7) + (((((k) >> 3) ^ ((r) & 7)) << 3) | ((k) & 7)))

// ===========================================================================
// k_prep (unchanged)
// ===========================================================================
__global__ __launch_bounds__(256) void k_prep(
    const float* __restrict__ M, const float* __restrict__ Wk,
    const float* __restrict__ sm,
    const float* __restrict__ w1, const float* __restrict__ w2,
    const float* __restrict__ w3,
    const float* __restrict__ wg1a, const float* __restrict__ wg1b,
    const float* __restrict__ wg2a,
    float* __restrict__ ws, float* __restrict__ out)
{
  __shared__ float Msh[80 * 26];
  __shared__ float Ash[80 * 80];
  __shared__ float d1[64];
  __shared__ float d2s[16];
  const int t = threadIdx.x;

  if (blockIdx.x == 0) {
    for (int e = t; e < 80 * 26; e += 256) Msh[e] = M[e];
    __syncthreads();
    for (int e = t; e < 6400; e += 256) {
      int i = e / 80, j = e % 80;
      float v = 0.f;
      if (j < i) {
        float s = 0.f;
        for (int k = 0; k < 26; ++k) s += Msh[i * 26 + k] * Msh[j * 26 + k];
        v = s > 0.f ? s : 0.f;
      }
      Ash[e] = v;
    }
    __syncthreads();
    if (t > 0 && t < 80) {
      int i = t;
      float m = -3.4e38f;
      for (int j = 0; j < i; ++j) m = fmaxf(m, Ash[i * 80 + j]);
      float s = 0.f;
      for (int j = 0; j < i; ++j) {
        float e = expf(Ash[i * 80 + j] - m);
        Ash[i * 80 + j] = e;
        s += e;
      }
      float inv = 1.f / s;
      for (int j = 0; j < i; ++j) Ash[i * 80 + j] *= inv;
    }
    __syncthreads();
    {
      float* Aws = ws + OFF_A;
      float* Aout = out + OUT_A;
      for (int e = t; e < 6400; e += 256) { Aws[e] = Ash[e]; Aout[e] = Ash[e]; }
    }
    if (t < 64) {
      int c = 0;
      for (int j = 0; j < 64; ++j) if (Ash[t * 80 + j] > 1e-15f) ++c;
      d1[t] = 1.f / sqrtf(1.f + (float)c);
    } else if (t < 80) {
      int i = t - 64; int c = 0;
      for (int j = 0; j < 16; ++j) if (Ash[(64 + i) * 80 + 64 + j] > 1e-15f) ++c;
      d2s[i] = 1.f / sqrtf(1.f + (float)c);
    }
    __syncthreads();
    {
      float* an22 = ws + OFF_AN22;
      unsigned short* anH = (unsigned short*)(ws + OFF_ANH);
      unsigned short* anL = (unsigned short*)(ws + OFF_ANL);
      for (int e = t; e < 4096; e += 256) {
        int i = e >> 6, j = e & 63;
        float v = d1[i] * Ash[i * 80 + j] * d1[j];
        unsigned short h = f2bf(v);
        anH[e] = h; anL[e] = f2bf(v - bf2f(h));
      }
      for (int e = t; e < 256; e += 256) {
        int i = e >> 4, j = e & 15;
        an22[e] = d2s[i] * Ash[(64 + i) * 80 + 64 + j] * d2s[j];
      }
    }
    if (t < 16) {
      float* mk = ws + OFF_MK;
      int j = t;
      float m = -3.4e38f;
      for (int i = 0; i < 64; ++i) {
        float v = Ash[(64 + j) * 80 + i];
        v = (v != 0.f) ? v : NEGBIG;
        m = fmaxf(m, v);
      }
      float s = 0.f;
      for (int i = 0; i < 64; ++i) {
        float v = Ash[(64 + j) * 80 + i];
        v = (v != 0.f) ? v : NEGBIG;
        s += expf(v - m);
      }
      float inv = 1.f / s;
      for (int i = 0; i < 64; ++i) {
        float v = Ash[(64 + j) * 80 + i];
        v = (v != 0.f) ? v : NEGBIG;
        mk[j * 64 + i] = (expf(v - m) * inv >= 0.004f) ? 1.f : 0.f;
      }
    }
  } else if (blockIdx.x == 1) {
    unsigned short* wkh = (unsigned short*)(ws + OFF_WKH);
    unsigned short* wkl = (unsigned short*)(ws + OFF_WKL);
    for (int e = t; e < 4096; e += 256) {
      int h = e >> 6, o = e & 63;
      float v = (o < 50) ? Wk[o * 64 + h] : 0.f;
      unsigned short hh = f2bf(v);
      wkh[e] = hh; wkl[e] = f2bf(v - bf2f(hh));
    }
    if (t == 0) {
      float v = sm[0];
      float sig = 1.f / (1.f + expf(-v));
      (ws + OFF_SC)[0] = -0.5f / (sig * 0.01f);
    }
  } else if (blockIdx.x == 2) {
    unsigned short* w1h = (unsigned short*)(ws + OFF_W1H);
    unsigned short* w1l = (unsigned short*)(ws + OFF_W1L);
    for (int e = t; e < 8192; e += 256) {
      int n = e >> 6, k = e & 63;
      float v = (k < 51) ? w1[n * 51 + k] : 0.f;
      unsigned short h = f2bf(v);
      w1h[e] = h; w1l[e] = f2bf(v - bf2f(h));
    }
    unsigned short* w3h = (unsigned short*)(ws + OFF_W3H);
    unsigned short* w3l = (unsigned short*)(ws + OFF_W3L);
    for (int e = t; e < 8192; e += 256) {
      int n = e >> 7, k = e & 127;
      float v = (n < 50) ? w3[n * 128 + k] : 0.f;
      unsigned short h = f2bf(v);
      w3h[e] = h; w3l[e] = f2bf(v - bf2f(h));
    }
    unsigned short* gah = (unsigned short*)(ws + OFF_GAH);
    unsigned short* gal = (unsigned short*)(ws + OFF_GAL);
    for (int e = t; e < 4096; e += 256) {
      int n = e >> 6, k = e & 63;
      float v = (k < 51) ? wg1a[n * 51 + k] : 0.f;
      unsigned short h = f2bf(v);
      gah[e] = h; gal[e] = f2bf(v - bf2f(h));
    }
  } else {
    unsigned short* w2h = (unsigned short*)(ws + OFF_W2H);
    unsigned short* w2l = (unsigned short*)(ws + OFF_W2L);
    for (int e = t; e < 16384; e += 256) {
      int n = e >> 7, k = e & 127;
      float v = w2[n * 128 + k];
      unsigned short h = f2bf(v);
      w2h[e] = h; w2l[e] = f2bf(v - bf2f(h));
    }
    unsigned short* gbh = (unsigned short*)(ws + OFF_GBH);
    unsigned short* gbl = (unsigned short*)(ws + OFF_GBL);
    for (int e = t; e < 4096; e += 256) {
      int n = e >> 6, k = e & 63;
      float v = (n < 50) ? wg1b[n * 64 + k] : 0.f;
      unsigned short h = f2bf(v);
      gbh[e] = h; gbl[e] = f2bf(v - bf2f(h));
    }
    float* g2at = ws + OFF_G2AT;
    for (int e = t; e < 64 * 51; e += 256) { int o = e / 51, k = e % 51; g2at[k * 64 + o] = wg2a[e]; }
  }
}

// ===========================================================================
// k_mlp: 512 threads, 8 waves; wave pair (s, s+4) shares stripe s, splits N.
// ===========================================================================
__global__ __launch_bounds__(512) void k_mlp(
    const float* __restrict__ data,
    const float* __restrict__ emb0, const float* __restrict__ emb1,
    const float* __restrict__ emb2,
    const float* __restrict__ b1, const float* __restrict__ b2,
    const float* __restrict__ b3,
    float* __restrict__ ws)
{
  __shared__ __align__(16) unsigned short actH[64 * 128];
  __shared__ __align__(16) unsigned short actL[64 * 128];
  __shared__ __align__(16) unsigned short wbH[8192];
  __shared__ __align__(16) unsigned short wbL[8192];
  const int t = threadIdx.x;
  const int lane = t & 63, wave = t >> 6;
  const int s = wave & 3, half = wave >> 2;
  const int m16 = lane & 15, quad = lane >> 4;
  const int base = blockIdx.x * 64;
  const int row0 = s * 16;
  const int arow = row0 + m16;
  const unsigned short* w1h = (const unsigned short*)(ws + OFF_W1H);
  const unsigned short* w1l = (const unsigned short*)(ws + OFF_W1L);
  const unsigned short* w2h = (const unsigned short*)(ws + OFF_W2H);
  const unsigned short* w2l = (const unsigned short*)(ws + OFF_W2L);
  const unsigned short* w3h = (const unsigned short*)(ws + OFF_W3H);
  const unsigned short* w3l = (const unsigned short*)(ws + OFF_W3L);
  float* x = ws + OFF_X;

  for (int e = t; e < 4096; e += 512) {
    int r = e >> 6, c = e & 63;
    int g = base + r;
    float v = 0.f;
    if (c < 32)      { int i0 = (int)data[g * 6 + 0]; v = emb0[i0 * 32 + c]; }
    else if (c < 40) { int i1 = (int)data[g * 6 + 1]; v = emb1[i1 * 8 + (c - 32)]; }
    else if (c < 48) { int i2 = (int)data[g * 6 + 2]; v = emb2[i2 * 8 + (c - 40)]; }
    else if (c < 51) { v = data[g * 6 + 3 + (c - 48)]; }
    int idx = SWZ7(r, c);
    split2(v, actH[idx], actL[idx]);
  }
  for (int q = t; q < 1024; q += 512) {
    int col = q >> 3, c = q & 7;
    int dst = (col << 6) + ((c ^ (col & 7)) << 3);
    *(bf16x8*)(wbH + dst) = *(const bf16x8*)(w1h + (col << 6) + (c << 3));
    *(bf16x8*)(wbL + dst) = *(const bf16x8*)(w1l + (col << 6) + (c << 3));
  }
  __syncthreads();

  // layer 1: K=64, N=128
  {
    f32x4 acc[4];
#pragma unroll
    for (int n = 0; n < 4; ++n) acc[n] = (f32x4){0.f, 0.f, 0.f, 0.f};
#pragma unroll
    for (int kb8 = 0; kb8 < 8; kb8 += 4) {
      int ach = ((quad + kb8) ^ (m16 & 7)) << 3;
      bf16x8 aH = *(const bf16x8*)(actH + (arow << 7) + ach);
      bf16x8 aL = *(const bf16x8*)(actL + (arow << 7) + ach);
#pragma unroll
      for (int n = 0; n < 4; ++n) {
        const int col = (half * 4 + n) * 16 + m16;
        int boff = (col << 6) + ach;
        bf16x8 bH = *(const bf16x8*)(wbH + boff);
        bf16x8 bL = *(const bf16x8*)(wbL + boff);
        acc[n] = __builtin_amdgcn_mfma_f32_16x16x32_bf16(aH, bH, acc[n], 0, 0, 0);
        acc[n] = __builtin_amdgcn_mfma_f32_16x16x32_bf16(aH, bL, acc[n], 0, 0, 0);
        acc[n] = __builtin_amdgcn_mfma_f32_16x16x32_bf16(aL, bH, acc[n], 0, 0, 0);
      }
    }
#pragma unroll
    for (int n = 0; n < 4; ++n) {
      const int col = (half * 4 + n) * 16 + m16;
      const float bias = b1[col];
#pragma unroll
      for (int r = 0; r < 4; ++r) {
        float v = acc[n][r] + bias; v = v > 0.f ? v : 0.f;
        int idx = SWZ7(row0 + quad * 4 + r, col);
        split2(v, actH[idx], actL[idx]);
      }
    }
  }

  // layer 2: K=128, N=128 in two 64-col weight halves
  f32x4 acc2[2][2];
#pragma unroll
  for (int a2 = 0; a2 < 2; ++a2)
#pragma unroll
    for (int n = 0; n < 2; ++n) acc2[a2][n] = (f32x4){0.f, 0.f, 0.f, 0.f};
  for (int h2 = 0; h2 < 2; ++h2) {
    __syncthreads();
    for (int q = t; q < 1024; q += 512) {
      int coll = q >> 4, c = q & 15;
      int srcc = (((h2 << 6) + coll) << 7) + (c << 3);
      int dst = (coll << 7) + ((c ^ (coll & 7)) << 3);
      *(bf16x8*)(wbH + dst) = *(const bf16x8*)(w2h + srcc);
      *(bf16x8*)(wbL + dst) = *(const bf16x8*)(w2l + srcc);
    }
    __syncthreads();
#pragma unroll
    for (int kb8 = 0; kb8 < 16; kb8 += 4) {
      int ach = ((quad + kb8) ^ (m16 & 7)) << 3;
      bf16x8 aH = *(const bf16x8*)(actH + (arow << 7) + ach);
      bf16x8 aL = *(const bf16x8*)(actL + (arow << 7) + ach);
#pragma unroll
      for (int n = 0; n < 2; ++n) {
        const int cl = (half * 2 + n) * 16 + m16;
        int boff = (cl << 7) + ach;
        bf16x8 bH = *(const bf16x8*)(wbH + boff);
        bf16x8 bL = *(const bf16x8*)(wbL + boff);
        f32x4 a = acc2[h2][n];
        a = __builtin_amdgcn_mfma_f32_16x16x32_bf16(aH, bH, a, 0, 0, 0);
        a = __builtin_amdgcn_mfma_f32_16x16x32_bf16(aH, bL, a, 0, 0, 0);
        a = __builtin_amdgcn_mfma_f32_16x16x32_bf16(aL, bH, a, 0, 0, 0);
        acc2[h2][n] = a;
      }
    }
  }
  __syncthreads();   // all L2 A-reads done before overwriting act
#pragma unroll
  for (int hh = 0; hh < 2; ++hh) {
#pragma unroll
    for (int n = 0; n < 2; ++n) {
      const int col = hh * 64 + (half * 2 + n) * 16 + m16;
      const float bias = b2[col];
#pragma unroll
      for (int r = 0; r < 4; ++r) {
        float v = acc2[hh][n][r] + bias; v = v > 0.f ? v : 0.f;
        int idx = SWZ7(row0 + quad * 4 + r, col);
        split2(v, actH[idx], actL[idx]);
      }
    }
  }

  // layer 3: K=128, N=64 (50 real)
  for (int q = t; q < 1024; q += 512) {
    int coll = q >> 4, c = q & 15;
    int dst = (coll << 7) + ((c ^ (coll & 7)) << 3);
    *(bf16x8*)(wbH + dst) = *(const bf16x8*)(w3h + (coll << 7) + (c << 3));
    *(bf16x8*)(wbL + dst) = *(const bf16x8*)(w3l + (coll << 7) + (c << 3));
  }
  __syncthreads();
  {
    f32x4 acc[2];
#pragma unroll
    for (int n = 0; n < 2; ++n) acc[n] = (f32x4){0.f, 0.f, 0.f, 0.f};
#pragma unroll
    for (int kb8 = 0; kb8 < 16; kb8 += 4) {
      int ach = ((quad + kb8) ^ (m16 & 7)) << 3;
      bf16x8 aH = *(const bf16x8*)(actH + (arow << 7) + ach);
      bf16x8 aL = *(const bf16x8*)(actL + (arow << 7) + ach);
#pragma unroll
      for (int n = 0; n < 2; ++n) {
        const int col = (half * 2 + n) * 16 + m16;
        int boff = (col << 7) + ach;
        bf16x8 bH = *(const bf16x8*)(wbH + boff);
        bf16x8 bL = *(const bf16x8*)(wbL + boff);
        acc[n] = __builtin_amdgcn_mfma_f32_16x16x32_bf16(aH, bH, acc[n], 0, 0, 0);
        acc[n] = __builtin_amdgcn_mfma_f32_16x16x32_bf16(aH, bL, acc[n], 0, 0, 0);
        acc[n] = __builtin_amdgcn_mfma_f32_16x16x32_bf16(aL, bH, acc[n], 0, 0, 0);
      }
    }
#pragma unroll
    for (int n = 0; n < 2; ++n) {
      const int col = (half * 2 + n) * 16 + m16;
      if (col < 50) {
        const float bias = b3[col];
#pragma unroll
        for (int r = 0; r < 4; ++r) {
          int row = row0 + quad * 4 + r;
          x[(base + row) * 51 + col] = acc[n][r] + bias;
        }
      }
    }
  }
  if (t < 64) x[(base + t) * 51 + 50] = data[(base + t) * 6 + 5];
}

// ===========================================================================
// k_g1: 512 threads, 8 waves, col-split pairs.
// ===========================================================================
__global__ __launch_bounds__(512) void k_g1(float* __restrict__ ws)
{
  __shared__ __align__(16) unsigned short b1H[4096], b1L[4096];
  __shared__ __align__(16) unsigned short b2H[4096], b2L[4096];
  __shared__ __align__(16) unsigned short anH[4096], anL[4096];
  __shared__ __align__(16) unsigned short wH[4096],  wL[4096];
  const int t = threadIdx.x, b = blockIdx.x;
  const int lane = t & 63, wave = t >> 6;
  const int s = wave & 3, half = wave >> 2;
  const int m16 = lane & 15, quad = lane >> 4;
  const int row0 = s * 16;
  const int arow = row0 + m16;
  const float* x = ws + OFF_X;
  const unsigned short* gAnH = (const unsigned short*)(ws + OFF_ANH);
  const unsigned short* gAnL = (const unsigned short*)(ws + OFF_ANL);
  const unsigned short* gaH = (const unsigned short*)(ws + OFF_GAH);
  const unsigned short* gaL = (const unsigned short*)(ws + OFF_GAL);
  const unsigned short* gbH = (const unsigned short*)(ws + OFF_GBH);
  const unsigned short* gbL = (const unsigned short*)(ws + OFF_GBL);
  float* x1 = ws + OFF_X1;

  for (int e = t; e < 4096; e += 512) {
    int r = e >> 6, k = e & 63;
    float v = (k < 51) ? x[(b * 80 + r) * 51 + k] : 0.f;
    int idx = SWZ6(r, k);
    split2(v, b1H[idx], b1L[idx]);
  }
  for (int q = t; q < 512; q += 512) {
    int r = q >> 3, c = q & 7;
    int dst = (r << 6) + ((c ^ (r & 7)) << 3);
    int src = (r << 6) + (c << 3);
    *(bf16x8*)(anH + dst) = *(const bf16x8*)(gAnH + src);
    *(bf16x8*)(anL + dst) = *(const bf16x8*)(gAnL + src);
    *(bf16x8*)(wH + dst)  = *(const bf16x8*)(gaH + src);
    *(bf16x8*)(wL + dst)  = *(const bf16x8*)(gaL + src);
  }
  __syncthreads();

  // GEMM1: T1 = sg1 @ W1a^T -> b2 [col][k]
  {
    f32x4 acc[2];
#pragma unroll
    for (int n = 0; n < 2; ++n) acc[n] = (f32x4){0.f, 0.f, 0.f, 0.f};
#pragma unroll
    for (int kb8 = 0; kb8 < 8; kb8 += 4) {
      int ach = ((quad + kb8) ^ (m16 & 7)) << 3;
      bf16x8 aH = *(const bf16x8*)(b1H + (arow << 6) + ach);
      bf16x8 aL = *(const bf16x8*)(b1L + (arow << 6) + ach);
#pragma unroll
      for (int n = 0; n < 2; ++n) {
        const int col = (half * 2 + n) * 16 + m16;
        int boff = (col << 6) + ach;
        bf16x8 bH = *(const bf16x8*)(wH + boff);
        bf16x8 bL = *(const bf16x8*)(wL + boff);
        acc[n] = __builtin_amdgcn_mfma_f32_16x16x32_bf16(aH, bH, acc[n], 0, 0, 0);
        acc[n] = __builtin_amdgcn_mfma_f32_16x16x32_bf16(aH, bL, acc[n], 0, 0, 0);
        acc[n] = __builtin_amdgcn_mfma_f32_16x16x32_bf16(aL, bH, acc[n], 0, 0, 0);
      }
    }
    const int kb = row0 + quad * 4;
#pragma unroll
    for (int n = 0; n < 2; ++n) {
      const int col = (half * 2 + n) * 16 + m16;
      int idx = (col << 6) + (((((kb >> 3) ^ (col & 7)) << 3)) | (kb & 7));
      s16x4 hv, lv;
#pragma unroll
      for (int r = 0; r < 4; ++r) {
        unsigned short hh, ll; split2(acc[n][r], hh, ll);
        hv[r] = (short)hh; lv[r] = (short)ll;
      }
      *(s16x4*)(b2H + idx) = hv; *(s16x4*)(b2L + idx) = lv;
    }
  }
  __syncthreads();

  // stage W1b + GEMM2: P = relu(An @ T1)
  for (int q = t; q < 512; q += 512) {
    int r = q >> 3, c = q & 7;
    int dst = (r << 6) + ((c ^ (r & 7)) << 3);
    int src = (r << 6) + (c << 3);
    *(bf16x8*)(wH + dst) = *(const bf16x8*)(gbH + src);
    *(bf16x8*)(wL + dst) = *(const bf16x8*)(gbL + src);
  }
  f32x4 accP[2];
  {
#pragma unroll
    for (int n = 0; n < 2; ++n) accP[n] = (f32x4){0.f, 0.f, 0.f, 0.f};
#pragma unroll
    for (int kb8 = 0; kb8 < 8; kb8 += 4) {
      int ach = ((quad + kb8) ^ (m16 & 7)) << 3;
      bf16x8 aH = *(const bf16x8*)(anH + (arow << 6) + ach);
      bf16x8 aL = *(const bf16x8*)(anL + (arow << 6) + ach);
#pragma unroll
      for (int n = 0; n < 2; ++n) {
        const int col = (half * 2 + n) * 16 + m16;
        int boff = (col << 6) + ach;
        bf16x8 bH = *(const bf16x8*)(b2H + boff);
        bf16x8 bL = *(const bf16x8*)(b2L + boff);
        accP[n] = __builtin_amdgcn_mfma_f32_16x16x32_bf16(aH, bH, accP[n], 0, 0, 0);
        accP[n] = __builtin_amdgcn_mfma_f32_16x16x32_bf16(aH, bL, accP[n], 0, 0, 0);
        accP[n] = __builtin_amdgcn_mfma_f32_16x16x32_bf16(aL, bH, accP[n], 0, 0, 0);
      }
    }
  }
  __syncthreads();   // T1 reads done
  {
    const int kb = row0 + quad * 4;
#pragma unroll
    for (int n = 0; n < 2; ++n) {
      const int col = (half * 2 + n) * 16 + m16;
      int idx = (col << 6) + (((((kb >> 3) ^ (col & 7)) << 3)) | (kb & 7));
      s16x4 hv, lv;
#pragma unroll
      for (int r = 0; r < 4; ++r) {
        float v = accP[n][r]; v = v > 0.f ? v : 0.f;
        unsigned short hh, ll; split2(v, hh, ll);
        hv[r] = (short)hh; lv[r] = (short)ll;
      }
      *(s16x4*)(b2H + idx) = hv; *(s16x4*)(b2L + idx) = lv;
    }
  }
  __syncthreads();

  // GEMM3: Q = An @ P -> b1 [row][k]
  {
    f32x4 acc[2];
#pragma unroll
    for (int n = 0; n < 2; ++n) acc[n] = (f32x4){0.f, 0.f, 0.f, 0.f};
#pragma unroll
    for (int kb8 = 0; kb8 < 8; kb8 += 4) {
      int ach = ((quad + kb8) ^ (m16 & 7)) << 3;
      bf16x8 aH = *(const bf16x8*)(anH + (arow << 6) + ach);
      bf16x8 aL = *(const bf16x8*)(anL + (arow << 6) + ach);
#pragma unroll
      for (int n = 0; n < 2; ++n) {
        const int col = (half * 2 + n) * 16 + m16;
        int boff = (col << 6) + ach;
        bf16x8 bH = *(const bf16x8*)(b2H + boff);
        bf16x8 bL = *(const bf16x8*)(b2L + boff);
        acc[n] = __builtin_amdgcn_mfma_f32_16x16x32_bf16(aH, bH, acc[n], 0, 0, 0);
        acc[n] = __builtin_amdgcn_mfma_f32_16x16x32_bf16(aH, bL, acc[n], 0, 0, 0);
        acc[n] = __builtin_amdgcn_mfma_f32_16x16x32_bf16(aL, bH, acc[n], 0, 0, 0);
      }
    }
#pragma unroll
    for (int n = 0; n < 2; ++n) {
      const int col = (half * 2 + n) * 16 + m16;
#pragma unroll
      for (int r = 0; r < 4; ++r) {
        int idx = SWZ6(row0 + quad * 4 + r, col);
        split2(acc[n][r], b1H[idx], b1L[idx]);
      }
    }
  }
  __syncthreads();   // pair-wave wrote other half of our rows

  // GEMM4: x1 = Q @ W1b^T -> global
  {
    f32x4 acc[2];
#pragma unroll
    for (int n = 0; n < 2; ++n) acc[n] = (f32x4){0.f, 0.f, 0.f, 0.f};
#pragma unroll
    for (int kb8 = 0; kb8 < 8; kb8 += 4) {
      int ach = ((quad + kb8) ^ (m16 & 7)) << 3;
      bf16x8 aH = *(const bf16x8*)(b1H + (arow << 6) + ach);
      bf16x8 aL = *(const bf16x8*)(b1L + (arow << 6) + ach);
#pragma unroll
      for (int n = 0; n < 2; ++n) {
        const int col = (half * 2 + n) * 16 + m16;
        int boff = (col << 6) + ach;
        bf16x8 bH = *(const bf16x8*)(wH + boff);
        bf16x8 bL = *(const bf16x8*)(wL + boff);
        acc[n] = __builtin_amdgcn_mfma_f32_16x16x32_bf16(aH, bH, acc[n], 0, 0, 0);
        acc[n] = __builtin_amdgcn_mfma_f32_16x16x32_bf16(aH, bL, acc[n], 0, 0, 0);
        acc[n] = __builtin_amdgcn_mfma_f32_16x16x32_bf16(aL, bH, acc[n], 0, 0, 0);
      }
    }
#pragma unroll
    for (int n = 0; n < 2; ++n) {
      const int col = (half * 2 + n) * 16 + m16;
      if (col < 50) {
#pragma unroll
        for (int r = 0; r < 4; ++r) {
          int row = row0 + quad * 4 + r;
          x1[(b * 64 + row) * 50 + col] = acc[n][r];
        }
      }
    }
  }
}

// ===========================================================================
// k_q: 512 threads, 8 waves; 4-term MFMA on Zp/Zf/cross; fused g2.
// ===========================================================================
__global__ __launch_bounds__(512) void k_q(const float* __restrict__ wg2b,
                                           float* __restrict__ ws,
                                           float* __restrict__ out)
{
  __shared__ __align__(16) unsigned short zH[4096], zL[4096];   // Xp -> Zp
  __shared__ __align__(16) unsigned char bufB[16384];           // WkT | g2 scratch
  __shared__ __align__(16) unsigned short xfH[1024], xfL[1024];
  __shared__ __align__(16) unsigned short zfH[1024], zfL[1024];
  __shared__ float spal[64 * 34];   // spP then al (aliased)
  __shared__ float sp[64], sf[16], yv[64], yhs[16];
  const int t = threadIdx.x, b = blockIdx.x;
  const int lane = t & 63, wave = t >> 6;
  const int s = wave & 3, half = wave >> 2;
  const int m16 = lane & 15, quad = lane >> 4;
  const int row0 = s * 16;
  const int arow = row0 + m16;
  const float* x = ws + OFF_X;
  const float* x1 = ws + OFF_X1;
  const float* mk = ws + OFF_MK;
  const float* an22 = ws + OFF_AN22;
  const float* g2at = ws + OFF_G2AT;
  const float sc = (ws + OFF_SC)[0];
  float* yh = ws + OFF_YH;

  unsigned short* wkH = (unsigned short*)bufB;
  unsigned short* wkL = wkH + 4096;

  for (int e = t; e < 4096; e += 512) {
    int r = e >> 6, c = e & 63;
    float v = (c < 50) ? x1[(b * 64 + r) * 50 + c] : 0.f;
    int idx = SWZ6(r, c);
    split2(v, zH[idx], zL[idx]);
  }
  for (int e = t; e < 1024; e += 512) {
    int r = e >> 6, c = e & 63;
    float v = (c < 50) ? x[(b * 80 + 64 + r) * 51 + c] : 0.f;
    int idx = SWZ6(r, c);
    split2(v, xfH[idx], xfL[idx]);
  }
  {
    const unsigned short* gwkH = (const unsigned short*)(ws + OFF_WKH);
    const unsigned short* gwkL = (const unsigned short*)(ws + OFF_WKL);
    for (int q = t; q < 512; q += 512) {
      int r = q >> 3, c = q & 7;
      int dst = (r << 6) + ((c ^ (r & 7)) << 3);
      int src = (r << 6) + (c << 3);
      *(bf16x8*)(wkH + dst) = *(const bf16x8*)(gwkH + src);
      *(bf16x8*)(wkL + dst) = *(const bf16x8*)(gwkL + src);
    }
  }
  if (t < 64) yv[t] = x[(b * 80 + t) * 51 + 50];
  __syncthreads();

  // GEMM1: Zp = Xp @ Wk (4-term); Zf on half-0 waves (4-term)
  f32x4 accZ[2];
#pragma unroll
  for (int n = 0; n < 2; ++n) accZ[n] = (f32x4){0.f, 0.f, 0.f, 0.f};
#pragma unroll
  for (int kb8 = 0; kb8 < 8; kb8 += 4) {
    int ach = ((quad + kb8) ^ (m16 & 7)) << 3;
    bf16x8 aH = *(const bf16x8*)(zH + (arow << 6) + ach);
    bf16x8 aL = *(const bf16x8*)(zL + (arow << 6) + ach);
#pragma unroll
    for (int n = 0; n < 2; ++n) {
      const int col = (half * 2 + n) * 16 + m16;
      int boff = (col << 6) + ach;
      bf16x8 bH = *(const bf16x8*)(wkH + boff);
      bf16x8 bL = *(const bf16x8*)(wkL + boff);
      accZ[n] = __builtin_amdgcn_mfma_f32_16x16x32_bf16(aH, bH, accZ[n], 0, 0, 0);
      accZ[n] = __builtin_amdgcn_mfma_f32_16x16x32_bf16(aH, bL, accZ[n], 0, 0, 0);
      accZ[n] = __builtin_amdgcn_mfma_f32_16x16x32_bf16(aL, bH, accZ[n], 0, 0, 0);
      accZ[n] = __builtin_amdgcn_mfma_f32_16x16x32_bf16(aL, bL, accZ[n], 0, 0, 0);
    }
  }
  if (half == 0) {
    f32x4 af = (f32x4){0.f, 0.f, 0.f, 0.f};
#pragma unroll
    for (int kb8 = 0; kb8 < 8; kb8 += 4) {
      int ach = ((quad + kb8) ^ (m16 & 7)) << 3;
      bf16x8 aH = *(const bf16x8*)(xfH + (m16 << 6) + ach);
      bf16x8 aL = *(const bf16x8*)(xfL + (m16 << 6) + ach);
      const int col = s * 16 + m16;
      int boff = (col << 6) + ach;
      bf16x8 bH = *(const bf16x8*)(wkH + boff);
      bf16x8 bL = *(const bf16x8*)(wkL + boff);
      af = __builtin_amdgcn_mfma_f32_16x16x32_bf16(aH, bH, af, 0, 0, 0);
      af = __builtin_amdgcn_mfma_f32_16x16x32_bf16(aH, bL, af, 0, 0, 0);
      af = __builtin_amdgcn_mfma_f32_16x16x32_bf16(aL, bH, af, 0, 0, 0);
      af = __builtin_amdgcn_mfma_f32_16x16x32_bf16(aL, bL, af, 0, 0, 0);
    }
    const int h = s * 16 + m16;
#pragma unroll
    for (int r = 0; r < 4; ++r) {
      int idx = SWZ6(quad * 4 + r, h);
      split2(af[r], zfH[idx], zfL[idx]);
    }
  }
  __syncthreads();   // all Xp reads done; zf visible

  // Zp epilogue (in-place) + sp partials
  {
    float s2[4] = {0.f, 0.f, 0.f, 0.f};
#pragma unroll
    for (int n = 0; n < 2; ++n) {
      const int h = (half * 2 + n) * 16 + m16;
#pragma unroll
      for (int r = 0; r < 4; ++r) {
        float v = accZ[n][r];
        s2[r] += v * v;
        int idx = SWZ6(row0 + quad * 4 + r, h);
        split2(v, zH[idx], zL[idx]);
      }
    }
#pragma unroll
    for (int r = 0; r < 4; ++r)
      spal[(row0 + quad * 4 + r) * 34 + half * 16 + m16] = s2[r];
  }
  __syncthreads();   // Zp + spP visible

  if (t < 64) {
    float ssum = 0.f;
#pragma unroll
    for (int m = 0; m < 32; ++m) ssum += spal[t * 34 + m];
    sp[t] = ssum;
  } else if (t < 80) {
    int j = t - 64;
    float ssum = 0.f;
    for (int h = 0; h < 64; ++h) {
      int idx = SWZ6(j, h);
      float v = bf2f(zfH[idx]) + bf2f(zfL[idx]);
      ssum += v * v;
    }
    sf[j] = ssum;
  }
  __syncthreads();

  // cross = Zp @ Zf^T (4-term; redundant across halves, half0 writes al)
  {
    f32x4 ac2 = (f32x4){0.f, 0.f, 0.f, 0.f};
#pragma unroll
    for (int kb8 = 0; kb8 < 8; kb8 += 4) {
      int ach = ((quad + kb8) ^ (m16 & 7)) << 3;
      bf16x8 aH = *(const bf16x8*)(zH + (arow << 6) + ach);
      bf16x8 aL = *(const bf16x8*)(zL + (arow << 6) + ach);
      bf16x8 bH = *(const bf16x8*)(zfH + (m16 << 6) + ach);
      bf16x8 bL = *(const bf16x8*)(zfL + (m16 << 6) + ach);
      ac2 = __builtin_amdgcn_mfma_f32_16x16x32_bf16(aH, bH, ac2, 0, 0, 0);
      ac2 = __builtin_amdgcn_mfma_f32_16x16x32_bf16(aH, bL, ac2, 0, 0, 0);
      ac2 = __builtin_amdgcn_mfma_f32_16x16x32_bf16(aL, bH, ac2, 0, 0, 0);
      ac2 = __builtin_amdgcn_mfma_f32_16x16x32_bf16(aL, bL, ac2, 0, 0, 0);
    }
    if (half == 0) {
      float* al = spal;   // alias (spP dead)
#pragma unroll
      for (int r = 0; r < 4; ++r) {
        int i = row0 + quad * 4 + r;
        al[i * 17 + m16] = sc * (sp[i] + sf[m16] - 2.f * ac2[r]);
      }
    }
  }
  __syncthreads();
  // masked softmax over j per i
  {
    float* al = spal;
    if (t < 64) {
      const int i = t;
      float lv[16];
      float m = -3.4e38f;
#pragma unroll
      for (int j = 0; j < 16; ++j) {
        float v = (mk[j * 64 + i] != 0.f) ? al[i * 17 + j] : NEGBIG;
        lv[j] = v;
        m = fmaxf(m, v);
      }
      float ssum = 0.f;
#pragma unroll
      for (int j = 0; j < 16; ++j) { lv[j] = expf(lv[j] - m); ssum += lv[j]; }
      float inv = 1.f / ssum;
#pragma unroll
      for (int j = 0; j < 16; ++j) al[i * 17 + j] = lv[j] * inv;
    }
  }
  __syncthreads();
  if (t < 16) {
    float* al = spal;
    float ssum = 0.f;
    for (int i = 0; i < 64; ++i) ssum += al[i * 17 + t] * yv[i];
    yh[b * 16 + t] = ssum;
    yhs[t] = ssum;
  }
  __syncthreads();

  // ===== fused g2 (bufB reused as fp32 scratch) =====
  float* X2  = (float*)bufB;
  float* A22 = X2 + 832;
  float* G   = A22 + 256;
  float* Pm  = G + 1024;
  float* wb  = Pm + 1024;
  float* zz  = wb + 64;

  for (int e = t; e < 832; e += 512) {
    int r = e / 52, c = e - r * 52;
    float v = 0.f;
    if (c < 50)       v = x[(b * 80 + 64 + r) * 51 + c];
    else if (c == 50) v = yhs[r];
    X2[e] = v;
  }
  for (int e = t; e < 256; e += 512) A22[e] = an22[e];
  if (t < 64) wb[t] = wg2b[t];
  __syncthreads();
  for (int e = t; e < 1024; e += 512) {
    int j = e >> 6, h = e & 63;
    float ssum = 0.f;
    for (int k = 0; k < 51; ++k) ssum += X2[j * 52 + k] * g2at[k * 64 + h];
    G[e] = ssum;
  }
  __syncthreads();
  for (int e = t; e < 1024; e += 512) {
    int j = e >> 6, h = e & 63;
    float ssum = 0.f;
#pragma unroll
    for (int k = 0; k < 16; ++k) ssum += A22[j * 16 + k] * G[k * 64 + h];
    Pm[e] = ssum > 0.f ? ssum : 0.f;
  }
  __syncthreads();
  if (t < 16) {
    float ssum = 0.f;
    for (int h = 0; h < 64; ++h) ssum += Pm[t * 64 + h] * wb[h];
    zz[t] = ssum;
  }
  __syncthreads();
  if (t < 16) {
    float ssum = 0.f;
#pragma unroll
    for (int k = 0; k < 16; ++k) ssum += A22[t * 16 + k] * zz[k];
    out[OUT_OUT + b * 16 + t] = ssum;
  }
}

// ===========================================================================
// k_dist: MFMA Gram, sq from diagonal.
// ===========================================================================
__global__ __launch_bounds__(320) void k_dist(float* __restrict__ ws,
                                              float* __restrict__ out)
{
  __shared__ __align__(16) unsigned short xcH[5120], xcL[5120];
  __shared__ float sq[80];
  const int t = threadIdx.x, b = blockIdx.x;
  const int lane = t & 63, wave = t >> 6;
  const int m16 = lane & 15, quad = lane >> 4;
  const int row0 = wave * 16;
  const int arow = row0 + m16;
  const float* x = ws + OFF_X;
  const float* yhg = ws + OFF_YH;
  float* dist = out + OUT_DIST + b * 6400;

  for (int e = t; e < 5120; e += 320) {
    int n = e >> 6, c = e & 63;
    float v = 0.f;
    if (c < 50)       v = x[(b * 80 + n) * 51 + c];
    else if (c == 50) v = (n < 64) ? x[(b * 80 + n) * 51 + 50] : yhg[b * 16 + (n - 64)];
    int idx = SWZ6(n, c);
    split2(v, xcH[idx], xcL[idx]);
  }
  __syncthreads();

  f32x4 acc[5];
#pragma unroll
  for (int n = 0; n < 5; ++n) acc[n] = (f32x4){0.f, 0.f, 0.f, 0.f};
#pragma unroll
  for (int kb8 = 0; kb8 < 8; kb8 += 4) {
    int ach = ((quad + kb8) ^ (m16 & 7)) << 3;
    bf16x8 aH = *(const bf16x8*)(xcH + (arow << 6) + ach);
    bf16x8 aL = *(const bf16x8*)(xcL + (arow << 6) + ach);
#pragma unroll
    for (int nf = 0; nf < 5; ++nf) {
      const int col = nf * 16 + m16;
      int boff = (col << 6) + ach;
      bf16x8 bH = *(const bf16x8*)(xcH + boff);
      bf16x8 bL = *(const bf16x8*)(xcL + boff);
      acc[nf] = __builtin_amdgcn_mfma_f32_16x16x32_bf16(aH, bH, acc[nf], 0, 0, 0);
      acc[nf] = __builtin_amdgcn_mfma_f32_16x16x32_bf16(aH, bL, acc[nf], 0, 0, 0);
      acc[nf] = __builtin_amdgcn_mfma_f32_16x16x32_bf16(aL, bH, acc[nf], 0, 0, 0);
    }
  }
  if ((m16 >> 2) == quad) sq[row0 + m16] = acc[wave][m16 & 3];
  __syncthreads();

#pragma unroll
  for (int nf = 0; nf < 5; ++nf) {
    const int m = nf * 16 + m16;
#pragma unroll
    for (int r = 0; r < 4; ++r) {
      int i = row0 + quad * 4 + r;
      float d2 = sq[i] + sq[m] - 2.f * acc[nf][r];
      d2 = d2 > 0.f ? d2 : 0.f;
      dist[i * 80 + m] = d2 > 0.f ? sqrtf(d2) : 0.f;
    }
  }
}

// ===========================================================================
extern "C" void kernel_launch(void* const* d_in, const int* in_sizes, int n_in,
                              void* d_out, int out_size, void* d_ws, size_t ws_size,
                              hipStream_t stream)
{
  const float* data = (const float*)d_in[0];
  const float* emb0 = (const float*)d_in[1];
  const float* emb1 = (const float*)d_in[2];
  const float* emb2 = (const float*)d_in[3];
  const float* w1   = (const float*)d_in[4];
  const float* b1   = (const float*)d_in[5];
  const float* w2   = (const float*)d_in[6];
  const float* b2   = (const float*)d_in[7];
  const float* w3   = (const float*)d_in[8];
  const float* b3   = (const float*)d_in[9];
  const float* M    = (const float*)d_in[10];
  const float* wg1a = (const float*)d_in[11];
  const float* wg1b = (const float*)d_in[12];
  const float* Wk   = (const float*)d_in[13];
  const float* smo  = (const float*)d_in[14];
  const float* wg2a = (const float*)d_in[15];
  const float* wg2b = (const float*)d_in[16];
  float* ws  = (float*)d_ws;
  float* out = (float*)d_out;

  k_prep<<<dim3(4),    dim3(256), 0, stream>>>(M, Wk, smo, w1, w2, w3, wg1a, wg1b, wg2a, ws, out);
  k_mlp <<<dim3(1280), dim3(512), 0, stream>>>(data, emb0, emb1, emb2, b1, b2, b3, ws);
  k_g1  <<<dim3(1024), dim3(512), 0, stream>>>(ws);
  k_q   <<<dim3(1024), dim3(512), 0, stream>>>(wg2b, ws, out);
  k_dist<<<dim3(1024), dim3(320), 0, stream>>>(ws, out);
}

// Round 8
// 213.582 us; speedup vs baseline: 1.8024x; 1.0701x over previous
//
#include <hip/hip_runtime.h>
#include <math.h>

// ---------------------------------------------------------------------------
// GAT_23613730193923 — round 8: register-prefetch weight pipelining (k_mlp)
// + k_g1/k_q/g2 fused into k_gq (x1 stays in LDS; phase-aliased 64KB pool).
// ---------------------------------------------------------------------------

#define NEGBIG (-1e30f)

// ---- workspace offsets (floats) ----
#define OFF_X     0          // B*80*51 = 4177920
#define OFF_YH    7454720    // B*16
#define OFF_A     7471104    // 80*80
#define OFF_AN22  7481600    // 16*16
#define OFF_MK    7484356    // 16*64
#define OFF_GAH   7514692    // W1a hi: 64*64 ushort
#define OFF_GAL   7516740
#define OFF_G2AT  7521156    // 51*64 fp32
#define OFF_SC    7524420    // 1
#define OFF_W1H   7524424    // 128*64 ushort
#define OFF_W1L   7528520
#define OFF_W2H   7532616    // 128*128 ushort
#define OFF_W2L   7540808
#define OFF_W3H   7549000    // 64*128 ushort
#define OFF_W3L   7553096
#define OFF_ANH   7557192    // An11 hi: 64*64 ushort
#define OFF_ANL   7559240
#define OFF_GBH   7561288    // W1b hi: 64*64 ushort
#define OFF_GBL   7563336
#define OFF_WKH   7565384    // Wk^T hi: [h=64][o=64] ushort
#define OFF_WKL   7567432

// ---- output offsets (floats): (out B*16, dist B*6400, A 6400) ----
#define OUT_OUT   0
#define OUT_DIST  16384
#define OUT_A     6569984

typedef __attribute__((ext_vector_type(8))) short bf16x8;
typedef __attribute__((ext_vector_type(4))) short s16x4;
typedef __attribute__((ext_vector_type(4))) float f32x4;

__device__ __forceinline__ unsigned short f2bf(float x) {  // RTN
  union { float f; unsigned u; } v; v.f = x;
  unsigned r = v.u + 0x7fffu + ((v.u >> 16) & 1u);
  return (unsigned short)(r >> 16);
}
__device__ __forceinline__ float bf2f(unsigned short h) {
  union { unsigned u; float f; } v; v.u = ((unsigned)h) << 16; return v.f;
}
__device__ __forceinline__ void split2(float v, unsigned short& h, unsigned short& l) {
  unsigned short hh = f2bf(v);
  h = hh;
  l = f2bf(v - bf2f(hh));
}
#define SWZ6(r, k) (((r) << 6) + (((((k) >> 3) ^ ((r) & 7)) << 3) | ((k) & 7)))
#define SWZ7(r, k) (((r) << 7) + (((((k) >> 3) ^ ((r) & 7)) << 3) | ((k) & 7)))

#define MFMA3(acc, aH, aL, bH, bL) \
  acc = __builtin_amdgcn_mfma_f32_16x16x32_bf16(aH, bH, acc, 0, 0, 0); \
  acc = __builtin_amdgcn_mfma_f32_16x16x32_bf16(aH, bL, acc, 0, 0, 0); \
  acc = __builtin_amdgcn_mfma_f32_16x16x32_bf16(aL, bH, acc, 0, 0, 0);
#define MFMA4(acc, aH, aL, bH, bL) \
  MFMA3(acc, aH, aL, bH, bL) \
  acc = __builtin_amdgcn_mfma_f32_16x16x32_bf16(aL, bL, acc, 0, 0, 0);

// ===========================================================================
// k_prep (unchanged)
// ===========================================================================
__global__ __launch_bounds__(256) void k_prep(
    const float* __restrict__ M, const float* __restrict__ Wk,
    const float* __restrict__ sm,
    const float* __restrict__ w1, const float* __restrict__ w2,
    const float* __restrict__ w3,
    const float* __restrict__ wg1a, const float* __restrict__ wg1b,
    const float* __restrict__ wg2a,
    float* __restrict__ ws, float* __restrict__ out)
{
  __shared__ float Msh[80 * 26];
  __shared__ float Ash[80 * 80];
  __shared__ float d1[64];
  __shared__ float d2s[16];
  const int t = threadIdx.x;

  if (blockIdx.x == 0) {
    for (int e = t; e < 80 * 26; e += 256) Msh[e] = M[e];
    __syncthreads();
    for (int e = t; e < 6400; e += 256) {
      int i = e / 80, j = e % 80;
      float v = 0.f;
      if (j < i) {
        float s = 0.f;
        for (int k = 0; k < 26; ++k) s += Msh[i * 26 + k] * Msh[j * 26 + k];
        v = s > 0.f ? s : 0.f;
      }
      Ash[e] = v;
    }
    __syncthreads();
    if (t > 0 && t < 80) {
      int i = t;
      float m = -3.4e38f;
      for (int j = 0; j < i; ++j) m = fmaxf(m, Ash[i * 80 + j]);
      float s = 0.f;
      for (int j = 0; j < i; ++j) {
        float e = expf(Ash[i * 80 + j] - m);
        Ash[i * 80 + j] = e;
        s += e;
      }
      float inv = 1.f / s;
      for (int j = 0; j < i; ++j) Ash[i * 80 + j] *= inv;
    }
    __syncthreads();
    {
      float* Aws = ws + OFF_A;
      float* Aout = out + OUT_A;
      for (int e = t; e < 6400; e += 256) { Aws[e] = Ash[e]; Aout[e] = Ash[e]; }
    }
    if (t < 64) {
      int c = 0;
      for (int j = 0; j < 64; ++j) if (Ash[t * 80 + j] > 1e-15f) ++c;
      d1[t] = 1.f / sqrtf(1.f + (float)c);
    } else if (t < 80) {
      int i = t - 64; int c = 0;
      for (int j = 0; j < 16; ++j) if (Ash[(64 + i) * 80 + 64 + j] > 1e-15f) ++c;
      d2s[i] = 1.f / sqrtf(1.f + (float)c);
    }
    __syncthreads();
    {
      float* an22 = ws + OFF_AN22;
      unsigned short* anH = (unsigned short*)(ws + OFF_ANH);
      unsigned short* anL = (unsigned short*)(ws + OFF_ANL);
      for (int e = t; e < 4096; e += 256) {
        int i = e >> 6, j = e & 63;
        float v = d1[i] * Ash[i * 80 + j] * d1[j];
        unsigned short h = f2bf(v);
        anH[e] = h; anL[e] = f2bf(v - bf2f(h));
      }
      for (int e = t; e < 256; e += 256) {
        int i = e >> 4, j = e & 15;
        an22[e] = d2s[i] * Ash[(64 + i) * 80 + 64 + j] * d2s[j];
      }
    }
    if (t < 16) {
      float* mk = ws + OFF_MK;
      int j = t;
      float m = -3.4e38f;
      for (int i = 0; i < 64; ++i) {
        float v = Ash[(64 + j) * 80 + i];
        v = (v != 0.f) ? v : NEGBIG;
        m = fmaxf(m, v);
      }
      float s = 0.f;
      for (int i = 0; i < 64; ++i) {
        float v = Ash[(64 + j) * 80 + i];
        v = (v != 0.f) ? v : NEGBIG;
        s += expf(v - m);
      }
      float inv = 1.f / s;
      for (int i = 0; i < 64; ++i) {
        float v = Ash[(64 + j) * 80 + i];
        v = (v != 0.f) ? v : NEGBIG;
        mk[j * 64 + i] = (expf(v - m) * inv >= 0.004f) ? 1.f : 0.f;
      }
    }
  } else if (blockIdx.x == 1) {
    unsigned short* wkh = (unsigned short*)(ws + OFF_WKH);
    unsigned short* wkl = (unsigned short*)(ws + OFF_WKL);
    for (int e = t; e < 4096; e += 256) {
      int h = e >> 6, o = e & 63;
      float v = (o < 50) ? Wk[o * 64 + h] : 0.f;
      unsigned short hh = f2bf(v);
      wkh[e] = hh; wkl[e] = f2bf(v - bf2f(hh));
    }
    if (t == 0) {
      float v = sm[0];
      float sig = 1.f / (1.f + expf(-v));
      (ws + OFF_SC)[0] = -0.5f / (sig * 0.01f);
    }
  } else if (blockIdx.x == 2) {
    unsigned short* w1h = (unsigned short*)(ws + OFF_W1H);
    unsigned short* w1l = (unsigned short*)(ws + OFF_W1L);
    for (int e = t; e < 8192; e += 256) {
      int n = e >> 6, k = e & 63;
      float v = (k < 51) ? w1[n * 51 + k] : 0.f;
      unsigned short h = f2bf(v);
      w1h[e] = h; w1l[e] = f2bf(v - bf2f(h));
    }
    unsigned short* w3h = (unsigned short*)(ws + OFF_W3H);
    unsigned short* w3l = (unsigned short*)(ws + OFF_W3L);
    for (int e = t; e < 8192; e += 256) {
      int n = e >> 7, k = e & 127;
      float v = (n < 50) ? w3[n * 128 + k] : 0.f;
      unsigned short h = f2bf(v);
      w3h[e] = h; w3l[e] = f2bf(v - bf2f(h));
    }
    unsigned short* gah = (unsigned short*)(ws + OFF_GAH);
    unsigned short* gal = (unsigned short*)(ws + OFF_GAL);
    for (int e = t; e < 4096; e += 256) {
      int n = e >> 6, k = e & 63;
      float v = (k < 51) ? wg1a[n * 51 + k] : 0.f;
      unsigned short h = f2bf(v);
      gah[e] = h; gal[e] = f2bf(v - bf2f(h));
    }
  } else {
    unsigned short* w2h = (unsigned short*)(ws + OFF_W2H);
    unsigned short* w2l = (unsigned short*)(ws + OFF_W2L);
    for (int e = t; e < 16384; e += 256) {
      int n = e >> 7, k = e & 127;
      float v = w2[n * 128 + k];
      unsigned short h = f2bf(v);
      w2h[e] = h; w2l[e] = f2bf(v - bf2f(h));
    }
    unsigned short* gbh = (unsigned short*)(ws + OFF_GBH);
    unsigned short* gbl = (unsigned short*)(ws + OFF_GBL);
    for (int e = t; e < 4096; e += 256) {
      int n = e >> 6, k = e & 63;
      float v = (n < 50) ? wg1b[n * 64 + k] : 0.f;
      unsigned short h = f2bf(v);
      gbh[e] = h; gbl[e] = f2bf(v - bf2f(h));
    }
    float* g2at = ws + OFF_G2AT;
    for (int e = t; e < 64 * 51; e += 256) { int o = e / 51, k = e % 51; g2at[k * 64 + o] = wg2a[e]; }
  }
}

// ===========================================================================
// k_mlp v6: 512 threads, register-prefetch weight pipeline.
// ===========================================================================
__global__ __launch_bounds__(512) void k_mlp(
    const float* __restrict__ data,
    const float* __restrict__ emb0, const float* __restrict__ emb1,
    const float* __restrict__ emb2,
    const float* __restrict__ b1, const float* __restrict__ b2,
    const float* __restrict__ b3,
    float* __restrict__ ws)
{
  __shared__ __align__(16) unsigned short actH[64 * 128];
  __shared__ __align__(16) unsigned short actL[64 * 128];
  __shared__ __align__(16) unsigned short wbH[8192];
  __shared__ __align__(16) unsigned short wbL[8192];
  const int t = threadIdx.x;
  const int lane = t & 63, wave = t >> 6;
  const int s = wave & 3, half = wave >> 2;
  const int m16 = lane & 15, quad = lane >> 4;
  const int base = blockIdx.x * 64;
  const int row0 = s * 16;
  const int arow = row0 + m16;
  const unsigned short* w1h = (const unsigned short*)(ws + OFF_W1H);
  const unsigned short* w1l = (const unsigned short*)(ws + OFF_W1L);
  const unsigned short* w2h = (const unsigned short*)(ws + OFF_W2H);
  const unsigned short* w2l = (const unsigned short*)(ws + OFF_W2L);
  const unsigned short* w3h = (const unsigned short*)(ws + OFF_W3H);
  const unsigned short* w3l = (const unsigned short*)(ws + OFF_W3L);
  float* x = ws + OFF_X;

  // ---- P0: gather act + stage W1; prefetch W2 half0 into regs ----
  for (int e = t; e < 4096; e += 512) {
    int r = e >> 6, c = e & 63;
    int g = base + r;
    float v = 0.f;
    if (c < 32)      { int i0 = (int)data[g * 6 + 0]; v = emb0[i0 * 32 + c]; }
    else if (c < 40) { int i1 = (int)data[g * 6 + 1]; v = emb1[i1 * 8 + (c - 32)]; }
    else if (c < 48) { int i2 = (int)data[g * 6 + 2]; v = emb2[i2 * 8 + (c - 40)]; }
    else if (c < 51) { v = data[g * 6 + 3 + (c - 48)]; }
    int idx = SWZ7(r, c);
    split2(v, actH[idx], actL[idx]);
  }
  for (int q = t; q < 1024; q += 512) {
    int col = q >> 3, c = q & 7;
    int dst = (col << 6) + ((c ^ (col & 7)) << 3);
    *(bf16x8*)(wbH + dst) = *(const bf16x8*)(w1h + (col << 6) + (c << 3));
    *(bf16x8*)(wbL + dst) = *(const bf16x8*)(w1l + (col << 6) + (c << 3));
  }
  bf16x8 pH[2], pL[2];
#pragma unroll
  for (int i = 0; i < 2; ++i) {          // W2 half0
    int q = t + i * 512;
    int coll = q >> 4, c = q & 15;
    int src = (coll << 7) + (c << 3);
    pH[i] = *(const bf16x8*)(w2h + src);
    pL[i] = *(const bf16x8*)(w2l + src);
  }
  if (t < 64) x[(base + t) * 51 + 50] = data[(base + t) * 6 + 5];
  __syncthreads();   // B1

  // ---- layer 1 ----
  {
    f32x4 acc[4];
#pragma unroll
    for (int n = 0; n < 4; ++n) acc[n] = (f32x4){0.f, 0.f, 0.f, 0.f};
#pragma unroll
    for (int kb8 = 0; kb8 < 8; kb8 += 4) {
      int ach = ((quad + kb8) ^ (m16 & 7)) << 3;
      bf16x8 aH = *(const bf16x8*)(actH + (arow << 7) + ach);
      bf16x8 aL = *(const bf16x8*)(actL + (arow << 7) + ach);
#pragma unroll
      for (int n = 0; n < 4; ++n) {
        const int col = (half * 4 + n) * 16 + m16;
        int boff = (col << 6) + ach;
        bf16x8 bH = *(const bf16x8*)(wbH + boff);
        bf16x8 bL = *(const bf16x8*)(wbL + boff);
        MFMA3(acc[n], aH, aL, bH, bL)
      }
    }
#pragma unroll
    for (int n = 0; n < 4; ++n) {
      const int col = (half * 4 + n) * 16 + m16;
      const float bias = b1[col];
#pragma unroll
      for (int r = 0; r < 4; ++r) {
        float v = acc[n][r] + bias; v = v > 0.f ? v : 0.f;
        int idx = SWZ7(row0 + quad * 4 + r, col);
        split2(v, actH[idx], actL[idx]);
      }
    }
  }
  __syncthreads();   // B2: W1 reads + L1 epi done

  // ---- write W2h0; prefetch W2h1 ----
#pragma unroll
  for (int i = 0; i < 2; ++i) {
    int q = t + i * 512;
    int coll = q >> 4, c = q & 15;
    int dst = (coll << 7) + ((c ^ (coll & 7)) << 3);
    *(bf16x8*)(wbH + dst) = pH[i];
    *(bf16x8*)(wbL + dst) = pL[i];
  }
#pragma unroll
  for (int i = 0; i < 2; ++i) {          // W2 half1
    int q = t + i * 512;
    int coll = q >> 4, c = q & 15;
    int src = ((64 + coll) << 7) + (c << 3);
    pH[i] = *(const bf16x8*)(w2h + src);
    pL[i] = *(const bf16x8*)(w2l + src);
  }
  __syncthreads();   // B3

  // ---- layer 2 half0 ----
  f32x4 acc2[2][2];
#pragma unroll
  for (int a2 = 0; a2 < 2; ++a2)
#pragma unroll
    for (int n = 0; n < 2; ++n) acc2[a2][n] = (f32x4){0.f, 0.f, 0.f, 0.f};
#pragma unroll
  for (int kb8 = 0; kb8 < 16; kb8 += 4) {
    int ach = ((quad + kb8) ^ (m16 & 7)) << 3;
    bf16x8 aH = *(const bf16x8*)(actH + (arow << 7) + ach);
    bf16x8 aL = *(const bf16x8*)(actL + (arow << 7) + ach);
#pragma unroll
    for (int n = 0; n < 2; ++n) {
      const int cl = (half * 2 + n) * 16 + m16;
      int boff = (cl << 7) + ach;
      bf16x8 bH = *(const bf16x8*)(wbH + boff);
      bf16x8 bL = *(const bf16x8*)(wbL + boff);
      MFMA3(acc2[0][n], aH, aL, bH, bL)
    }
  }
  __syncthreads();   // B4

  // ---- write W2h1; prefetch W3 ----
#pragma unroll
  for (int i = 0; i < 2; ++i) {
    int q = t + i * 512;
    int coll = q >> 4, c = q & 15;
    int dst = (coll << 7) + ((c ^ (coll & 7)) << 3);
    *(bf16x8*)(wbH + dst) = pH[i];
    *(bf16x8*)(wbL + dst) = pL[i];
  }
#pragma unroll
  for (int i = 0; i < 2; ++i) {          // W3
    int q = t + i * 512;
    int coll = q >> 4, c = q & 15;
    int src = (coll << 7) + (c << 3);
    pH[i] = *(const bf16x8*)(w3h + src);
    pL[i] = *(const bf16x8*)(w3l + src);
  }
  __syncthreads();   // B5

  // ---- layer 2 half1 ----
#pragma unroll
  for (int kb8 = 0; kb8 < 16; kb8 += 4) {
    int ach = ((quad + kb8) ^ (m16 & 7)) << 3;
    bf16x8 aH = *(const bf16x8*)(actH + (arow << 7) + ach);
    bf16x8 aL = *(const bf16x8*)(actL + (arow << 7) + ach);
#pragma unroll
    for (int n = 0; n < 2; ++n) {
      const int cl = (half * 2 + n) * 16 + m16;
      int boff = (cl << 7) + ach;
      bf16x8 bH = *(const bf16x8*)(wbH + boff);
      bf16x8 bL = *(const bf16x8*)(wbL + boff);
      MFMA3(acc2[1][n], aH, aL, bH, bL)
    }
  }
  __syncthreads();   // B6: all L2 act/wb reads done

  // ---- L2 epilogue + write W3 ----
#pragma unroll
  for (int hh = 0; hh < 2; ++hh) {
#pragma unroll
    for (int n = 0; n < 2; ++n) {
      const int col = hh * 64 + (half * 2 + n) * 16 + m16;
      const float bias = b2[col];
#pragma unroll
      for (int r = 0; r < 4; ++r) {
        float v = acc2[hh][n][r] + bias; v = v > 0.f ? v : 0.f;
        int idx = SWZ7(row0 + quad * 4 + r, col);
        split2(v, actH[idx], actL[idx]);
      }
    }
  }
#pragma unroll
  for (int i = 0; i < 2; ++i) {
    int q = t + i * 512;
    int coll = q >> 4, c = q & 15;
    int dst = (coll << 7) + ((c ^ (coll & 7)) << 3);
    *(bf16x8*)(wbH + dst) = pH[i];
    *(bf16x8*)(wbL + dst) = pL[i];
  }
  __syncthreads();   // B7

  // ---- layer 3 ----
  {
    f32x4 acc[2];
#pragma unroll
    for (int n = 0; n < 2; ++n) acc[n] = (f32x4){0.f, 0.f, 0.f, 0.f};
#pragma unroll
    for (int kb8 = 0; kb8 < 16; kb8 += 4) {
      int ach = ((quad + kb8) ^ (m16 & 7)) << 3;
      bf16x8 aH = *(const bf16x8*)(actH + (arow << 7) + ach);
      bf16x8 aL = *(const bf16x8*)(actL + (arow << 7) + ach);
#pragma unroll
      for (int n = 0; n < 2; ++n) {
        const int col = (half * 2 + n) * 16 + m16;
        int boff = (col << 7) + ach;
        bf16x8 bH = *(const bf16x8*)(wbH + boff);
        bf16x8 bL = *(const bf16x8*)(wbL + boff);
        MFMA3(acc[n], aH, aL, bH, bL)
      }
    }
#pragma unroll
    for (int n = 0; n < 2; ++n) {
      const int col = (half * 2 + n) * 16 + m16;
      if (col < 50) {
        const float bias = b3[col];
#pragma unroll
        for (int r = 0; r < 4; ++r) {
          int row = row0 + quad * 4 + r;
          x[(base + row) * 51 + col] = acc[n][r] + bias;
        }
      }
    }
  }
}

// ===========================================================================
// k_gq: fused g1 + q + g2. 512 threads. One 64KB LDS pool, phase-aliased:
//   B1: sg1 -> Q -> Zp          B2: T1 -> P -> x1 -> g2 scratch
//   AN: An  -> WkT              W : W1a -> W1b -> {xf, zf, al, sp, yv, ...}
// ===========================================================================
__global__ __launch_bounds__(512) void k_gq(const float* __restrict__ wg2b,
                                            float* __restrict__ ws,
                                            float* __restrict__ out)
{
  __shared__ __align__(16) unsigned short SH[32768];
  unsigned short* b1H = SH;
  unsigned short* b1L = SH + 4096;
  unsigned short* b2H = SH + 8192;
  unsigned short* b2L = SH + 12288;
  unsigned short* anH = SH + 16384;
  unsigned short* anL = SH + 20480;
  unsigned short* wH  = SH + 24576;
  unsigned short* wL  = SH + 28672;
  // late-phase aliases (W region; valid after GEMM4):
  unsigned short* xfH = SH + 24576;
  unsigned short* xfL = SH + 25600;
  unsigned short* zfH = SH + 26624;
  unsigned short* zfL = SH + 27648;
  float* alS  = (float*)(SH + 28672);   // 64*17 = 1088 fl
  float* spH2 = (float*)(SH + 30848);   // 128 fl
  float* spS  = (float*)(SH + 31104);   // 64
  float* sfS  = (float*)(SH + 31232);   // 16
  float* yvS  = (float*)(SH + 31264);   // 64
  float* yhsS = (float*)(SH + 31392);   // 16
  // g2 scratch aliases (B2 region; valid after GEMM5):
  float* X2v  = (float*)(SH + 8192);    // 832 fl
  float* A22v = X2v + 832;              // 256
  float* G2v  = A22v + 256;             // 1024
  float* Pmv  = G2v + 1024;             // 1024
  float* wb2  = Pmv + 1024;             // 64
  float* zzv  = wb2 + 64;               // 16

  const int t = threadIdx.x, b = blockIdx.x;
  const int lane = t & 63, wave = t >> 6;
  const int s = wave & 3, half = wave >> 2;
  const int m16 = lane & 15, quad = lane >> 4;
  const int row0 = s * 16;
  const int arow = row0 + m16;
  const float* x = ws + OFF_X;
  const float* mk = ws + OFF_MK;
  const float* an22 = ws + OFF_AN22;
  const float* g2at = ws + OFF_G2AT;
  const unsigned short* gAnH = (const unsigned short*)(ws + OFF_ANH);
  const unsigned short* gAnL = (const unsigned short*)(ws + OFF_ANL);
  const unsigned short* gaH = (const unsigned short*)(ws + OFF_GAH);
  const unsigned short* gaL = (const unsigned short*)(ws + OFF_GAL);
  const unsigned short* gbH = (const unsigned short*)(ws + OFF_GBH);
  const unsigned short* gbL = (const unsigned short*)(ws + OFF_GBL);
  const unsigned short* gwkH = (const unsigned short*)(ws + OFF_WKH);
  const unsigned short* gwkL = (const unsigned short*)(ws + OFF_WKL);
  const float sc = (ws + OFF_SC)[0];
  float* yh = ws + OFF_YH;

  // ---- P0: stage sg1, An, W1a; keep yv in reg; prefetch W1b ----
  for (int e = t; e < 4096; e += 512) {
    int r = e >> 6, k = e & 63;
    float v = (k < 51) ? x[(b * 80 + r) * 51 + k] : 0.f;
    int idx = SWZ6(r, k);
    split2(v, b1H[idx], b1L[idx]);
  }
  {
    int q = t;
    if (q < 512) {
      int r = q >> 3, c = q & 7;
      int dst = (r << 6) + ((c ^ (r & 7)) << 3);
      int src = (r << 6) + (c << 3);
      *(bf16x8*)(anH + dst) = *(const bf16x8*)(gAnH + src);
      *(bf16x8*)(anL + dst) = *(const bf16x8*)(gAnL + src);
      *(bf16x8*)(wH + dst)  = *(const bf16x8*)(gaH + src);
      *(bf16x8*)(wL + dst)  = *(const bf16x8*)(gaL + src);
    }
  }
  float yvreg = 0.f;
  if (t < 64) yvreg = x[(b * 80 + t) * 51 + 50];
  bf16x8 pH, pL;           // W1b prefetch (consumed post-B2)
  {
    int q = t & 511;
    int r = q >> 3, c = q & 7;
    int src = (r << 6) + (c << 3);
    pH = *(const bf16x8*)(gbH + src);
    pL = *(const bf16x8*)(gbL + src);
  }
  __syncthreads();   // B1

  // ---- GEMM1: T1 = sg1 @ W1a^T ----
  f32x4 accA[2];
#pragma unroll
  for (int n = 0; n < 2; ++n) accA[n] = (f32x4){0.f, 0.f, 0.f, 0.f};
#pragma unroll
  for (int kb8 = 0; kb8 < 8; kb8 += 4) {
    int ach = ((quad + kb8) ^ (m16 & 7)) << 3;
    bf16x8 aH = *(const bf16x8*)(b1H + (arow << 6) + ach);
    bf16x8 aL = *(const bf16x8*)(b1L + (arow << 6) + ach);
#pragma unroll
    for (int n = 0; n < 2; ++n) {
      const int col = (half * 2 + n) * 16 + m16;
      int boff = (col << 6) + ach;
      bf16x8 bH = *(const bf16x8*)(wH + boff);
      bf16x8 bL = *(const bf16x8*)(wL + boff);
      MFMA3(accA[n], aH, aL, bH, bL)
    }
  }
  __syncthreads();   // B2: sg1/W1a reads done

  // ---- E1: T1 -> B2 [col][k]; W1b -> W; prefetch WkT ----
  {
    const int kb = row0 + quad * 4;
#pragma unroll
    for (int n = 0; n < 2; ++n) {
      const int col = (half * 2 + n) * 16 + m16;
      int idx = (col << 6) + (((((kb >> 3) ^ (col & 7)) << 3)) | (kb & 7));
      s16x4 hv, lv;
#pragma unroll
      for (int r = 0; r < 4; ++r) {
        unsigned short hh, ll; split2(accA[n][r], hh, ll);
        hv[r] = (short)hh; lv[r] = (short)ll;
      }
      *(s16x4*)(b2H + idx) = hv; *(s16x4*)(b2L + idx) = lv;
    }
  }
  {
    int q = t & 511;
    int r = q >> 3, c = q & 7;
    int dst = (r << 6) + ((c ^ (r & 7)) << 3);
    *(bf16x8*)(wH + dst) = pH;
    *(bf16x8*)(wL + dst) = pL;
    int src = (r << 6) + (c << 3);
    pH = *(const bf16x8*)(gwkH + src);   // WkT prefetch (consumed post-B6)
    pL = *(const bf16x8*)(gwkL + src);
  }
  __syncthreads();   // B3

  // ---- GEMM2: P = relu(An @ T1) ----
#pragma unroll
  for (int n = 0; n < 2; ++n) accA[n] = (f32x4){0.f, 0.f, 0.f, 0.f};
#pragma unroll
  for (int kb8 = 0; kb8 < 8; kb8 += 4) {
    int ach = ((quad + kb8) ^ (m16 & 7)) << 3;
    bf16x8 aH = *(const bf16x8*)(anH + (arow << 6) + ach);
    bf16x8 aL = *(const bf16x8*)(anL + (arow << 6) + ach);
#pragma unroll
    for (int n = 0; n < 2; ++n) {
      const int col = (half * 2 + n) * 16 + m16;
      int boff = (col << 6) + ach;
      bf16x8 bH = *(const bf16x8*)(b2H + boff);
      bf16x8 bL = *(const bf16x8*)(b2L + boff);
      MFMA3(accA[n], aH, aL, bH, bL)
    }
  }
  __syncthreads();   // B4: T1 reads done

  // ---- E2: P -> B2 ----
  {
    const int kb = row0 + quad * 4;
#pragma unroll
    for (int n = 0; n < 2; ++n) {
      const int col = (half * 2 + n) * 16 + m16;
      int idx = (col << 6) + (((((kb >> 3) ^ (col & 7)) << 3)) | (kb & 7));
      s16x4 hv, lv;
#pragma unroll
      for (int r = 0; r < 4; ++r) {
        float v = accA[n][r]; v = v > 0.f ? v : 0.f;
        unsigned short hh, ll; split2(v, hh, ll);
        hv[r] = (short)hh; lv[r] = (short)ll;
      }
      *(s16x4*)(b2H + idx) = hv; *(s16x4*)(b2L + idx) = lv;
    }
  }
  __syncthreads();   // B5

  // ---- GEMM3: Q = An @ P ----
#pragma unroll
  for (int n = 0; n < 2; ++n) accA[n] = (f32x4){0.f, 0.f, 0.f, 0.f};
#pragma unroll
  for (int kb8 = 0; kb8 < 8; kb8 += 4) {
    int ach = ((quad + kb8) ^ (m16 & 7)) << 3;
    bf16x8 aH = *(const bf16x8*)(anH + (arow << 6) + ach);
    bf16x8 aL = *(const bf16x8*)(anL + (arow << 6) + ach);
#pragma unroll
    for (int n = 0; n < 2; ++n) {
      const int col = (half * 2 + n) * 16 + m16;
      int boff = (col << 6) + ach;
      bf16x8 bH = *(const bf16x8*)(b2H + boff);
      bf16x8 bL = *(const bf16x8*)(b2L + boff);
      MFMA3(accA[n], aH, aL, bH, bL)
    }
  }
  __syncthreads();   // B6: An + P reads done

  // ---- E3: Q -> B1 [row][k]; WkT -> AN ----
#pragma unroll
  for (int n = 0; n < 2; ++n) {
    const int col = (half * 2 + n) * 16 + m16;
#pragma unroll
    for (int r = 0; r < 4; ++r) {
      int idx = SWZ6(row0 + quad * 4 + r, col);
      split2(accA[n][r], b1H[idx], b1L[idx]);
    }
  }
  {
    int q = t & 511;
    int r = q >> 3, c = q & 7;
    int dst = (r << 6) + ((c ^ (r & 7)) << 3);
    *(bf16x8*)(anH + dst) = pH;
    *(bf16x8*)(anL + dst) = pL;
  }
  // prefetch xf (2 scalars per thread; consumed at E4)
  float xf0 = 0.f, xf1 = 0.f;
  {
    int e0 = t, e1 = t + 512;
    int r0r = e0 >> 6, c0 = e0 & 63;
    int r1r = e1 >> 6, c1 = e1 & 63;
    if (c0 < 50) xf0 = x[(b * 80 + 64 + r0r) * 51 + c0];
    if (c1 < 50) xf1 = x[(b * 80 + 64 + r1r) * 51 + c1];
  }
  __syncthreads();   // B7

  // ---- GEMM4: x1 = Q @ W1b^T ----
#pragma unroll
  for (int n = 0; n < 2; ++n) accA[n] = (f32x4){0.f, 0.f, 0.f, 0.f};
#pragma unroll
  for (int kb8 = 0; kb8 < 8; kb8 += 4) {
    int ach = ((quad + kb8) ^ (m16 & 7)) << 3;
    bf16x8 aH = *(const bf16x8*)(b1H + (arow << 6) + ach);
    bf16x8 aL = *(const bf16x8*)(b1L + (arow << 6) + ach);
#pragma unroll
    for (int n = 0; n < 2; ++n) {
      const int col = (half * 2 + n) * 16 + m16;
      int boff = (col << 6) + ach;
      bf16x8 bH = *(const bf16x8*)(wH + boff);
      bf16x8 bL = *(const bf16x8*)(wL + boff);
      MFMA3(accA[n], aH, aL, bH, bL)
    }
  }
  __syncthreads();   // B8: Q + W1b reads done (W region free)

  // ---- E4: x1 -> B2 [row][k]; xf -> XF; yv -> yvS ----
#pragma unroll
  for (int n = 0; n < 2; ++n) {
    const int col = (half * 2 + n) * 16 + m16;
#pragma unroll
    for (int r = 0; r < 4; ++r) {
      int idx = SWZ6(row0 + quad * 4 + r, col);
      split2(accA[n][r], b2H[idx], b2L[idx]);
    }
  }
  {
    int e0 = t, e1 = t + 512;
    int i0 = SWZ6(e0 >> 6, e0 & 63);
    int i1 = SWZ6(e1 >> 6, e1 & 63);
    split2(xf0, xfH[i0], xfL[i0]);
    split2(xf1, xfH[i1], xfL[i1]);
  }
  if (t < 64) yvS[t] = yvreg;
  __syncthreads();   // B9

  // ---- GEMM5: Zp = x1 @ WkT (4-term); Zf on half0; sp via shuffles ----
#pragma unroll
  for (int n = 0; n < 2; ++n) accA[n] = (f32x4){0.f, 0.f, 0.f, 0.f};
#pragma unroll
  for (int kb8 = 0; kb8 < 8; kb8 += 4) {
    int ach = ((quad + kb8) ^ (m16 & 7)) << 3;
    bf16x8 aH = *(const bf16x8*)(b2H + (arow << 6) + ach);
    bf16x8 aL = *(const bf16x8*)(b2L + (arow << 6) + ach);
#pragma unroll
    for (int n = 0; n < 2; ++n) {
      const int col = (half * 2 + n) * 16 + m16;
      int boff = (col << 6) + ach;
      bf16x8 bH = *(const bf16x8*)(anH + boff);
      bf16x8 bL = *(const bf16x8*)(anL + boff);
      MFMA4(accA[n], aH, aL, bH, bL)
    }
  }
  if (half == 0) {   // Zf = xf @ WkT: wave s computes h-frag s
    f32x4 af = (f32x4){0.f, 0.f, 0.f, 0.f};
#pragma unroll
    for (int kb8 = 0; kb8 < 8; kb8 += 4) {
      int ach = ((quad + kb8) ^ (m16 & 7)) << 3;
      bf16x8 aH = *(const bf16x8*)(xfH + (m16 << 6) + ach);
      bf16x8 aL = *(const bf16x8*)(xfL + (m16 << 6) + ach);
      const int col = s * 16 + m16;
      int boff = (col << 6) + ach;
      bf16x8 bH = *(const bf16x8*)(anH + boff);
      bf16x8 bL = *(const bf16x8*)(anL + boff);
      MFMA4(af, aH, aL, bH, bL)
    }
    const int h = s * 16 + m16;
#pragma unroll
    for (int r = 0; r < 4; ++r) {
      int idx = SWZ6(quad * 4 + r, h);
      split2(af[r], zfH[idx], zfL[idx]);
    }
  }
  // Zp epilogue: write to B1 + sp partial via in-quad shuffle reduce
  {
    float s2[4];
#pragma unroll
    for (int r = 0; r < 4; ++r)
      s2[r] = accA[0][r] * accA[0][r] + accA[1][r] * accA[1][r];
#pragma unroll
    for (int n = 0; n < 2; ++n) {
      const int h = (half * 2 + n) * 16 + m16;
#pragma unroll
      for (int r = 0; r < 4; ++r) {
        int idx = SWZ6(row0 + quad * 4 + r, h);
        split2(accA[n][r], b1H[idx], b1L[idx]);
      }
    }
#pragma unroll
    for (int m = 1; m < 16; m <<= 1)
#pragma unroll
      for (int r = 0; r < 4; ++r) s2[r] += __shfl_xor(s2[r], m);
    if (m16 == 0) {
#pragma unroll
      for (int r = 0; r < 4; ++r)
        spH2[(row0 + quad * 4 + r) * 2 + half] = s2[r];
    }
  }
  __syncthreads();   // B10

  if (t < 64) {
    spS[t] = spH2[t * 2] + spH2[t * 2 + 1];
  } else if (t < 80) {
    int j = t - 64;
    float ssum = 0.f;
    for (int h = 0; h < 64; ++h) {
      int idx = SWZ6(j, h);
      float v = bf2f(zfH[idx]) + bf2f(zfL[idx]);
      ssum += v * v;
    }
    sfS[j] = ssum;
  }
  __syncthreads();   // B11

  // ---- GEMM6: cross = Zp @ Zf^T (4-term); half0 writes al ----
  {
    f32x4 ac2 = (f32x4){0.f, 0.f, 0.f, 0.f};
#pragma unroll
    for (int kb8 = 0; kb8 < 8; kb8 += 4) {
      int ach = ((quad + kb8) ^ (m16 & 7)) << 3;
      bf16x8 aH = *(const bf16x8*)(b1H + (arow << 6) + ach);
      bf16x8 aL = *(const bf16x8*)(b1L + (arow << 6) + ach);
      bf16x8 bH = *(const bf16x8*)(zfH + (m16 << 6) + ach);
      bf16x8 bL = *(const bf16x8*)(zfL + (m16 << 6) + ach);
      MFMA4(ac2, aH, aL, bH, bL)
    }
    if (half == 0) {
#pragma unroll
      for (int r = 0; r < 4; ++r) {
        int i = row0 + quad * 4 + r;
        alS[i * 17 + m16] = sc * (spS[i] + sfS[m16] - 2.f * ac2[r]);
      }
    }
  }
  __syncthreads();   // B12

  // ---- masked softmax over j per i ----
  if (t < 64) {
    const int i = t;
    float lv[16];
    float m = -3.4e38f;
#pragma unroll
    for (int j = 0; j < 16; ++j) {
      float v = (mk[j * 64 + i] != 0.f) ? alS[i * 17 + j] : NEGBIG;
      lv[j] = v;
      m = fmaxf(m, v);
    }
    float ssum = 0.f;
#pragma unroll
    for (int j = 0; j < 16; ++j) { lv[j] = expf(lv[j] - m); ssum += lv[j]; }
    float inv = 1.f / ssum;
#pragma unroll
    for (int j = 0; j < 16; ++j) alS[i * 17 + j] = lv[j] * inv;
  }
  __syncthreads();   // B13

  if (t < 16) {
    float ssum = 0.f;
    for (int i = 0; i < 64; ++i) ssum += alS[i * 17 + t] * yvS[i];
    yh[b * 16 + t] = ssum;
    yhsS[t] = ssum;
  }
  __syncthreads();   // B14

  // ---- fused g2 (scratch in B2 region; x1 dead after GEMM5) ----
  for (int e = t; e < 832; e += 512) {
    int r = e / 52, c = e - r * 52;
    float v = 0.f;
    if (c < 50)       v = x[(b * 80 + 64 + r) * 51 + c];
    else if (c == 50) v = yhsS[r];
    X2v[e] = v;
  }
  for (int e = t; e < 256; e += 512) A22v[e] = an22[e];
  if (t < 64) wb2[t] = wg2b[t];
  __syncthreads();   // B15
  for (int e = t; e < 1024; e += 512) {
    int j = e >> 6, h = e & 63;
    float ssum = 0.f;
    for (int k = 0; k < 51; ++k) ssum += X2v[j * 52 + k] * g2at[k * 64 + h];
    G2v[e] = ssum;
  }
  __syncthreads();   // B16
  for (int e = t; e < 1024; e += 512) {
    int j = e >> 6, h = e & 63;
    float ssum = 0.f;
#pragma unroll
    for (int k = 0; k < 16; ++k) ssum += A22v[j * 16 + k] * G2v[k * 64 + h];
    Pmv[e] = ssum > 0.f ? ssum : 0.f;
  }
  __syncthreads();   // B17
  if (t < 16) {
    float ssum = 0.f;
    for (int h = 0; h < 64; ++h) ssum += Pmv[t * 64 + h] * wb2[h];
    zzv[t] = ssum;
  }
  __syncthreads();   // B18
  if (t < 16) {
    float ssum = 0.f;
#pragma unroll
    for (int k = 0; k < 16; ++k) ssum += A22v[t * 16 + k] * zzv[k];
    out[OUT_OUT + b * 16 + t] = ssum;
  }
}

// ===========================================================================
// k_dist (unchanged from round 7)
// ===========================================================================
__global__ __launch_bounds__(320) void k_dist(float* __restrict__ ws,
                                              float* __restrict__ out)
{
  __shared__ __align__(16) unsigned short xcH[5120], xcL[5120];
  __shared__ float sq[80];
  const int t = threadIdx.x, b = blockIdx.x;
  const int lane = t & 63, wave = t >> 6;
  const int m16 = lane & 15, quad = lane >> 4;
  const int row0 = wave * 16;
  const int arow = row0 + m16;
  const float* x = ws + OFF_X;
  const float* yhg = ws + OFF_YH;
  float* dist = out + OUT_DIST + b * 6400;

  for (int e = t; e < 5120; e += 320) {
    int n = e >> 6, c = e & 63;
    float v = 0.f;
    if (c < 50)       v = x[(b * 80 + n) * 51 + c];
    else if (c == 50) v = (n < 64) ? x[(b * 80 + n) * 51 + 50] : yhg[b * 16 + (n - 64)];
    int idx = SWZ6(n, c);
    split2(v, xcH[idx], xcL[idx]);
  }
  __syncthreads();

  f32x4 acc[5];
#pragma unroll
  for (int n = 0; n < 5; ++n) acc[n] = (f32x4){0.f, 0.f, 0.f, 0.f};
#pragma unroll
  for (int kb8 = 0; kb8 < 8; kb8 += 4) {
    int ach = ((quad + kb8) ^ (m16 & 7)) << 3;
    bf16x8 aH = *(const bf16x8*)(xcH + (arow << 6) + ach);
    bf16x8 aL = *(const bf16x8*)(xcL + (arow << 6) + ach);
#pragma unroll
    for (int nf = 0; nf < 5; ++nf) {
      const int col = nf * 16 + m16;
      int boff = (col << 6) + ach;
      bf16x8 bH = *(const bf16x8*)(xcH + boff);
      bf16x8 bL = *(const bf16x8*)(xcL + boff);
      MFMA3(acc[nf], aH, aL, bH, bL)
    }
  }
  if ((m16 >> 2) == quad) sq[row0 + m16] = acc[wave][m16 & 3];
  __syncthreads();

#pragma unroll
  for (int nf = 0; nf < 5; ++nf) {
    const int m = nf * 16 + m16;
#pragma unroll
    for (int r = 0; r < 4; ++r) {
      int i = row0 + quad * 4 + r;
      float d2 = sq[i] + sq[m] - 2.f * acc[nf][r];
      d2 = d2 > 0.f ? d2 : 0.f;
      dist[i * 80 + m] = d2 > 0.f ? sqrtf(d2) : 0.f;
    }
  }
}

// ===========================================================================
extern "C" void kernel_launch(void* const* d_in, const int* in_sizes, int n_in,
                              void* d_out, int out_size, void* d_ws, size_t ws_size,
                              hipStream_t stream)
{
  const float* data = (const float*)d_in[0];
  const float* emb0 = (const float*)d_in[1];
  const float* emb1 = (const float*)d_in[2];
  const float* emb2 = (const float*)d_in[3];
  const float* w1   = (const float*)d_in[4];
  const float* b1   = (const float*)d_in[5];
  const float* w2   = (const float*)d_in[6];
  const float* b2   = (const float*)d_in[7];
  const float* w3   = (const float*)d_in[8];
  const float* b3   = (const float*)d_in[9];
  const float* M    = (const float*)d_in[10];
  const float* wg1a = (const float*)d_in[11];
  const float* wg1b = (const float*)d_in[12];
  const float* Wk   = (const float*)d_in[13];
  const float* smo  = (const float*)d_in[14];
  const float* wg2a = (const float*)d_in[15];
  const float* wg2b = (const float*)d_in[16];
  float* ws  = (float*)d_ws;
  float* out = (float*)d_out;

  k_prep<<<dim3(4),    dim3(256), 0, stream>>>(M, Wk, smo, w1, w2, w3, wg1a, wg1b, wg2a, ws, out);
  k_mlp <<<dim3(1280), dim3(512), 0, stream>>>(data, emb0, emb1, emb2, b1, b2, b3, ws);
  k_gq  <<<dim3(1024), dim3(512), 0, stream>>>(wg2b, ws, out);
  k_dist<<<dim3(1024), dim3(320), 0, stream>>>(ws, out);
}

// Round 9
// 210.323 us; speedup vs baseline: 1.8303x; 1.0155x over previous
//
#include <hip/hip_runtime.h>
#include <math.h>

// ---------------------------------------------------------------------------
// GAT_23613730193923 — round 9: k_dist fused into k_gq (-> k_gqd): one fewer
// device-wide sync; dist Gram runs out of reused LDS regions after yh.
// k_prep / k_mlp unchanged from round 8.
// ---------------------------------------------------------------------------

#define NEGBIG (-1e30f)

// ---- workspace offsets (floats) ----
#define OFF_X     0          // B*80*51 = 4177920
#define OFF_A     7471104    // 80*80
#define OFF_AN22  7481600    // 16*16
#define OFF_MK    7484356    // 16*64
#define OFF_GAH   7514692    // W1a hi: 64*64 ushort
#define OFF_GAL   7516740
#define OFF_G2AT  7521156    // 51*64 fp32
#define OFF_SC    7524420    // 1
#define OFF_W1H   7524424    // 128*64 ushort
#define OFF_W1L   7528520
#define OFF_W2H   7532616    // 128*128 ushort
#define OFF_W2L   7540808
#define OFF_W3H   7549000    // 64*128 ushort
#define OFF_W3L   7553096
#define OFF_ANH   7557192    // An11 hi: 64*64 ushort
#define OFF_ANL   7559240
#define OFF_GBH   7561288    // W1b hi: 64*64 ushort
#define OFF_GBL   7563336
#define OFF_WKH   7565384    // Wk^T hi: [h=64][o=64] ushort
#define OFF_WKL   7567432

// ---- output offsets (floats): (out B*16, dist B*6400, A 6400) ----
#define OUT_OUT   0
#define OUT_DIST  16384
#define OUT_A     6569984

typedef __attribute__((ext_vector_type(8))) short bf16x8;
typedef __attribute__((ext_vector_type(4))) short s16x4;
typedef __attribute__((ext_vector_type(4))) float f32x4;

__device__ __forceinline__ unsigned short f2bf(float x) {  // RTN
  union { float f; unsigned u; } v; v.f = x;
  unsigned r = v.u + 0x7fffu + ((v.u >> 16) & 1u);
  return (unsigned short)(r >> 16);
}
__device__ __forceinline__ float bf2f(unsigned short h) {
  union { unsigned u; float f; } v; v.u = ((unsigned)h) << 16; return v.f;
}
__device__ __forceinline__ void split2(float v, unsigned short& h, unsigned short& l) {
  unsigned short hh = f2bf(v);
  h = hh;
  l = f2bf(v - bf2f(hh));
}
#define SWZ6(r, k) (((r) << 6) + (((((k) >> 3) ^ ((r) & 7)) << 3) | ((k) & 7)))
#define SWZ7(r, k) (((r) << 7) + (((((k) >> 3) ^ ((r) & 7)) << 3) | ((k) & 7)))

#define MFMA3(acc, aH, aL, bH, bL) \
  acc = __builtin_amdgcn_mfma_f32_16x16x32_bf16(aH, bH, acc, 0, 0, 0); \
  acc = __builtin_amdgcn_mfma_f32_16x16x32_bf16(aH, bL, acc, 0, 0, 0); \
  acc = __builtin_amdgcn_mfma_f32_16x16x32_bf16(aL, bH, acc, 0, 0, 0);
#define MFMA4(acc, aH, aL, bH, bL) \
  MFMA3(acc, aH, aL, bH, bL) \
  acc = __builtin_amdgcn_mfma_f32_16x16x32_bf16(aL, bL, acc, 0, 0, 0);

// ===========================================================================
// k_prep (unchanged)
// ===========================================================================
__global__ __launch_bounds__(256) void k_prep(
    const float* __restrict__ M, const float* __restrict__ Wk,
    const float* __restrict__ sm,
    const float* __restrict__ w1, const float* __restrict__ w2,
    const float* __restrict__ w3,
    const float* __restrict__ wg1a, const float* __restrict__ wg1b,
    const float* __restrict__ wg2a,
    float* __restrict__ ws, float* __restrict__ out)
{
  __shared__ float Msh[80 * 26];
  __shared__ float Ash[80 * 80];
  __shared__ float d1[64];
  __shared__ float d2s[16];
  const int t = threadIdx.x;

  if (blockIdx.x == 0) {
    for (int e = t; e < 80 * 26; e += 256) Msh[e] = M[e];
    __syncthreads();
    for (int e = t; e < 6400; e += 256) {
      int i = e / 80, j = e % 80;
      float v = 0.f;
      if (j < i) {
        float s = 0.f;
        for (int k = 0; k < 26; ++k) s += Msh[i * 26 + k] * Msh[j * 26 + k];
        v = s > 0.f ? s : 0.f;
      }
      Ash[e] = v;
    }
    __syncthreads();
    if (t > 0 && t < 80) {
      int i = t;
      float m = -3.4e38f;
      for (int j = 0; j < i; ++j) m = fmaxf(m, Ash[i * 80 + j]);
      float s = 0.f;
      for (int j = 0; j < i; ++j) {
        float e = expf(Ash[i * 80 + j] - m);
        Ash[i * 80 + j] = e;
        s += e;
      }
      float inv = 1.f / s;
      for (int j = 0; j < i; ++j) Ash[i * 80 + j] *= inv;
    }
    __syncthreads();
    {
      float* Aws = ws + OFF_A;
      float* Aout = out + OUT_A;
      for (int e = t; e < 6400; e += 256) { Aws[e] = Ash[e]; Aout[e] = Ash[e]; }
    }
    if (t < 64) {
      int c = 0;
      for (int j = 0; j < 64; ++j) if (Ash[t * 80 + j] > 1e-15f) ++c;
      d1[t] = 1.f / sqrtf(1.f + (float)c);
    } else if (t < 80) {
      int i = t - 64; int c = 0;
      for (int j = 0; j < 16; ++j) if (Ash[(64 + i) * 80 + 64 + j] > 1e-15f) ++c;
      d2s[i] = 1.f / sqrtf(1.f + (float)c);
    }
    __syncthreads();
    {
      float* an22 = ws + OFF_AN22;
      unsigned short* anH = (unsigned short*)(ws + OFF_ANH);
      unsigned short* anL = (unsigned short*)(ws + OFF_ANL);
      for (int e = t; e < 4096; e += 256) {
        int i = e >> 6, j = e & 63;
        float v = d1[i] * Ash[i * 80 + j] * d1[j];
        unsigned short h = f2bf(v);
        anH[e] = h; anL[e] = f2bf(v - bf2f(h));
      }
      for (int e = t; e < 256; e += 256) {
        int i = e >> 4, j = e & 15;
        an22[e] = d2s[i] * Ash[(64 + i) * 80 + 64 + j] * d2s[j];
      }
    }
    if (t < 16) {
      float* mk = ws + OFF_MK;
      int j = t;
      float m = -3.4e38f;
      for (int i = 0; i < 64; ++i) {
        float v = Ash[(64 + j) * 80 + i];
        v = (v != 0.f) ? v : NEGBIG;
        m = fmaxf(m, v);
      }
      float s = 0.f;
      for (int i = 0; i < 64; ++i) {
        float v = Ash[(64 + j) * 80 + i];
        v = (v != 0.f) ? v : NEGBIG;
        s += expf(v - m);
      }
      float inv = 1.f / s;
      for (int i = 0; i < 64; ++i) {
        float v = Ash[(64 + j) * 80 + i];
        v = (v != 0.f) ? v : NEGBIG;
        mk[j * 64 + i] = (expf(v - m) * inv >= 0.004f) ? 1.f : 0.f;
      }
    }
  } else if (blockIdx.x == 1) {
    unsigned short* wkh = (unsigned short*)(ws + OFF_WKH);
    unsigned short* wkl = (unsigned short*)(ws + OFF_WKL);
    for (int e = t; e < 4096; e += 256) {
      int h = e >> 6, o = e & 63;
      float v = (o < 50) ? Wk[o * 64 + h] : 0.f;
      unsigned short hh = f2bf(v);
      wkh[e] = hh; wkl[e] = f2bf(v - bf2f(hh));
    }
    if (t == 0) {
      float v = sm[0];
      float sig = 1.f / (1.f + expf(-v));
      (ws + OFF_SC)[0] = -0.5f / (sig * 0.01f);
    }
  } else if (blockIdx.x == 2) {
    unsigned short* w1h = (unsigned short*)(ws + OFF_W1H);
    unsigned short* w1l = (unsigned short*)(ws + OFF_W1L);
    for (int e = t; e < 8192; e += 256) {
      int n = e >> 6, k = e & 63;
      float v = (k < 51) ? w1[n * 51 + k] : 0.f;
      unsigned short h = f2bf(v);
      w1h[e] = h; w1l[e] = f2bf(v - bf2f(h));
    }
    unsigned short* w3h = (unsigned short*)(ws + OFF_W3H);
    unsigned short* w3l = (unsigned short*)(ws + OFF_W3L);
    for (int e = t; e < 8192; e += 256) {
      int n = e >> 7, k = e & 127;
      float v = (n < 50) ? w3[n * 128 + k] : 0.f;
      unsigned short h = f2bf(v);
      w3h[e] = h; w3l[e] = f2bf(v - bf2f(h));
    }
    unsigned short* gah = (unsigned short*)(ws + OFF_GAH);
    unsigned short* gal = (unsigned short*)(ws + OFF_GAL);
    for (int e = t; e < 4096; e += 256) {
      int n = e >> 6, k = e & 63;
      float v = (k < 51) ? wg1a[n * 51 + k] : 0.f;
      unsigned short h = f2bf(v);
      gah[e] = h; gal[e] = f2bf(v - bf2f(h));
    }
  } else {
    unsigned short* w2h = (unsigned short*)(ws + OFF_W2H);
    unsigned short* w2l = (unsigned short*)(ws + OFF_W2L);
    for (int e = t; e < 16384; e += 256) {
      int n = e >> 7, k = e & 127;
      float v = w2[n * 128 + k];
      unsigned short h = f2bf(v);
      w2h[e] = h; w2l[e] = f2bf(v - bf2f(h));
    }
    unsigned short* gbh = (unsigned short*)(ws + OFF_GBH);
    unsigned short* gbl = (unsigned short*)(ws + OFF_GBL);
    for (int e = t; e < 4096; e += 256) {
      int n = e >> 6, k = e & 63;
      float v = (n < 50) ? wg1b[n * 64 + k] : 0.f;
      unsigned short h = f2bf(v);
      gbh[e] = h; gbl[e] = f2bf(v - bf2f(h));
    }
    float* g2at = ws + OFF_G2AT;
    for (int e = t; e < 64 * 51; e += 256) { int o = e / 51, k = e % 51; g2at[k * 64 + o] = wg2a[e]; }
  }
}

// ===========================================================================
// k_mlp (unchanged from round 8)
// ===========================================================================
__global__ __launch_bounds__(512) void k_mlp(
    const float* __restrict__ data,
    const float* __restrict__ emb0, const float* __restrict__ emb1,
    const float* __restrict__ emb2,
    const float* __restrict__ b1, const float* __restrict__ b2,
    const float* __restrict__ b3,
    float* __restrict__ ws)
{
  __shared__ __align__(16) unsigned short actH[64 * 128];
  __shared__ __align__(16) unsigned short actL[64 * 128];
  __shared__ __align__(16) unsigned short wbH[8192];
  __shared__ __align__(16) unsigned short wbL[8192];
  const int t = threadIdx.x;
  const int lane = t & 63, wave = t >> 6;
  const int s = wave & 3, half = wave >> 2;
  const int m16 = lane & 15, quad = lane >> 4;
  const int base = blockIdx.x * 64;
  const int row0 = s * 16;
  const int arow = row0 + m16;
  const unsigned short* w1h = (const unsigned short*)(ws + OFF_W1H);
  const unsigned short* w1l = (const unsigned short*)(ws + OFF_W1L);
  const unsigned short* w2h = (const unsigned short*)(ws + OFF_W2H);
  const unsigned short* w2l = (const unsigned short*)(ws + OFF_W2L);
  const unsigned short* w3h = (const unsigned short*)(ws + OFF_W3H);
  const unsigned short* w3l = (const unsigned short*)(ws + OFF_W3L);
  float* x = ws + OFF_X;

  for (int e = t; e < 4096; e += 512) {
    int r = e >> 6, c = e & 63;
    int g = base + r;
    float v = 0.f;
    if (c < 32)      { int i0 = (int)data[g * 6 + 0]; v = emb0[i0 * 32 + c]; }
    else if (c < 40) { int i1 = (int)data[g * 6 + 1]; v = emb1[i1 * 8 + (c - 32)]; }
    else if (c < 48) { int i2 = (int)data[g * 6 + 2]; v = emb2[i2 * 8 + (c - 40)]; }
    else if (c < 51) { v = data[g * 6 + 3 + (c - 48)]; }
    int idx = SWZ7(r, c);
    split2(v, actH[idx], actL[idx]);
  }
  for (int q = t; q < 1024; q += 512) {
    int col = q >> 3, c = q & 7;
    int dst = (col << 6) + ((c ^ (col & 7)) << 3);
    *(bf16x8*)(wbH + dst) = *(const bf16x8*)(w1h + (col << 6) + (c << 3));
    *(bf16x8*)(wbL + dst) = *(const bf16x8*)(w1l + (col << 6) + (c << 3));
  }
  bf16x8 pH[2], pL[2];
#pragma unroll
  for (int i = 0; i < 2; ++i) {          // W2 half0
    int q = t + i * 512;
    int coll = q >> 4, c = q & 15;
    int src = (coll << 7) + (c << 3);
    pH[i] = *(const bf16x8*)(w2h + src);
    pL[i] = *(const bf16x8*)(w2l + src);
  }
  if (t < 64) x[(base + t) * 51 + 50] = data[(base + t) * 6 + 5];
  __syncthreads();   // B1

  // layer 1
  {
    f32x4 acc[4];
#pragma unroll
    for (int n = 0; n < 4; ++n) acc[n] = (f32x4){0.f, 0.f, 0.f, 0.f};
#pragma unroll
    for (int kb8 = 0; kb8 < 8; kb8 += 4) {
      int ach = ((quad + kb8) ^ (m16 & 7)) << 3;
      bf16x8 aH = *(const bf16x8*)(actH + (arow << 7) + ach);
      bf16x8 aL = *(const bf16x8*)(actL + (arow << 7) + ach);
#pragma unroll
      for (int n = 0; n < 4; ++n) {
        const int col = (half * 4 + n) * 16 + m16;
        int boff = (col << 6) + ach;
        bf16x8 bH = *(const bf16x8*)(wbH + boff);
        bf16x8 bL = *(const bf16x8*)(wbL + boff);
        MFMA3(acc[n], aH, aL, bH, bL)
      }
    }
#pragma unroll
    for (int n = 0; n < 4; ++n) {
      const int col = (half * 4 + n) * 16 + m16;
      const float bias = b1[col];
#pragma unroll
      for (int r = 0; r < 4; ++r) {
        float v = acc[n][r] + bias; v = v > 0.f ? v : 0.f;
        int idx = SWZ7(row0 + quad * 4 + r, col);
        split2(v, actH[idx], actL[idx]);
      }
    }
  }
  __syncthreads();   // B2

#pragma unroll
  for (int i = 0; i < 2; ++i) {
    int q = t + i * 512;
    int coll = q >> 4, c = q & 15;
    int dst = (coll << 7) + ((c ^ (coll & 7)) << 3);
    *(bf16x8*)(wbH + dst) = pH[i];
    *(bf16x8*)(wbL + dst) = pL[i];
  }
#pragma unroll
  for (int i = 0; i < 2; ++i) {          // W2 half1
    int q = t + i * 512;
    int coll = q >> 4, c = q & 15;
    int src = ((64 + coll) << 7) + (c << 3);
    pH[i] = *(const bf16x8*)(w2h + src);
    pL[i] = *(const bf16x8*)(w2l + src);
  }
  __syncthreads();   // B3

  f32x4 acc2[2][2];
#pragma unroll
  for (int a2 = 0; a2 < 2; ++a2)
#pragma unroll
    for (int n = 0; n < 2; ++n) acc2[a2][n] = (f32x4){0.f, 0.f, 0.f, 0.f};
#pragma unroll
  for (int kb8 = 0; kb8 < 16; kb8 += 4) {
    int ach = ((quad + kb8) ^ (m16 & 7)) << 3;
    bf16x8 aH = *(const bf16x8*)(actH + (arow << 7) + ach);
    bf16x8 aL = *(const bf16x8*)(actL + (arow << 7) + ach);
#pragma unroll
    for (int n = 0; n < 2; ++n) {
      const int cl = (half * 2 + n) * 16 + m16;
      int boff = (cl << 7) + ach;
      bf16x8 bH = *(const bf16x8*)(wbH + boff);
      bf16x8 bL = *(const bf16x8*)(wbL + boff);
      MFMA3(acc2[0][n], aH, aL, bH, bL)
    }
  }
  __syncthreads();   // B4

#pragma unroll
  for (int i = 0; i < 2; ++i) {
    int q = t + i * 512;
    int coll = q >> 4, c = q & 15;
    int dst = (coll << 7) + ((c ^ (coll & 7)) << 3);
    *(bf16x8*)(wbH + dst) = pH[i];
    *(bf16x8*)(wbL + dst) = pL[i];
  }
#pragma unroll
  for (int i = 0; i < 2; ++i) {          // W3
    int q = t + i * 512;
    int coll = q >> 4, c = q & 15;
    int src = (coll << 7) + (c << 3);
    pH[i] = *(const bf16x8*)(w3h + src);
    pL[i] = *(const bf16x8*)(w3l + src);
  }
  __syncthreads();   // B5

#pragma unroll
  for (int kb8 = 0; kb8 < 16; kb8 += 4) {
    int ach = ((quad + kb8) ^ (m16 & 7)) << 3;
    bf16x8 aH = *(const bf16x8*)(actH + (arow << 7) + ach);
    bf16x8 aL = *(const bf16x8*)(actL + (arow << 7) + ach);
#pragma unroll
    for (int n = 0; n < 2; ++n) {
      const int cl = (half * 2 + n) * 16 + m16;
      int boff = (cl << 7) + ach;
      bf16x8 bH = *(const bf16x8*)(wbH + boff);
      bf16x8 bL = *(const bf16x8*)(wbL + boff);
      MFMA3(acc2[1][n], aH, aL, bH, bL)
    }
  }
  __syncthreads();   // B6

#pragma unroll
  for (int hh = 0; hh < 2; ++hh) {
#pragma unroll
    for (int n = 0; n < 2; ++n) {
      const int col = hh * 64 + (half * 2 + n) * 16 + m16;
      const float bias = b2[col];
#pragma unroll
      for (int r = 0; r < 4; ++r) {
        float v = acc2[hh][n][r] + bias; v = v > 0.f ? v : 0.f;
        int idx = SWZ7(row0 + quad * 4 + r, col);
        split2(v, actH[idx], actL[idx]);
      }
    }
  }
#pragma unroll
  for (int i = 0; i < 2; ++i) {
    int q = t + i * 512;
    int coll = q >> 4, c = q & 15;
    int dst = (coll << 7) + ((c ^ (coll & 7)) << 3);
    *(bf16x8*)(wbH + dst) = pH[i];
    *(bf16x8*)(wbL + dst) = pL[i];
  }
  __syncthreads();   // B7

  {
    f32x4 acc[2];
#pragma unroll
    for (int n = 0; n < 2; ++n) acc[n] = (f32x4){0.f, 0.f, 0.f, 0.f};
#pragma unroll
    for (int kb8 = 0; kb8 < 16; kb8 += 4) {
      int ach = ((quad + kb8) ^ (m16 & 7)) << 3;
      bf16x8 aH = *(const bf16x8*)(actH + (arow << 7) + ach);
      bf16x8 aL = *(const bf16x8*)(actL + (arow << 7) + ach);
#pragma unroll
      for (int n = 0; n < 2; ++n) {
        const int col = (half * 2 + n) * 16 + m16;
        int boff = (col << 7) + ach;
        bf16x8 bH = *(const bf16x8*)(wbH + boff);
        bf16x8 bL = *(const bf16x8*)(wbL + boff);
        MFMA3(acc[n], aH, aL, bH, bL)
      }
    }
#pragma unroll
    for (int n = 0; n < 2; ++n) {
      const int col = (half * 2 + n) * 16 + m16;
      if (col < 50) {
        const float bias = b3[col];
#pragma unroll
        for (int r = 0; r < 4; ++r) {
          int row = row0 + quad * 4 + r;
          x[(base + row) * 51 + col] = acc[n][r] + bias;
        }
      }
    }
  }
}

// ===========================================================================
// k_gqd: fused g1 + q + g2 + dist. 512 threads, 1 batch/block, 64KB LDS.
// Regions: B1: sg1->Q->Zp->xcH | B2: T1->P->x1->g2 scratch
//          AN: An->WkT->xcL+sq | W: W1a->W1b->{xf,zf,al,sp,yv,...}
// ===========================================================================
__global__ __launch_bounds__(512) void k_gqd(const float* __restrict__ wg2b,
                                             float* __restrict__ ws,
                                             float* __restrict__ out)
{
  __shared__ __align__(16) unsigned short SH[32768];
  unsigned short* b1H = SH;
  unsigned short* b1L = SH + 4096;
  unsigned short* b2H = SH + 8192;
  unsigned short* b2L = SH + 12288;
  unsigned short* anH = SH + 16384;
  unsigned short* anL = SH + 20480;
  unsigned short* wH  = SH + 24576;
  unsigned short* wL  = SH + 28672;
  // late-phase aliases (W region; valid after GEMM4):
  unsigned short* xfH = SH + 24576;
  unsigned short* xfL = SH + 25600;
  unsigned short* zfH = SH + 26624;
  unsigned short* zfL = SH + 27648;
  float* alS  = (float*)(SH + 28672);   // 64*17 fl
  float* spH2 = (float*)(SH + 30848);   // 128 fl
  float* spS  = (float*)(SH + 31104);   // 64
  float* sfS  = (float*)(SH + 31232);   // 16
  float* yvS  = (float*)(SH + 31264);   // 64
  float* yhsS = (float*)(SH + 31392);   // 16
  // g2 scratch aliases (B2 region; valid after GEMM5):
  float* X2v  = (float*)(SH + 8192);    // 832 fl
  float* A22v = X2v + 832;              // 256
  float* G2v  = A22v + 256;             // 1024
  float* Pmv  = G2v + 1024;             // 1024
  float* wb2  = Pmv + 1024;             // 64
  float* zzv  = wb2 + 64;               // 16
  // dist aliases (valid after B12/B14):
  unsigned short* xcH = SH;             // 5120 u (b1 region + spill into b1L)
  unsigned short* xcL = SH + 16384;     // 5120 u (AN region)
  float* sqS = (float*)(SH + 21504);    // 80 fl (AN region tail)

  const int t = threadIdx.x, b = blockIdx.x;
  const int lane = t & 63, wave = t >> 6;
  const int s = wave & 3, half = wave >> 2;
  const int m16 = lane & 15, quad = lane >> 4;
  const int row0 = s * 16;
  const int arow = row0 + m16;
  const float* x = ws + OFF_X;
  const float* mk = ws + OFF_MK;
  const float* an22 = ws + OFF_AN22;
  const float* g2at = ws + OFF_G2AT;
  const unsigned short* gAnH = (const unsigned short*)(ws + OFF_ANH);
  const unsigned short* gAnL = (const unsigned short*)(ws + OFF_ANL);
  const unsigned short* gaH = (const unsigned short*)(ws + OFF_GAH);
  const unsigned short* gaL = (const unsigned short*)(ws + OFF_GAL);
  const unsigned short* gbH = (const unsigned short*)(ws + OFF_GBH);
  const unsigned short* gbL = (const unsigned short*)(ws + OFF_GBL);
  const unsigned short* gwkH = (const unsigned short*)(ws + OFF_WKH);
  const unsigned short* gwkL = (const unsigned short*)(ws + OFF_WKL);
  const float sc = (ws + OFF_SC)[0];

  // ---- P0: stage sg1, An, W1a; yv in reg; prefetch W1b ----
  for (int e = t; e < 4096; e += 512) {
    int r = e >> 6, k = e & 63;
    float v = (k < 51) ? x[(b * 80 + r) * 51 + k] : 0.f;
    int idx = SWZ6(r, k);
    split2(v, b1H[idx], b1L[idx]);
  }
  {
    int q = t;
    if (q < 512) {
      int r = q >> 3, c = q & 7;
      int dst = (r << 6) + ((c ^ (r & 7)) << 3);
      int src = (r << 6) + (c << 3);
      *(bf16x8*)(anH + dst) = *(const bf16x8*)(gAnH + src);
      *(bf16x8*)(anL + dst) = *(const bf16x8*)(gAnL + src);
      *(bf16x8*)(wH + dst)  = *(const bf16x8*)(gaH + src);
      *(bf16x8*)(wL + dst)  = *(const bf16x8*)(gaL + src);
    }
  }
  float yvreg = 0.f;
  if (t < 64) yvreg = x[(b * 80 + t) * 51 + 50];
  bf16x8 pH, pL;
  {
    int q = t & 511;
    int r = q >> 3, c = q & 7;
    int src = (r << 6) + (c << 3);
    pH = *(const bf16x8*)(gbH + src);
    pL = *(const bf16x8*)(gbL + src);
  }
  __syncthreads();   // B1

  // ---- GEMM1: T1 = sg1 @ W1a^T ----
  f32x4 accA[2];
#pragma unroll
  for (int n = 0; n < 2; ++n) accA[n] = (f32x4){0.f, 0.f, 0.f, 0.f};
#pragma unroll
  for (int kb8 = 0; kb8 < 8; kb8 += 4) {
    int ach = ((quad + kb8) ^ (m16 & 7)) << 3;
    bf16x8 aH = *(const bf16x8*)(b1H + (arow << 6) + ach);
    bf16x8 aL = *(const bf16x8*)(b1L + (arow << 6) + ach);
#pragma unroll
    for (int n = 0; n < 2; ++n) {
      const int col = (half * 2 + n) * 16 + m16;
      int boff = (col << 6) + ach;
      bf16x8 bH = *(const bf16x8*)(wH + boff);
      bf16x8 bL = *(const bf16x8*)(wL + boff);
      MFMA3(accA[n], aH, aL, bH, bL)
    }
  }
  __syncthreads();   // B2

  // ---- E1: T1 -> B2 [col][k]; W1b -> W; prefetch WkT ----
  {
    const int kb = row0 + quad * 4;
#pragma unroll
    for (int n = 0; n < 2; ++n) {
      const int col = (half * 2 + n) * 16 + m16;
      int idx = (col << 6) + (((((kb >> 3) ^ (col & 7)) << 3)) | (kb & 7));
      s16x4 hv, lv;
#pragma unroll
      for (int r = 0; r < 4; ++r) {
        unsigned short hh, ll; split2(accA[n][r], hh, ll);
        hv[r] = (short)hh; lv[r] = (short)ll;
      }
      *(s16x4*)(b2H + idx) = hv; *(s16x4*)(b2L + idx) = lv;
    }
  }
  {
    int q = t & 511;
    int r = q >> 3, c = q & 7;
    int dst = (r << 6) + ((c ^ (r & 7)) << 3);
    *(bf16x8*)(wH + dst) = pH;
    *(bf16x8*)(wL + dst) = pL;
    int src = (r << 6) + (c << 3);
    pH = *(const bf16x8*)(gwkH + src);
    pL = *(const bf16x8*)(gwkL + src);
  }
  __syncthreads();   // B3

  // ---- GEMM2: P = relu(An @ T1) ----
#pragma unroll
  for (int n = 0; n < 2; ++n) accA[n] = (f32x4){0.f, 0.f, 0.f, 0.f};
#pragma unroll
  for (int kb8 = 0; kb8 < 8; kb8 += 4) {
    int ach = ((quad + kb8) ^ (m16 & 7)) << 3;
    bf16x8 aH = *(const bf16x8*)(anH + (arow << 6) + ach);
    bf16x8 aL = *(const bf16x8*)(anL + (arow << 6) + ach);
#pragma unroll
    for (int n = 0; n < 2; ++n) {
      const int col = (half * 2 + n) * 16 + m16;
      int boff = (col << 6) + ach;
      bf16x8 bH = *(const bf16x8*)(b2H + boff);
      bf16x8 bL = *(const bf16x8*)(b2L + boff);
      MFMA3(accA[n], aH, aL, bH, bL)
    }
  }
  __syncthreads();   // B4

  // ---- E2: P -> B2 ----
  {
    const int kb = row0 + quad * 4;
#pragma unroll
    for (int n = 0; n < 2; ++n) {
      const int col = (half * 2 + n) * 16 + m16;
      int idx = (col << 6) + (((((kb >> 3) ^ (col & 7)) << 3)) | (kb & 7));
      s16x4 hv, lv;
#pragma unroll
      for (int r = 0; r < 4; ++r) {
        float v = accA[n][r]; v = v > 0.f ? v : 0.f;
        unsigned short hh, ll; split2(v, hh, ll);
        hv[r] = (short)hh; lv[r] = (short)ll;
      }
      *(s16x4*)(b2H + idx) = hv; *(s16x4*)(b2L + idx) = lv;
    }
  }
  __syncthreads();   // B5

  // ---- GEMM3: Q = An @ P ----
#pragma unroll
  for (int n = 0; n < 2; ++n) accA[n] = (f32x4){0.f, 0.f, 0.f, 0.f};
#pragma unroll
  for (int kb8 = 0; kb8 < 8; kb8 += 4) {
    int ach = ((quad + kb8) ^ (m16 & 7)) << 3;
    bf16x8 aH = *(const bf16x8*)(anH + (arow << 6) + ach);
    bf16x8 aL = *(const bf16x8*)(anL + (arow << 6) + ach);
#pragma unroll
    for (int n = 0; n < 2; ++n) {
      const int col = (half * 2 + n) * 16 + m16;
      int boff = (col << 6) + ach;
      bf16x8 bH = *(const bf16x8*)(b2H + boff);
      bf16x8 bL = *(const bf16x8*)(b2L + boff);
      MFMA3(accA[n], aH, aL, bH, bL)
    }
  }
  __syncthreads();   // B6

  // ---- E3: Q -> B1 [row][k]; WkT -> AN ----
#pragma unroll
  for (int n = 0; n < 2; ++n) {
    const int col = (half * 2 + n) * 16 + m16;
#pragma unroll
    for (int r = 0; r < 4; ++r) {
      int idx = SWZ6(row0 + quad * 4 + r, col);
      split2(accA[n][r], b1H[idx], b1L[idx]);
    }
  }
  {
    int q = t & 511;
    int r = q >> 3, c = q & 7;
    int dst = (r << 6) + ((c ^ (r & 7)) << 3);
    *(bf16x8*)(anH + dst) = pH;
    *(bf16x8*)(anL + dst) = pL;
  }
  float xf0 = 0.f, xf1 = 0.f;
  {
    int e0 = t, e1 = t + 512;
    int r0r = e0 >> 6, c0 = e0 & 63;
    int r1r = e1 >> 6, c1 = e1 & 63;
    if (c0 < 50) xf0 = x[(b * 80 + 64 + r0r) * 51 + c0];
    if (c1 < 50) xf1 = x[(b * 80 + 64 + r1r) * 51 + c1];
  }
  __syncthreads();   // B7

  // ---- GEMM4: x1 = Q @ W1b^T ----
#pragma unroll
  for (int n = 0; n < 2; ++n) accA[n] = (f32x4){0.f, 0.f, 0.f, 0.f};
#pragma unroll
  for (int kb8 = 0; kb8 < 8; kb8 += 4) {
    int ach = ((quad + kb8) ^ (m16 & 7)) << 3;
    bf16x8 aH = *(const bf16x8*)(b1H + (arow << 6) + ach);
    bf16x8 aL = *(const bf16x8*)(b1L + (arow << 6) + ach);
#pragma unroll
    for (int n = 0; n < 2; ++n) {
      const int col = (half * 2 + n) * 16 + m16;
      int boff = (col << 6) + ach;
      bf16x8 bH = *(const bf16x8*)(wH + boff);
      bf16x8 bL = *(const bf16x8*)(wL + boff);
      MFMA3(accA[n], aH, aL, bH, bL)
    }
  }
  __syncthreads();   // B8

  // ---- E4: x1 -> B2 [row][k]; xf -> XF; yv -> yvS ----
#pragma unroll
  for (int n = 0; n < 2; ++n) {
    const int col = (half * 2 + n) * 16 + m16;
#pragma unroll
    for (int r = 0; r < 4; ++r) {
      int idx = SWZ6(row0 + quad * 4 + r, col);
      split2(accA[n][r], b2H[idx], b2L[idx]);
    }
  }
  {
    int e0 = t, e1 = t + 512;
    int i0 = SWZ6(e0 >> 6, e0 & 63);
    int i1 = SWZ6(e1 >> 6, e1 & 63);
    split2(xf0, xfH[i0], xfL[i0]);
    split2(xf1, xfH[i1], xfL[i1]);
  }
  if (t < 64) yvS[t] = yvreg;
  __syncthreads();   // B9

  // ---- GEMM5: Zp = x1 @ WkT (4-term); Zf on half0; sp via shuffles ----
#pragma unroll
  for (int n = 0; n < 2; ++n) accA[n] = (f32x4){0.f, 0.f, 0.f, 0.f};
#pragma unroll
  for (int kb8 = 0; kb8 < 8; kb8 += 4) {
    int ach = ((quad + kb8) ^ (m16 & 7)) << 3;
    bf16x8 aH = *(const bf16x8*)(b2H + (arow << 6) + ach);
    bf16x8 aL = *(const bf16x8*)(b2L + (arow << 6) + ach);
#pragma unroll
    for (int n = 0; n < 2; ++n) {
      const int col = (half * 2 + n) * 16 + m16;
      int boff = (col << 6) + ach;
      bf16x8 bH = *(const bf16x8*)(anH + boff);
      bf16x8 bL = *(const bf16x8*)(anL + boff);
      MFMA4(accA[n], aH, aL, bH, bL)
    }
  }
  if (half == 0) {
    f32x4 af = (f32x4){0.f, 0.f, 0.f, 0.f};
#pragma unroll
    for (int kb8 = 0; kb8 < 8; kb8 += 4) {
      int ach = ((quad + kb8) ^ (m16 & 7)) << 3;
      bf16x8 aH = *(const bf16x8*)(xfH + (m16 << 6) + ach);
      bf16x8 aL = *(const bf16x8*)(xfL + (m16 << 6) + ach);
      const int col = s * 16 + m16;
      int boff = (col << 6) + ach;
      bf16x8 bH = *(const bf16x8*)(anH + boff);
      bf16x8 bL = *(const bf16x8*)(anL + boff);
      MFMA4(af, aH, aL, bH, bL)
    }
    const int h = s * 16 + m16;
#pragma unroll
    for (int r = 0; r < 4; ++r) {
      int idx = SWZ6(quad * 4 + r, h);
      split2(af[r], zfH[idx], zfL[idx]);
    }
  }
  {
    float s2[4];
#pragma unroll
    for (int r = 0; r < 4; ++r)
      s2[r] = accA[0][r] * accA[0][r] + accA[1][r] * accA[1][r];
#pragma unroll
    for (int n = 0; n < 2; ++n) {
      const int h = (half * 2 + n) * 16 + m16;
#pragma unroll
      for (int r = 0; r < 4; ++r) {
        int idx = SWZ6(row0 + quad * 4 + r, h);
        split2(accA[n][r], b1H[idx], b1L[idx]);
      }
    }
#pragma unroll
    for (int m = 1; m < 16; m <<= 1)
#pragma unroll
      for (int r = 0; r < 4; ++r) s2[r] += __shfl_xor(s2[r], m);
    if (m16 == 0) {
#pragma unroll
      for (int r = 0; r < 4; ++r)
        spH2[(row0 + quad * 4 + r) * 2 + half] = s2[r];
    }
  }
  __syncthreads();   // B10

  if (t < 64) {
    spS[t] = spH2[t * 2] + spH2[t * 2 + 1];
  } else if (t < 80) {
    int j = t - 64;
    float ssum = 0.f;
    for (int h = 0; h < 64; ++h) {
      int idx = SWZ6(j, h);
      float v = bf2f(zfH[idx]) + bf2f(zfL[idx]);
      ssum += v * v;
    }
    sfS[j] = ssum;
  }
  __syncthreads();   // B11

  // ---- GEMM6: cross = Zp @ Zf^T (4-term); half0 writes al ----
  {
    f32x4 ac2 = (f32x4){0.f, 0.f, 0.f, 0.f};
#pragma unroll
    for (int kb8 = 0; kb8 < 8; kb8 += 4) {
      int ach = ((quad + kb8) ^ (m16 & 7)) << 3;
      bf16x8 aH = *(const bf16x8*)(b1H + (arow << 6) + ach);
      bf16x8 aL = *(const bf16x8*)(b1L + (arow << 6) + ach);
      bf16x8 bH = *(const bf16x8*)(zfH + (m16 << 6) + ach);
      bf16x8 bL = *(const bf16x8*)(zfL + (m16 << 6) + ach);
      MFMA4(ac2, aH, aL, bH, bL)
    }
    if (half == 0) {
#pragma unroll
      for (int r = 0; r < 4; ++r) {
        int i = row0 + quad * 4 + r;
        alS[i * 17 + m16] = sc * (spS[i] + sfS[m16] - 2.f * ac2[r]);
      }
    }
  }
  __syncthreads();   // B12 (b1/AN/W regions dead after this)

  // ---- masked softmax over j per i ----
  if (t < 64) {
    const int i = t;
    float lv[16];
    float m = -3.4e38f;
#pragma unroll
    for (int j = 0; j < 16; ++j) {
      float v = (mk[j * 64 + i] != 0.f) ? alS[i * 17 + j] : NEGBIG;
      lv[j] = v;
      m = fmaxf(m, v);
    }
    float ssum = 0.f;
#pragma unroll
    for (int j = 0; j < 16; ++j) { lv[j] = expf(lv[j] - m); ssum += lv[j]; }
    float inv = 1.f / ssum;
#pragma unroll
    for (int j = 0; j < 16; ++j) alS[i * 17 + j] = lv[j] * inv;
  }
  __syncthreads();   // B13

  if (t < 16) {
    float ssum = 0.f;
    for (int i = 0; i < 64; ++i) ssum += alS[i * 17 + t] * yvS[i];
    yhsS[t] = ssum;
  }
  __syncthreads();   // B14

  // ---- stage xc (dist) + g2 scratch ----
  for (int e = t; e < 5120; e += 512) {
    int n = e >> 6, c = e & 63;
    float v = 0.f;
    if (c < 50)       v = x[(b * 80 + n) * 51 + c];
    else if (c == 50) v = (n < 64) ? x[(b * 80 + n) * 51 + 50] : yhsS[n - 64];
    int idx = SWZ6(n, c);
    split2(v, xcH[idx], xcL[idx]);
  }
  for (int e = t; e < 832; e += 512) {
    int r = e / 52, c = e - r * 52;
    float v = 0.f;
    if (c < 50)       v = x[(b * 80 + 64 + r) * 51 + c];
    else if (c == 50) v = yhsS[r];
    X2v[e] = v;
  }
  for (int e = t; e < 256; e += 512) A22v[e] = an22[e];
  if (t < 64) wb2[t] = wg2b[t];
  __syncthreads();   // B15

  // ---- dist Gram (all waves, 25 tiles over 8 waves) + sq diag ----
  f32x4 accD[4];
  {
    int tc = 0;
    for (int idx = wave; idx < 25; idx += 8) {
      int ts = idx / 5, tf = idx - ts * 5;
      f32x4 acc = (f32x4){0.f, 0.f, 0.f, 0.f};
#pragma unroll
      for (int kb8 = 0; kb8 < 8; kb8 += 4) {
        int ach = ((quad + kb8) ^ (m16 & 7)) << 3;
        bf16x8 aH = *(const bf16x8*)(xcH + ((ts * 16 + m16) << 6) + ach);
        bf16x8 aL = *(const bf16x8*)(xcL + ((ts * 16 + m16) << 6) + ach);
        const int col = tf * 16 + m16;
        int boff = (col << 6) + ach;
        bf16x8 bH = *(const bf16x8*)(xcH + boff);
        bf16x8 bL = *(const bf16x8*)(xcL + boff);
        MFMA3(acc, aH, aL, bH, bL)
      }
      if (ts == tf && (m16 >> 2) == quad) sqS[ts * 16 + m16] = acc[m16 & 3];
      accD[tc++] = acc;
    }
  }
  // ---- g2: G = X2 @ W2a^T ----
  for (int e = t; e < 1024; e += 512) {
    int j = e >> 6, h = e & 63;
    float ssum = 0.f;
    for (int k = 0; k < 51; ++k) ssum += X2v[j * 52 + k] * g2at[k * 64 + h];
    G2v[e] = ssum;
  }
  __syncthreads();   // B16 (sq + G visible)

  // ---- g2: P = relu(A22 @ G) ----
  for (int e = t; e < 1024; e += 512) {
    int j = e >> 6, h = e & 63;
    float ssum = 0.f;
#pragma unroll
    for (int k = 0; k < 16; ++k) ssum += A22v[j * 16 + k] * G2v[k * 64 + h];
    Pmv[e] = ssum > 0.f ? ssum : 0.f;
  }
  // ---- dist epilogue + stores ----
  {
    float* dist = out + OUT_DIST + b * 6400;
    int tc = 0;
    for (int idx = wave; idx < 25; idx += 8) {
      int ts = idx / 5, tf = idx - ts * 5;
      f32x4 acc = accD[tc++];
#pragma unroll
      for (int r = 0; r < 4; ++r) {
        int i = ts * 16 + quad * 4 + r;
        int m = tf * 16 + m16;
        float d2 = sqS[i] + sqS[m] - 2.f * acc[r];
        d2 = d2 > 0.f ? d2 : 0.f;
        dist[i * 80 + m] = d2 > 0.f ? sqrtf(d2) : 0.f;
      }
    }
  }
  __syncthreads();   // B17
  if (t < 16) {
    float ssum = 0.f;
    for (int h = 0; h < 64; ++h) ssum += Pmv[t * 64 + h] * wb2[h];
    zzv[t] = ssum;
  }
  __syncthreads();   // B18
  if (t < 16) {
    float ssum = 0.f;
#pragma unroll
    for (int k = 0; k < 16; ++k) ssum += A22v[t * 16 + k] * zzv[k];
    out[OUT_OUT + b * 16 + t] = ssum;
  }
}

// ===========================================================================
extern "C" void kernel_launch(void* const* d_in, const int* in_sizes, int n_in,
                              void* d_out, int out_size, void* d_ws, size_t ws_size,
                              hipStream_t stream)
{
  const float* data = (const float*)d_in[0];
  const float* emb0 = (const float*)d_in[1];
  const float* emb1 = (const float*)d_in[2];
  const float* emb2 = (const float*)d_in[3];
  const float* w1   = (const float*)d_in[4];
  const float* b1   = (const float*)d_in[5];
  const float* w2   = (const float*)d_in[6];
  const float* b2   = (const float*)d_in[7];
  const float* w3   = (const float*)d_in[8];
  const float* b3   = (const float*)d_in[9];
  const float* M    = (const float*)d_in[10];
  const float* wg1a = (const float*)d_in[11];
  const float* wg1b = (const float*)d_in[12];
  const float* Wk   = (const float*)d_in[13];
  const float* smo  = (const float*)d_in[14];
  const float* wg2a = (const float*)d_in[15];
  const float* wg2b = (const float*)d_in[16];
  float* ws  = (float*)d_ws;
  float* out = (float*)d_out;

  k_prep<<<dim3(4),    dim3(256), 0, stream>>>(M, Wk, smo, w1, w2, w3, wg1a, wg1b, wg2a, ws, out);
  k_mlp <<<dim3(1280), dim3(512), 0, stream>>>(data, emb0, emb1, emb2, b1, b2, b3, ws);
  k_gqd <<<dim3(1024), dim3(512), 0, stream>>>(wg2b, ws, out);
}